// Round 5
// baseline (606.322 us; speedup 1.0000x reference)
//
#include <hip/hip_runtime.h>
#include <cstdint>

#define HS 62
#define HX 248
#define HXW (HX * HX)  // 61504
#define HSW (HS * HS)  // 3844

typedef __attribute__((ext_vector_type(8))) short bf16x8;
typedef __attribute__((ext_vector_type(4))) float f32x4;

static __device__ __forceinline__ unsigned short f2bf(float f) {
  uint32_t u = __builtin_bit_cast(uint32_t, f);
  u += 0x7fff + ((u >> 16) & 1);  // RNE
  return (unsigned short)(u >> 16);
}

// ---------------------------------------------------------------------------
// Depthwise 3x3 scalar (62x62 tensors), fp32 out, bias+residual.
// ---------------------------------------------------------------------------
__global__ void dwconv3_kernel(const float* __restrict__ x, const float* __restrict__ w,
                               const float* __restrict__ bias, float* __restrict__ y,
                               int C, int H, int W, int total, int residual) {
  int i = blockIdx.x * 256 + threadIdx.x;
  if (i >= total) return;
  int wx = i % W;
  int t = i / W;
  int hy = t % H;
  int bc = t / H;
  int c = bc % C;
  const float* xb = x + (size_t)bc * H * W;
  const float* wc = w + c * 9;
  float s = bias ? bias[c] : 0.0f;
  for (int di = -1; di <= 1; di++) {
    int h2 = hy + di;
    if (h2 < 0 || h2 >= H) continue;
    for (int dj = -1; dj <= 1; dj++) {
      int w2 = wx + dj;
      if (w2 < 0 || w2 >= W) continue;
      s += xb[(size_t)h2 * W + w2] * wc[(di + 1) * 3 + (dj + 1)];
    }
  }
  if (residual) s += xb[(size_t)hy * W + wx];
  y[i] = s;
}

// ---------------------------------------------------------------------------
// Depthwise 3x3 vectorized fp32 (x -> xp), 4 pixels/thread, W%4==0.
// ---------------------------------------------------------------------------
__global__ void dwconv4_kernel(const float* __restrict__ x, const float* __restrict__ w,
                               const float* __restrict__ bias, float* __restrict__ y,
                               int C, int H, int W, int total4, int residual) {
  int i = blockIdx.x * 256 + threadIdx.x;
  if (i >= total4) return;
  int W4 = W >> 2;
  int wq = (i % W4) * 4;
  int t = i / W4;
  int hy = t % H;
  int bc = t / H;
  int c = bc % C;
  const float* xb = x + (size_t)bc * H * W;
  const float* wc = w + c * 9;
  float bv = bias ? bias[c] : 0.0f;
  float s0 = bv, s1 = bv, s2 = bv, s3 = bv;
  for (int di = -1; di <= 1; di++) {
    int h2 = hy + di;
    if (h2 < 0 || h2 >= H) continue;
    const float* row = xb + (size_t)h2 * W + wq;
    float4 cv = *(const float4*)row;
    float lf = (wq > 0) ? row[-1] : 0.0f;
    float rt = (wq + 4 < W) ? row[4] : 0.0f;
    float w0 = wc[(di + 1) * 3 + 0];
    float w1 = wc[(di + 1) * 3 + 1];
    float w2 = wc[(di + 1) * 3 + 2];
    s0 += w0 * lf   + w1 * cv.x + w2 * cv.y;
    s1 += w0 * cv.x + w1 * cv.y + w2 * cv.z;
    s2 += w0 * cv.y + w1 * cv.z + w2 * cv.w;
    s3 += w0 * cv.z + w1 * cv.w + w2 * rt;
  }
  if (residual) {
    float4 cc = *(const float4*)(xb + (size_t)hy * W + wq);
    s0 += cc.x; s1 += cc.y; s2 += cc.z; s3 += cc.w;
  }
  *(float4*)(y + (size_t)bc * H * W + (size_t)hy * W + wq) = make_float4(s0, s1, s2, s3);
}

// ---------------------------------------------------------------------------
// Depthwise 3x3 q path: fp32 NCHW in -> bf16 NHWC out, pre-scaled by 32^-0.5.
// ---------------------------------------------------------------------------
__global__ void dwconv_q_kernel(const float* __restrict__ x, const float* __restrict__ w,
                                unsigned short* __restrict__ qn, int total) {
  int i = blockIdx.x * 256 + threadIdx.x;
  if (i >= total) return;
  int wx = i % HS;
  int t = i / HS;
  int hy = t % HS;
  int bc = t / HS;
  int c = bc & 127;
  int b = bc >> 7;
  const float* xb = x + (size_t)bc * HSW;
  const float* wc = w + c * 9;
  float s = 0.0f;
  for (int di = -1; di <= 1; di++) {
    int h2 = hy + di;
    if (h2 < 0 || h2 >= HS) continue;
    for (int dj = -1; dj <= 1; dj++) {
      int w2 = wx + dj;
      if (w2 < 0 || w2 >= HS) continue;
      s += xb[(size_t)h2 * HS + w2] * wc[(di + 1) * 3 + (dj + 1)];
    }
  }
  qn[((size_t)(b * HSW + hy * HS + wx)) * 128 + c] = f2bf(s * 0.17677669529663688f);
}

// ---------------------------------------------------------------------------
// Depthwise 3x3 K path: fp32 NCHW (K half of 256ch) -> bf16 NHWC.
// Block = (64-px strip, row hy, b): thread (c, half) marches 32 consecutive
// pixels of channel c (sequential L1-friendly reads), LDS [px][ch] transpose,
// coalesced 16 KB NHWC store. Grid (4, 248, 2).
// ---------------------------------------------------------------------------
__global__ __launch_bounds__(256) void dwconv_k_kernel(const float* __restrict__ x,
                                                       const float* __restrict__ w,
                                                       unsigned short* __restrict__ kT) {
  int strip = blockIdx.x;                 // 0..3
  int x0 = (strip == 3) ? 184 : strip * 64;
  int hy = blockIdx.y;
  int b = blockIdx.z;
  int c = threadIdx.x & 127;
  int half = threadIdx.x >> 7;            // 0..1
  int px0 = x0 + half * 32;
  const float* xb = x + ((size_t)(b * 256 + c)) * HXW;
  const float* wc = w + c * 9;
  float w00 = wc[0], w01 = wc[1], w02 = wc[2];
  float w10 = wc[3], w11 = wc[4], w12 = wc[5];
  float w20 = wc[6], w21 = wc[7], w22 = wc[8];
  __shared__ unsigned short t[64 * 128];  // [px][ch] 16 KB
  const float* r0 = xb + (size_t)(hy - 1) * HX;
  const float* r1 = xb + (size_t)hy * HX;
  const float* r2 = xb + (size_t)(hy + 1) * HX;
  bool v0 = hy > 0, v2 = hy < HX - 1;
  float lf0 = (px0 > 0 && v0) ? r0[px0 - 1] : 0.0f;
  float lf1 = (px0 > 0)       ? r1[px0 - 1] : 0.0f;
  float lf2 = (px0 > 0 && v2) ? r2[px0 - 1] : 0.0f;
  const float4 z4 = make_float4(0.f, 0.f, 0.f, 0.f);
#pragma unroll
  for (int pg = 0; pg < 8; pg++) {
    int wq = px0 + pg * 4;
    float4 c0 = v0 ? *(const float4*)(r0 + wq) : z4;
    float4 c1 = *(const float4*)(r1 + wq);
    float4 c2 = v2 ? *(const float4*)(r2 + wq) : z4;
    bool vr = (wq + 4) < HX;
    float rt0 = (vr && v0) ? r0[wq + 4] : 0.0f;
    float rt1 = vr          ? r1[wq + 4] : 0.0f;
    float rt2 = (vr && v2) ? r2[wq + 4] : 0.0f;
    float s0 = w00*lf0  + w01*c0.x + w02*c0.y + w10*lf1  + w11*c1.x + w12*c1.y + w20*lf2  + w21*c2.x + w22*c2.y;
    float s1 = w00*c0.x + w01*c0.y + w02*c0.z + w10*c1.x + w11*c1.y + w12*c1.z + w20*c2.x + w21*c2.y + w22*c2.z;
    float s2 = w00*c0.y + w01*c0.z + w02*c0.w + w10*c1.y + w11*c1.z + w12*c1.w + w20*c2.y + w21*c2.z + w22*c2.w;
    float s3 = w00*c0.z + w01*c0.w + w02*rt0  + w10*c1.z + w11*c1.w + w12*rt1  + w20*c2.z + w21*c2.w + w22*rt2;
    int p = half * 32 + pg * 4;
    t[(p + 0) * 128 + c] = f2bf(s0);
    t[(p + 1) * 128 + c] = f2bf(s1);
    t[(p + 2) * 128 + c] = f2bf(s2);
    t[(p + 3) * 128 + c] = f2bf(s3);
    lf0 = c0.w; lf1 = c1.w; lf2 = c2.w;
  }
  __syncthreads();
  size_t dst = ((size_t)(b * HXW) + (size_t)hy * HX + x0) * 128;
  const uint4* ts = (const uint4*)t;
  uint4* td = (uint4*)(kT + dst);
#pragma unroll
  for (int j = 0; j < 4; j++) td[j * 256 + threadIdx.x] = ts[j * 256 + threadIdx.x];
}

// ---------------------------------------------------------------------------
// Depthwise 3x3 V path: fp32 NCHW (V half of 256ch) -> bf16 NCHW (coalesced).
// ---------------------------------------------------------------------------
__global__ void dwconv_v_kernel(const float* __restrict__ x, const float* __restrict__ w,
                                unsigned short* __restrict__ v, int total4) {
  int i = blockIdx.x * 256 + threadIdx.x;
  if (i >= total4) return;
  int W4 = HX >> 2;
  int wq = (i % W4) * 4;
  int t = i / W4;
  int hy = t % HX;
  int bc = t / HX;             // b*128 + c
  int c = bc & 127;
  int b = bc >> 7;
  const float* xb = x + ((size_t)(b * 256 + 128 + c)) * HXW;
  const float* wc = w + (128 + c) * 9;
  float s0 = 0, s1 = 0, s2 = 0, s3 = 0;
  for (int di = -1; di <= 1; di++) {
    int h2 = hy + di;
    if (h2 < 0 || h2 >= HX) continue;
    const float* row = xb + (size_t)h2 * HX + wq;
    float4 cv = *(const float4*)row;
    float lf = (wq > 0) ? row[-1] : 0.0f;
    float rt = (wq + 4 < HX) ? row[4] : 0.0f;
    float w0 = wc[(di + 1) * 3 + 0];
    float w1 = wc[(di + 1) * 3 + 1];
    float w2 = wc[(di + 1) * 3 + 2];
    s0 += w0 * lf   + w1 * cv.x + w2 * cv.y;
    s1 += w0 * cv.x + w1 * cv.y + w2 * cv.z;
    s2 += w0 * cv.y + w1 * cv.z + w2 * cv.w;
    s3 += w0 * cv.z + w1 * cv.w + w2 * rt;
  }
  uint2 d;
  d.x = (uint32_t)f2bf(s0) | ((uint32_t)f2bf(s1) << 16);
  d.y = (uint32_t)f2bf(s2) | ((uint32_t)f2bf(s3) << 16);
  *(uint2*)(v + (size_t)bc * HXW + (size_t)hy * HX + wq) = d;
}

// ---------------------------------------------------------------------------
// 1x1 conv tiled SGEMM (fp32).
// ---------------------------------------------------------------------------
template <int O>
__global__ __launch_bounds__(256) void conv1_kernel(const float* __restrict__ x,
                                                    const float* __restrict__ w,
                                                    float* __restrict__ y, int HW) {
  constexpr int K = 128;
  constexpr int BK = 32;
  __shared__ __align__(16) float ws_s[BK][64];
  __shared__ __align__(16) float xs_s[BK][64];
  int b = blockIdx.z;
  int o0 = blockIdx.y * 64;
  int p0 = blockIdx.x * 64;
  const float* xb = x + (size_t)b * K * HW;
  int tx = threadIdx.x & 15;
  int ty = threadIdx.x >> 4;
  float acc[4][4] = {};
  int lo = threadIdx.x >> 2;
  int lk = (threadIdx.x & 3) * 8;
  int lc = threadIdx.x >> 3;
  int lp = (threadIdx.x & 7) * 8;

  for (int k0 = 0; k0 < K; k0 += BK) {
    __syncthreads();
    {
      const float* wp = w + (size_t)(o0 + lo) * K + k0 + lk;
      float4 a = *(const float4*)wp;
      float4 bq = *(const float4*)(wp + 4);
      ws_s[lk + 0][lo] = a.x;  ws_s[lk + 1][lo] = a.y;
      ws_s[lk + 2][lo] = a.z;  ws_s[lk + 3][lo] = a.w;
      ws_s[lk + 4][lo] = bq.x; ws_s[lk + 5][lo] = bq.y;
      ws_s[lk + 6][lo] = bq.z; ws_s[lk + 7][lo] = bq.w;
    }
    {
      int p = p0 + lp;
      const float* xp = xb + (size_t)(k0 + lc) * HW;
      float4 a, bq;
      if (p + 7 < HW) {
        a = *(const float4*)(xp + p);
        bq = *(const float4*)(xp + p + 4);
      } else {
        float tv[8];
#pragma unroll
        for (int j = 0; j < 8; j++) tv[j] = (p + j < HW) ? xp[p + j] : 0.0f;
        a = make_float4(tv[0], tv[1], tv[2], tv[3]);
        bq = make_float4(tv[4], tv[5], tv[6], tv[7]);
      }
      *(float4*)&xs_s[lc][lp] = a;
      *(float4*)&xs_s[lc][lp + 4] = bq;
    }
    __syncthreads();
#pragma unroll
    for (int k = 0; k < BK; k++) {
      float4 wv = *(const float4*)&ws_s[k][ty * 4];
      float4 xv = *(const float4*)&xs_s[k][tx * 4];
      acc[0][0] += wv.x * xv.x; acc[0][1] += wv.x * xv.y; acc[0][2] += wv.x * xv.z; acc[0][3] += wv.x * xv.w;
      acc[1][0] += wv.y * xv.x; acc[1][1] += wv.y * xv.y; acc[1][2] += wv.y * xv.z; acc[1][3] += wv.y * xv.w;
      acc[2][0] += wv.z * xv.x; acc[2][1] += wv.z * xv.y; acc[2][2] += wv.z * xv.z; acc[2][3] += wv.z * xv.w;
      acc[3][0] += wv.w * xv.x; acc[3][1] += wv.w * xv.y; acc[3][2] += wv.w * xv.z; acc[3][3] += wv.w * xv.w;
    }
  }
  int p = p0 + tx * 4;
  float* yb = y + (size_t)b * O * HW + (size_t)(o0 + ty * 4) * HW;
#pragma unroll
  for (int j = 0; j < 4; j++) {
    float* yr = yb + (size_t)j * HW + p;
    if (p + 3 < HW) {
      *(float4*)yr = make_float4(acc[j][0], acc[j][1], acc[j][2], acc[j][3]);
    } else {
#pragma unroll
      for (int e = 0; e < 4; e++) if (p + e < HW) yr[e] = acc[j][e];
    }
  }
}

// ---------------------------------------------------------------------------
// MFMA windowed attention, head-pair blocks for 100% K-line use.
// Block = (window n, head-pair hp, batch b), 512 thr = 8 waves:
//   wave = (oct<<1)|hd : head h = hp*2+hd, key rows oct*8..oct*8+7.
// Scores are tiny (|s|<~0.2) by construction -> skip max-tracking entirely:
//   p = exp(s), merge = plain sum of (acc, l) over the 4 octs per head.
// K/V A-fragments load directly global->reg (NHWC / NCHW match MFMA layout).
// ---------------------------------------------------------------------------
__global__ __launch_bounds__(512) void attn_mfma_kernel(
    const unsigned short* __restrict__ qn,   // (2,62,62,128) bf16, pre-scaled
    const unsigned short* __restrict__ kT,   // (2,248,248,128) bf16 NHWC
    const unsigned short* __restrict__ vp,   // (2,128,248,248) bf16 NCHW
    float* __restrict__ o) {
  int n = blockIdx.x, hp = blockIdx.y, b = blockIdx.z;
  int wi = n / 10, wj = n % 10;
  int wave = threadIdx.x >> 6;
  int hd = wave & 1, oct = wave >> 1;
  int h = hp * 2 + hd;
  int lane = threadIdx.x & 63;
  int quad = lane >> 4;
  int l15 = lane & 15;
  int y0 = 24 * wi, x0 = 24 * wj;

  __shared__ __align__(16) unsigned short lds[20480];  // 40,960 B
  unsigned short* Pw = lds + wave * 2560;              // [q][40keys] 5KB/wave

  // Q B-fragments for this head (held in registers)
  bf16x8 QB[4];
#pragma unroll
  for (int nt = 0; nt < 4; nt++) {
    int qq = nt * 16 + l15;
    int qy = 6 * wi + (qq >> 3), qx = 6 * wj + (qq & 7);
    QB[nt] = __builtin_bit_cast(bf16x8,
        *(const uint4*)(qn + ((size_t)(b * HSW + qy * HS + qx)) * 128 + h * 32 + quad * 8));
  }

  f32x4 Oacc[2][4];
#pragma unroll
  for (int a = 0; a < 2; a++)
#pragma unroll
    for (int c = 0; c < 4; c++) Oacc[a][c] = f32x4{0.f, 0.f, 0.f, 0.f};
  float lsum[4] = {0.f, 0.f, 0.f, 0.f};

  const unsigned short* kb = kT + (size_t)b * HXW * 128 + h * 32;
  const unsigned short* vb = vp + ((size_t)(b * 128 + h * 32)) * HXW;

  uint4 ka[2][2], va[2][2];
  auto loadrow = [&](int r, uint4* kk, uint4* vv) {
    int y = y0 + r;
    const unsigned short* krow = kb + ((size_t)(y * HX + x0)) * 128;
    kk[0] = *(const uint4*)(krow + (size_t)l15 * 128 + quad * 8);
    kk[1] = *(const uint4*)(krow + (size_t)(16 + l15) * 128 + quad * 8);
    const unsigned short* vrow = vb + (size_t)y * HX + x0 + quad * 8;
    vv[0] = *(const uint4*)(vrow + (size_t)l15 * HXW);
    vv[1] = *(const uint4*)(vrow + (size_t)(16 + l15) * HXW);
  };
  loadrow(oct * 8, ka[0], va[0]);
  const f32x4 zf = {0.f, 0.f, 0.f, 0.f};

#pragma unroll 1
  for (int r8 = 0; r8 < 8; r8++) {
    int cur = r8 & 1, nxt = cur ^ 1;
    if (r8 < 7) loadrow(oct * 8 + r8 + 1, ka[nxt], va[nxt]);

    bf16x8 KA[2], VA[2];
    KA[0] = __builtin_bit_cast(bf16x8, ka[cur][0]);
    KA[1] = __builtin_bit_cast(bf16x8, ka[cur][1]);
    VA[0] = __builtin_bit_cast(bf16x8, va[cur][0]);
    VA[1] = __builtin_bit_cast(bf16x8, va[cur][1]);

    f32x4 S[2][4];
#pragma unroll
    for (int mt = 0; mt < 2; mt++)
#pragma unroll
      for (int nt = 0; nt < 4; nt++)
        S[mt][nt] = __builtin_amdgcn_mfma_f32_16x16x32_bf16(KA[mt], QB[nt], zf, 0, 0, 0);

#pragma unroll
    for (int nt = 0; nt < 4; nt++) {
      float pv[2][4];
      float cs = 0.f;
#pragma unroll
      for (int mt = 0; mt < 2; mt++)
#pragma unroll
        for (int r = 0; r < 4; r++) {
          pv[mt][r] = __expf(S[mt][nt][r]);
          cs += pv[mt][r];
        }
      lsum[nt] += cs;
#pragma unroll
      for (int mt = 0; mt < 2; mt++) {
        uint2 d;
        d.x = (uint32_t)f2bf(pv[mt][0]) | ((uint32_t)f2bf(pv[mt][1]) << 16);
        d.y = (uint32_t)f2bf(pv[mt][2]) | ((uint32_t)f2bf(pv[mt][3]) << 16);
        *(uint2*)(Pw + (16 * nt + l15) * 40 + 16 * mt + quad * 4) = d;
      }
    }
#pragma unroll
    for (int nt = 0; nt < 4; nt++) {
      bf16x8 PB = __builtin_bit_cast(bf16x8, *(const uint4*)(Pw + (16 * nt + l15) * 40 + quad * 8));
      Oacc[0][nt] = __builtin_amdgcn_mfma_f32_16x16x32_bf16(VA[0], PB, Oacc[0][nt], 0, 0, 0);
      Oacc[1][nt] = __builtin_amdgcn_mfma_f32_16x16x32_bf16(VA[1], PB, Oacc[1][nt], 0, 0, 0);
    }
  }

  // full row-sum of l over the quad rows (keys) of this wave
#pragma unroll
  for (int nt = 0; nt < 4; nt++) {
    lsum[nt] += __shfl_xor(lsum[nt], 16, 64);
    lsum[nt] += __shfl_xor(lsum[nt], 32, 64);
  }

  // ---- two-phase merge: sum (acc, l) over the 4 octs of each head ----
  float* mO = (float*)lds;                 // [oct][32ch][64q]  32 KB
  float* mL = (float*)(lds + 16384);       // [oct][64q]
#pragma unroll 1
  for (int p = 0; p < 2; p++) {
    __syncthreads();
    if (hd == p) {
#pragma unroll
      for (int mt = 0; mt < 2; mt++)
#pragma unroll
        for (int nt = 0; nt < 4; nt++)
#pragma unroll
          for (int r = 0; r < 4; r++)
            mO[oct * 2048 + (16 * mt + quad * 4 + r) * 64 + 16 * nt + l15] = Oacc[mt][nt][r];
      if (quad == 0) {
#pragma unroll
        for (int nt = 0; nt < 4; nt++) mL[oct * 64 + nt * 16 + l15] = lsum[nt];
      }
    }
    __syncthreads();
    {
      int q = threadIdx.x & 63;
      int cg = threadIdx.x >> 6;  // 0..7 -> 4 ch each
      float inv = 1.0f / (mL[q] + mL[64 + q] + mL[128 + q] + mL[192 + q]);
      float* ob = o + (((size_t)(b * 100 + n)) * 128 + (hp * 2 + p) * 32 + cg * 4) * 64 + q;
#pragma unroll
      for (int e = 0; e < 4; e++) {
        int ch = cg * 4 + e;
        float s = mO[ch * 64 + q] + mO[2048 + ch * 64 + q] +
                  mO[4096 + ch * 64 + q] + mO[6144 + ch * 64 + q];
        ob[(size_t)e * 64] = s * inv;
      }
    }
  }
}

// ---------------------------------------------------------------------------
// Reverse: scatter-average overlapping 8x8 windows (step 6) into (2,128,62,62)
// ---------------------------------------------------------------------------
__global__ void reverse_kernel(const float* __restrict__ win, float* __restrict__ out) {
  int i = blockIdx.x * 256 + threadIdx.x;
  const int total = 2 * 128 * HSW;
  if (i >= total) return;
  int x = i % HS;
  int t = i / HS;
  int y = t % HS;
  t /= HS;
  int c = t % 128;
  int b = t / 128;
  int wi0 = (y >= 7) ? (y - 2) / 6 : 0;
  int wi1 = min(9, y / 6);
  int wj0 = (x >= 7) ? (x - 2) / 6 : 0;
  int wj1 = min(9, x / 6);
  float s = 0.0f;
  for (int wi = wi0; wi <= wi1; wi++)
    for (int wj = wj0; wj <= wj1; wj++) {
      int di = y - 6 * wi, dj = x - 6 * wj;
      s += win[(((size_t)(b * 100 + wi * 10 + wj)) * 128 + c) * 64 + di * 8 + dj];
    }
  float cnt = (float)((wi1 - wi0 + 1) * (wj1 - wj0 + 1));
  out[i] = s / cnt;
}

// ---------------------------------------------------------------------------
extern "C" void kernel_launch(void* const* d_in, const int* in_sizes, int n_in,
                              void* d_out, int out_size, void* d_ws, size_t ws_size,
                              hipStream_t stream) {
  const float* x      = (const float*)d_in[0];
  const float* sp     = (const float*)d_in[1];
  const float* w_pos  = (const float*)d_in[2];
  const float* b_pos  = (const float*)d_in[3];
  const float* w_q    = (const float*)d_in[4];
  const float* w_qdw  = (const float*)d_in[5];
  const float* w_kv   = (const float*)d_in[6];
  const float* w_kvdw = (const float*)d_in[7];
  const float* w_out  = (const float*)d_in[8];
  float* out = (float*)d_out;

  const size_t N_x   = (size_t)2 * 128 * HXW;  // 15,745,024 floats
  const size_t N_t   = (size_t)2 * 256 * HXW;  // 31,490,048 floats
  const size_t N_s   = (size_t)2 * 128 * HSW;  //    984,064 floats
  const size_t N_att = (size_t)2 * 100 * 128 * 64;

  float* ws = (float*)d_ws;
  // bf16 K (NHWC) + V (NCHW) exactly fill the xp region (aliased; xp dead first)
  unsigned short* kT = (unsigned short*)ws;           // 2*HXW*128 ushorts
  unsigned short* vv = kT + (size_t)2 * HXW * 128;    // 2*HXW*128 ushorts
  float* xp  = ws;
  float* tkv = ws + N_x;
  float* att = tkv;            // alias: tkv dead after dwconv_k/v
  float* rev = tkv + N_att;
  float* spp = ws + N_x + N_t;
  float* tq  = spp + N_s;
  unsigned short* qn = (unsigned short*)(tq + N_s);   // N_s ushorts
  (void)ws_size; (void)in_sizes; (void)n_in; (void)out_size;

  // 1. xp = x + dwconv3(x, w_pos, b_pos)
  {
    int total4 = (int)(N_x / 4);
    dwconv4_kernel<<<(total4 + 255) / 256, 256, 0, stream>>>(x, w_pos, b_pos, xp, 128, HX, HX, total4, 1);
  }
  // 2. spp = sp + dwconv3(sp, w_pos, b_pos)
  {
    int total = (int)N_s;
    dwconv3_kernel<<<(total + 255) / 256, 256, 0, stream>>>(sp, w_pos, b_pos, spp, 128, HS, HS, total, 1);
  }
  // 3. tq = conv1(spp, w_q)
  {
    int HW = HSW;
    dim3 grid((HW + 63) / 64, 2, 2);
    conv1_kernel<128><<<grid, 256, 0, stream>>>(spp, w_q, tq, HW);
  }
  // 4. qn = bf16_nhwc(dwconv3(tq, w_qdw)) * 32^-0.5
  {
    int total = (int)N_s;
    dwconv_q_kernel<<<(total + 255) / 256, 256, 0, stream>>>(tq, w_qdw, qn, total);
  }
  // 5. tkv = conv1(xp, w_kv)   (O=256)
  {
    int HW = HXW;
    dim3 grid((HW + 63) / 64, 4, 2);
    conv1_kernel<256><<<grid, 256, 0, stream>>>(xp, w_kv, tkv, HW);
  }
  // 6a. kT = bf16_nhwc(dwconv3(tkv[K half]))  (strip blocks, coalesced I/O)
  {
    dim3 grid(4, 248, 2);
    dwconv_k_kernel<<<grid, 256, 0, stream>>>(tkv, w_kvdw, kT);
  }
  // 6b. vv = bf16_nchw(dwconv3(tkv[V half]))
  {
    int total4 = (int)(2 * 128 * HXW / 4);
    dwconv_v_kernel<<<(total4 + 255) / 256, 256, 0, stream>>>(tkv, w_kvdw, vv, total4);
  }
  // 7. attention -> att (2,100,128,64)   (att aliases tkv; tkv dead)
  {
    dim3 grid(100, 2, 2);
    attn_mfma_kernel<<<grid, 512, 0, stream>>>(qn, kT, vv, att);
  }
  // 8. rev = reverse(att)
  {
    int total = (int)N_s;
    reverse_kernel<<<(total + 255) / 256, 256, 0, stream>>>(att, rev);
  }
  // 9. out = conv1(rev, w_out)
  {
    int HW = HSW;
    dim3 grid((HW + 63) / 64, 2, 2);
    conv1_kernel<128><<<grid, 256, 0, stream>>>(rev, w_out, out, HW);
  }
}

// Round 6
// 585.352 us; speedup vs baseline: 1.0358x; 1.0358x over previous
//
#include <hip/hip_runtime.h>
#include <cstdint>

#define HS 62
#define HX 248
#define HXW (HX * HX)  // 61504
#define HSW (HS * HS)  // 3844

typedef __attribute__((ext_vector_type(8))) short bf16x8;
typedef __attribute__((ext_vector_type(4))) float f32x4;

static __device__ __forceinline__ unsigned short f2bf(float f) {
  uint32_t u = __builtin_bit_cast(uint32_t, f);
  u += 0x7fff + ((u >> 16) & 1);  // RNE
  return (unsigned short)(u >> 16);
}

// ---------------------------------------------------------------------------
// Depthwise 3x3 scalar (62x62 tensors), fp32 out, bias+residual.
// ---------------------------------------------------------------------------
__global__ void dwconv3_kernel(const float* __restrict__ x, const float* __restrict__ w,
                               const float* __restrict__ bias, float* __restrict__ y,
                               int C, int H, int W, int total, int residual) {
  int i = blockIdx.x * 256 + threadIdx.x;
  if (i >= total) return;
  int wx = i % W;
  int t = i / W;
  int hy = t % H;
  int bc = t / H;
  int c = bc % C;
  const float* xb = x + (size_t)bc * H * W;
  const float* wc = w + c * 9;
  float s = bias ? bias[c] : 0.0f;
  for (int di = -1; di <= 1; di++) {
    int h2 = hy + di;
    if (h2 < 0 || h2 >= H) continue;
    for (int dj = -1; dj <= 1; dj++) {
      int w2 = wx + dj;
      if (w2 < 0 || w2 >= W) continue;
      s += xb[(size_t)h2 * W + w2] * wc[(di + 1) * 3 + (dj + 1)];
    }
  }
  if (residual) s += xb[(size_t)hy * W + wx];
  y[i] = s;
}

// ---------------------------------------------------------------------------
// Depthwise 3x3 vectorized fp32 (x -> xp), 4 pixels/thread, W%4==0.
// ---------------------------------------------------------------------------
__global__ void dwconv4_kernel(const float* __restrict__ x, const float* __restrict__ w,
                               const float* __restrict__ bias, float* __restrict__ y,
                               int C, int H, int W, int total4, int residual) {
  int i = blockIdx.x * 256 + threadIdx.x;
  if (i >= total4) return;
  int W4 = W >> 2;
  int wq = (i % W4) * 4;
  int t = i / W4;
  int hy = t % H;
  int bc = t / H;
  int c = bc % C;
  const float* xb = x + (size_t)bc * H * W;
  const float* wc = w + c * 9;
  float bv = bias ? bias[c] : 0.0f;
  float s0 = bv, s1 = bv, s2 = bv, s3 = bv;
  for (int di = -1; di <= 1; di++) {
    int h2 = hy + di;
    if (h2 < 0 || h2 >= H) continue;
    const float* row = xb + (size_t)h2 * W + wq;
    float4 cv = *(const float4*)row;
    float lf = (wq > 0) ? row[-1] : 0.0f;
    float rt = (wq + 4 < W) ? row[4] : 0.0f;
    float w0 = wc[(di + 1) * 3 + 0];
    float w1 = wc[(di + 1) * 3 + 1];
    float w2 = wc[(di + 1) * 3 + 2];
    s0 += w0 * lf   + w1 * cv.x + w2 * cv.y;
    s1 += w0 * cv.x + w1 * cv.y + w2 * cv.z;
    s2 += w0 * cv.y + w1 * cv.z + w2 * cv.w;
    s3 += w0 * cv.z + w1 * cv.w + w2 * rt;
  }
  if (residual) {
    float4 cc = *(const float4*)(xb + (size_t)hy * W + wq);
    s0 += cc.x; s1 += cc.y; s2 += cc.z; s3 += cc.w;
  }
  *(float4*)(y + (size_t)bc * H * W + (size_t)hy * W + wq) = make_float4(s0, s1, s2, s3);
}

// ---------------------------------------------------------------------------
// Depthwise 3x3 q path: fp32 NCHW in -> bf16 NHWC out, pre-scaled by 32^-0.5.
// ---------------------------------------------------------------------------
__global__ void dwconv_q_kernel(const float* __restrict__ x, const float* __restrict__ w,
                                unsigned short* __restrict__ qn, int total) {
  int i = blockIdx.x * 256 + threadIdx.x;
  if (i >= total) return;
  int wx = i % HS;
  int t = i / HS;
  int hy = t % HS;
  int bc = t / HS;
  int c = bc & 127;
  int b = bc >> 7;
  const float* xb = x + (size_t)bc * HSW;
  const float* wc = w + c * 9;
  float s = 0.0f;
  for (int di = -1; di <= 1; di++) {
    int h2 = hy + di;
    if (h2 < 0 || h2 >= HS) continue;
    for (int dj = -1; dj <= 1; dj++) {
      int w2 = wx + dj;
      if (w2 < 0 || w2 >= HS) continue;
      s += xb[(size_t)h2 * HS + w2] * wc[(di + 1) * 3 + (dj + 1)];
    }
  }
  qn[((size_t)(b * HSW + hy * HS + wx)) * 128 + c] = f2bf(s * 0.17677669529663688f);
}

// ---------------------------------------------------------------------------
// Depthwise 3x3 K path: fp32 NCHW (K half of 256ch) -> bf16 NHWC.
// Block = (32-px strip, group of 4 rows, b): multi-row so the 3-row window is
// served by this block's own L1/L2 (row refetch 1.5x instead of 3x).
// LDS [px][ch] transpose (double-buffered), coalesced 8 KB NHWC store/row.
// Grid (8, 62, 2), 256 thr = 128 ch x 2 px-halves.
// ---------------------------------------------------------------------------
__global__ __launch_bounds__(256) void dwconv_k_kernel(const float* __restrict__ x,
                                                       const float* __restrict__ w,
                                                       unsigned short* __restrict__ kT) {
  int strip = blockIdx.x;                 // 0..7
  int x0 = (strip == 7) ? 216 : strip * 32;
  int g = blockIdx.y;                     // row group (4 rows)
  int b = blockIdx.z;
  int c = threadIdx.x & 127;
  int half = threadIdx.x >> 7;            // 0..1 (16 px each)
  int px0 = x0 + half * 16;
  const float* xb = x + ((size_t)(b * 256 + c)) * HXW;
  const float* wc = w + c * 9;
  float w00 = wc[0], w01 = wc[1], w02 = wc[2];
  float w10 = wc[3], w11 = wc[4], w12 = wc[5];
  float w20 = wc[6], w21 = wc[7], w22 = wc[8];
  __shared__ unsigned short t[2][32 * 128];  // [px][ch], double-buffered (16 KB)
  const float4 z4 = make_float4(0.f, 0.f, 0.f, 0.f);
#pragma unroll 1
  for (int r = 0; r < 4; r++) {
    int hy = g * 4 + r;
    const float* r0 = xb + (size_t)(hy - 1) * HX;
    const float* r1 = xb + (size_t)hy * HX;
    const float* r2 = xb + (size_t)(hy + 1) * HX;
    bool v0 = hy > 0, v2 = hy < HX - 1;
    float lf0 = (px0 > 0 && v0) ? r0[px0 - 1] : 0.0f;
    float lf1 = (px0 > 0)       ? r1[px0 - 1] : 0.0f;
    float lf2 = (px0 > 0 && v2) ? r2[px0 - 1] : 0.0f;
    unsigned short* tb = t[r & 1];
#pragma unroll
    for (int pg = 0; pg < 4; pg++) {
      int wq = px0 + pg * 4;
      float4 c0 = v0 ? *(const float4*)(r0 + wq) : z4;
      float4 c1 = *(const float4*)(r1 + wq);
      float4 c2 = v2 ? *(const float4*)(r2 + wq) : z4;
      bool vr = (wq + 4) < HX;
      float rt0 = (vr && v0) ? r0[wq + 4] : 0.0f;
      float rt1 = vr          ? r1[wq + 4] : 0.0f;
      float rt2 = (vr && v2) ? r2[wq + 4] : 0.0f;
      float s0 = w00*lf0  + w01*c0.x + w02*c0.y + w10*lf1  + w11*c1.x + w12*c1.y + w20*lf2  + w21*c2.x + w22*c2.y;
      float s1 = w00*c0.x + w01*c0.y + w02*c0.z + w10*c1.x + w11*c1.y + w12*c1.z + w20*c2.x + w21*c2.y + w22*c2.z;
      float s2 = w00*c0.y + w01*c0.z + w02*c0.w + w10*c1.y + w11*c1.z + w12*c1.w + w20*c2.y + w21*c2.z + w22*c2.w;
      float s3 = w00*c0.z + w01*c0.w + w02*rt0  + w10*c1.z + w11*c1.w + w12*rt1  + w20*c2.z + w21*c2.w + w22*rt2;
      int p = half * 16 + pg * 4;
      tb[(p + 0) * 128 + c] = f2bf(s0);
      tb[(p + 1) * 128 + c] = f2bf(s1);
      tb[(p + 2) * 128 + c] = f2bf(s2);
      tb[(p + 3) * 128 + c] = f2bf(s3);
      lf0 = c0.w; lf1 = c1.w; lf2 = c2.w;
    }
    __syncthreads();
    const uint4* ts = (const uint4*)tb;
    uint4* td = (uint4*)(kT + ((size_t)(b * HXW) + (size_t)hy * HX + x0) * 128);
    td[threadIdx.x] = ts[threadIdx.x];
    td[256 + threadIdx.x] = ts[256 + threadIdx.x];
  }
}

// ---------------------------------------------------------------------------
// Depthwise 3x3 V path: fp32 NCHW (V half of 256ch) -> bf16 NCHW (coalesced).
// ---------------------------------------------------------------------------
__global__ void dwconv_v_kernel(const float* __restrict__ x, const float* __restrict__ w,
                                unsigned short* __restrict__ v, int total4) {
  int i = blockIdx.x * 256 + threadIdx.x;
  if (i >= total4) return;
  int W4 = HX >> 2;
  int wq = (i % W4) * 4;
  int t = i / W4;
  int hy = t % HX;
  int bc = t / HX;             // b*128 + c
  int c = bc & 127;
  int b = bc >> 7;
  const float* xb = x + ((size_t)(b * 256 + 128 + c)) * HXW;
  const float* wc = w + (128 + c) * 9;
  float s0 = 0, s1 = 0, s2 = 0, s3 = 0;
  for (int di = -1; di <= 1; di++) {
    int h2 = hy + di;
    if (h2 < 0 || h2 >= HX) continue;
    const float* row = xb + (size_t)h2 * HX + wq;
    float4 cv = *(const float4*)row;
    float lf = (wq > 0) ? row[-1] : 0.0f;
    float rt = (wq + 4 < HX) ? row[4] : 0.0f;
    float w0 = wc[(di + 1) * 3 + 0];
    float w1 = wc[(di + 1) * 3 + 1];
    float w2 = wc[(di + 1) * 3 + 2];
    s0 += w0 * lf   + w1 * cv.x + w2 * cv.y;
    s1 += w0 * cv.x + w1 * cv.y + w2 * cv.z;
    s2 += w0 * cv.y + w1 * cv.z + w2 * cv.w;
    s3 += w0 * cv.z + w1 * cv.w + w2 * rt;
  }
  uint2 d;
  d.x = (uint32_t)f2bf(s0) | ((uint32_t)f2bf(s1) << 16);
  d.y = (uint32_t)f2bf(s2) | ((uint32_t)f2bf(s3) << 16);
  *(uint2*)(v + (size_t)bc * HXW + (size_t)hy * HX + wq) = d;
}

// ---------------------------------------------------------------------------
// 1x1 conv tiled SGEMM (fp32).
// ---------------------------------------------------------------------------
template <int O>
__global__ __launch_bounds__(256) void conv1_kernel(const float* __restrict__ x,
                                                    const float* __restrict__ w,
                                                    float* __restrict__ y, int HW) {
  constexpr int K = 128;
  constexpr int BK = 32;
  __shared__ __align__(16) float ws_s[BK][64];
  __shared__ __align__(16) float xs_s[BK][64];
  int b = blockIdx.z;
  int o0 = blockIdx.y * 64;
  int p0 = blockIdx.x * 64;
  const float* xb = x + (size_t)b * K * HW;
  int tx = threadIdx.x & 15;
  int ty = threadIdx.x >> 4;
  float acc[4][4] = {};
  int lo = threadIdx.x >> 2;
  int lk = (threadIdx.x & 3) * 8;
  int lc = threadIdx.x >> 3;
  int lp = (threadIdx.x & 7) * 8;

  for (int k0 = 0; k0 < K; k0 += BK) {
    __syncthreads();
    {
      const float* wp = w + (size_t)(o0 + lo) * K + k0 + lk;
      float4 a = *(const float4*)wp;
      float4 bq = *(const float4*)(wp + 4);
      ws_s[lk + 0][lo] = a.x;  ws_s[lk + 1][lo] = a.y;
      ws_s[lk + 2][lo] = a.z;  ws_s[lk + 3][lo] = a.w;
      ws_s[lk + 4][lo] = bq.x; ws_s[lk + 5][lo] = bq.y;
      ws_s[lk + 6][lo] = bq.z; ws_s[lk + 7][lo] = bq.w;
    }
    {
      int p = p0 + lp;
      const float* xp = xb + (size_t)(k0 + lc) * HW;
      float4 a, bq;
      if (p + 7 < HW) {
        a = *(const float4*)(xp + p);
        bq = *(const float4*)(xp + p + 4);
      } else {
        float tv[8];
#pragma unroll
        for (int j = 0; j < 8; j++) tv[j] = (p + j < HW) ? xp[p + j] : 0.0f;
        a = make_float4(tv[0], tv[1], tv[2], tv[3]);
        bq = make_float4(tv[4], tv[5], tv[6], tv[7]);
      }
      *(float4*)&xs_s[lc][lp] = a;
      *(float4*)&xs_s[lc][lp + 4] = bq;
    }
    __syncthreads();
#pragma unroll
    for (int k = 0; k < BK; k++) {
      float4 wv = *(const float4*)&ws_s[k][ty * 4];
      float4 xv = *(const float4*)&xs_s[k][tx * 4];
      acc[0][0] += wv.x * xv.x; acc[0][1] += wv.x * xv.y; acc[0][2] += wv.x * xv.z; acc[0][3] += wv.x * xv.w;
      acc[1][0] += wv.y * xv.x; acc[1][1] += wv.y * xv.y; acc[1][2] += wv.y * xv.z; acc[1][3] += wv.y * xv.w;
      acc[2][0] += wv.z * xv.x; acc[2][1] += wv.z * xv.y; acc[2][2] += wv.z * xv.z; acc[2][3] += wv.z * xv.w;
      acc[3][0] += wv.w * xv.x; acc[3][1] += wv.w * xv.y; acc[3][2] += wv.w * xv.z; acc[3][3] += wv.w * xv.w;
    }
  }
  int p = p0 + tx * 4;
  float* yb = y + (size_t)b * O * HW + (size_t)(o0 + ty * 4) * HW;
#pragma unroll
  for (int j = 0; j < 4; j++) {
    float* yr = yb + (size_t)j * HW + p;
    if (p + 3 < HW) {
      *(float4*)yr = make_float4(acc[j][0], acc[j][1], acc[j][2], acc[j][3]);
    } else {
#pragma unroll
      for (int e = 0; e < 4; e++) if (p + e < HW) yr[e] = acc[j][e];
    }
  }
}

// ---------------------------------------------------------------------------
// MFMA windowed attention, head-pair blocks. 512 thr = 8 waves:
//   wave = (oct<<1)|hd : head h = hp*2+hd, key rows oct*8..oct*8+7.
// No max-tracking (scores tiny by construction): p = exp(s), plain sums.
// Prefetch buffers are NAMED variables (A/B) with the row loop unrolled x2 —
// runtime-indexed buffer arrays spilled to scratch (round-4/5 bug: 106 MB
// scratch WRITE_SIZE, VGPR_Count 80).
// ---------------------------------------------------------------------------
__global__ __launch_bounds__(512) void attn_mfma_kernel(
    const unsigned short* __restrict__ qn,   // (2,62,62,128) bf16, pre-scaled
    const unsigned short* __restrict__ kT,   // (2,248,248,128) bf16 NHWC
    const unsigned short* __restrict__ vp,   // (2,128,248,248) bf16 NCHW
    float* __restrict__ o) {
  int n = blockIdx.x, hp = blockIdx.y, b = blockIdx.z;
  int wi = n / 10, wj = n % 10;
  int wave = threadIdx.x >> 6;
  int hd = wave & 1, oct = wave >> 1;
  int h = hp * 2 + hd;
  int lane = threadIdx.x & 63;
  int quad = lane >> 4;
  int l15 = lane & 15;
  int y0 = 24 * wi, x0 = 24 * wj;

  __shared__ __align__(16) unsigned short lds[20480];  // 40,960 B
  unsigned short* Pw = lds + wave * 2560;              // [q][40keys] 5KB/wave

  // Q B-fragments for this head (held in registers)
  bf16x8 QB[4];
#pragma unroll
  for (int nt = 0; nt < 4; nt++) {
    int qq = nt * 16 + l15;
    int qy = 6 * wi + (qq >> 3), qx = 6 * wj + (qq & 7);
    QB[nt] = __builtin_bit_cast(bf16x8,
        *(const uint4*)(qn + ((size_t)(b * HSW + qy * HS + qx)) * 128 + h * 32 + quad * 8));
  }

  f32x4 Oacc[2][4];
#pragma unroll
  for (int a = 0; a < 2; a++)
#pragma unroll
    for (int c = 0; c < 4; c++) Oacc[a][c] = f32x4{0.f, 0.f, 0.f, 0.f};
  float lsum[4] = {0.f, 0.f, 0.f, 0.f};

  const unsigned short* kb = kT + (size_t)b * HXW * 128 + h * 32;
  const unsigned short* vb = vp + ((size_t)(b * 128 + h * 32)) * HXW;
  const f32x4 zf = {0.f, 0.f, 0.f, 0.f};

#define LOADROW(r, K0, K1, V0, V1)                                              \
  {                                                                             \
    int y = y0 + (r);                                                           \
    const unsigned short* krow = kb + ((size_t)(y * HX + x0)) * 128;            \
    K0 = *(const uint4*)(krow + (size_t)l15 * 128 + quad * 8);                  \
    K1 = *(const uint4*)(krow + (size_t)(16 + l15) * 128 + quad * 8);           \
    const unsigned short* vrow = vb + (size_t)y * HX + x0 + quad * 8;           \
    V0 = *(const uint4*)(vrow + (size_t)l15 * HXW);                             \
    V1 = *(const uint4*)(vrow + (size_t)(16 + l15) * HXW);                      \
  }

  auto compute = [&](uint4 k0, uint4 k1, uint4 v0, uint4 v1) {
    bf16x8 KA0 = __builtin_bit_cast(bf16x8, k0);
    bf16x8 KA1 = __builtin_bit_cast(bf16x8, k1);
    bf16x8 VA0 = __builtin_bit_cast(bf16x8, v0);
    bf16x8 VA1 = __builtin_bit_cast(bf16x8, v1);
    f32x4 S[2][4];
#pragma unroll
    for (int nt = 0; nt < 4; nt++) {
      S[0][nt] = __builtin_amdgcn_mfma_f32_16x16x32_bf16(KA0, QB[nt], zf, 0, 0, 0);
      S[1][nt] = __builtin_amdgcn_mfma_f32_16x16x32_bf16(KA1, QB[nt], zf, 0, 0, 0);
    }
#pragma unroll
    for (int nt = 0; nt < 4; nt++) {
      float pv[2][4];
      float cs = 0.f;
#pragma unroll
      for (int mt = 0; mt < 2; mt++)
#pragma unroll
        for (int r = 0; r < 4; r++) {
          pv[mt][r] = __expf(S[mt][nt][r]);
          cs += pv[mt][r];
        }
      lsum[nt] += cs;
#pragma unroll
      for (int mt = 0; mt < 2; mt++) {
        uint2 d;
        d.x = (uint32_t)f2bf(pv[mt][0]) | ((uint32_t)f2bf(pv[mt][1]) << 16);
        d.y = (uint32_t)f2bf(pv[mt][2]) | ((uint32_t)f2bf(pv[mt][3]) << 16);
        *(uint2*)(Pw + (16 * nt + l15) * 40 + 16 * mt + quad * 4) = d;
      }
    }
#pragma unroll
    for (int nt = 0; nt < 4; nt++) {
      bf16x8 PB = __builtin_bit_cast(bf16x8, *(const uint4*)(Pw + (16 * nt + l15) * 40 + quad * 8));
      Oacc[0][nt] = __builtin_amdgcn_mfma_f32_16x16x32_bf16(VA0, PB, Oacc[0][nt], 0, 0, 0);
      Oacc[1][nt] = __builtin_amdgcn_mfma_f32_16x16x32_bf16(VA1, PB, Oacc[1][nt], 0, 0, 0);
    }
  };

  int rbase = oct * 8;
  uint4 kA0, kA1, vA0, vA1, kB0, kB1, vB0, vB1;
  LOADROW(rbase + 0, kA0, kA1, vA0, vA1);
  LOADROW(rbase + 1, kB0, kB1, vB0, vB1);
#pragma unroll 1
  for (int r = 0; r < 8; r += 2) {
    if (r + 2 < 8) {
      compute(kA0, kA1, vA0, vA1);
      LOADROW(rbase + r + 2, kA0, kA1, vA0, vA1);
      compute(kB0, kB1, vB0, vB1);
      LOADROW(rbase + r + 3, kB0, kB1, vB0, vB1);
    } else {
      compute(kA0, kA1, vA0, vA1);
      compute(kB0, kB1, vB0, vB1);
    }
  }
#undef LOADROW

  // full row-sum of l over the quad rows (keys) of this wave
#pragma unroll
  for (int nt = 0; nt < 4; nt++) {
    lsum[nt] += __shfl_xor(lsum[nt], 16, 64);
    lsum[nt] += __shfl_xor(lsum[nt], 32, 64);
  }

  // ---- two-phase merge: sum (acc, l) over the 4 octs of each head ----
  float* mO = (float*)lds;                 // [oct][32ch][64q]  32 KB
  float* mL = (float*)(lds + 16384);       // [oct][64q]
#pragma unroll 1
  for (int p = 0; p < 2; p++) {
    __syncthreads();
    if (hd == p) {
#pragma unroll
      for (int mt = 0; mt < 2; mt++)
#pragma unroll
        for (int nt = 0; nt < 4; nt++)
#pragma unroll
          for (int r = 0; r < 4; r++)
            mO[oct * 2048 + (16 * mt + quad * 4 + r) * 64 + 16 * nt + l15] = Oacc[mt][nt][r];
      if (quad == 0) {
#pragma unroll
        for (int nt = 0; nt < 4; nt++) mL[oct * 64 + nt * 16 + l15] = lsum[nt];
      }
    }
    __syncthreads();
    {
      int q = threadIdx.x & 63;
      int cg = threadIdx.x >> 6;  // 0..7 -> 4 ch each
      float inv = 1.0f / (mL[q] + mL[64 + q] + mL[128 + q] + mL[192 + q]);
      float* ob = o + (((size_t)(b * 100 + n)) * 128 + (hp * 2 + p) * 32 + cg * 4) * 64 + q;
#pragma unroll
      for (int e = 0; e < 4; e++) {
        int ch = cg * 4 + e;
        float s = mO[ch * 64 + q] + mO[2048 + ch * 64 + q] +
                  mO[4096 + ch * 64 + q] + mO[6144 + ch * 64 + q];
        ob[(size_t)e * 64] = s * inv;
      }
    }
  }
}

// ---------------------------------------------------------------------------
// Reverse: scatter-average overlapping 8x8 windows (step 6) into (2,128,62,62)
// ---------------------------------------------------------------------------
__global__ void reverse_kernel(const float* __restrict__ win, float* __restrict__ out) {
  int i = blockIdx.x * 256 + threadIdx.x;
  const int total = 2 * 128 * HSW;
  if (i >= total) return;
  int x = i % HS;
  int t = i / HS;
  int y = t % HS;
  t /= HS;
  int c = t % 128;
  int b = t / 128;
  int wi0 = (y >= 7) ? (y - 2) / 6 : 0;
  int wi1 = min(9, y / 6);
  int wj0 = (x >= 7) ? (x - 2) / 6 : 0;
  int wj1 = min(9, x / 6);
  float s = 0.0f;
  for (int wi = wi0; wi <= wi1; wi++)
    for (int wj = wj0; wj <= wj1; wj++) {
      int di = y - 6 * wi, dj = x - 6 * wj;
      s += win[(((size_t)(b * 100 + wi * 10 + wj)) * 128 + c) * 64 + di * 8 + dj];
    }
  float cnt = (float)((wi1 - wi0 + 1) * (wj1 - wj0 + 1));
  out[i] = s / cnt;
}

// ---------------------------------------------------------------------------
extern "C" void kernel_launch(void* const* d_in, const int* in_sizes, int n_in,
                              void* d_out, int out_size, void* d_ws, size_t ws_size,
                              hipStream_t stream) {
  const float* x      = (const float*)d_in[0];
  const float* sp     = (const float*)d_in[1];
  const float* w_pos  = (const float*)d_in[2];
  const float* b_pos  = (const float*)d_in[3];
  const float* w_q    = (const float*)d_in[4];
  const float* w_qdw  = (const float*)d_in[5];
  const float* w_kv   = (const float*)d_in[6];
  const float* w_kvdw = (const float*)d_in[7];
  const float* w_out  = (const float*)d_in[8];
  float* out = (float*)d_out;

  const size_t N_x   = (size_t)2 * 128 * HXW;  // 15,745,024 floats
  const size_t N_t   = (size_t)2 * 256 * HXW;  // 31,490,048 floats
  const size_t N_s   = (size_t)2 * 128 * HSW;  //    984,064 floats
  const size_t N_att = (size_t)2 * 100 * 128 * 64;

  float* ws = (float*)d_ws;
  // bf16 K (NHWC) + V (NCHW) exactly fill the xp region (aliased; xp dead first)
  unsigned short* kT = (unsigned short*)ws;           // 2*HXW*128 ushorts
  unsigned short* vv = kT + (size_t)2 * HXW * 128;    // 2*HXW*128 ushorts
  float* xp  = ws;
  float* tkv = ws + N_x;
  float* att = tkv;            // alias: tkv dead after dwconv_k/v
  float* rev = tkv + N_att;
  float* spp = ws + N_x + N_t;
  float* tq  = spp + N_s;
  unsigned short* qn = (unsigned short*)(tq + N_s);   // N_s ushorts
  (void)ws_size; (void)in_sizes; (void)n_in; (void)out_size;

  // 1. xp = x + dwconv3(x, w_pos, b_pos)
  {
    int total4 = (int)(N_x / 4);
    dwconv4_kernel<<<(total4 + 255) / 256, 256, 0, stream>>>(x, w_pos, b_pos, xp, 128, HX, HX, total4, 1);
  }
  // 2. spp = sp + dwconv3(sp, w_pos, b_pos)
  {
    int total = (int)N_s;
    dwconv3_kernel<<<(total + 255) / 256, 256, 0, stream>>>(sp, w_pos, b_pos, spp, 128, HS, HS, total, 1);
  }
  // 3. tq = conv1(spp, w_q)
  {
    int HW = HSW;
    dim3 grid((HW + 63) / 64, 2, 2);
    conv1_kernel<128><<<grid, 256, 0, stream>>>(spp, w_q, tq, HW);
  }
  // 4. qn = bf16_nhwc(dwconv3(tq, w_qdw)) * 32^-0.5
  {
    int total = (int)N_s;
    dwconv_q_kernel<<<(total + 255) / 256, 256, 0, stream>>>(tq, w_qdw, qn, total);
  }
  // 5. tkv = conv1(xp, w_kv)   (O=256)
  {
    int HW = HXW;
    dim3 grid((HW + 63) / 64, 4, 2);
    conv1_kernel<256><<<grid, 256, 0, stream>>>(xp, w_kv, tkv, HW);
  }
  // 6a. kT = bf16_nhwc(dwconv3(tkv[K half]))  (multi-row blocks, coalesced I/O)
  {
    dim3 grid(8, 62, 2);
    dwconv_k_kernel<<<grid, 256, 0, stream>>>(tkv, w_kvdw, kT);
  }
  // 6b. vv = bf16_nchw(dwconv3(tkv[V half]))
  {
    int total4 = (int)(2 * 128 * HXW / 4);
    dwconv_v_kernel<<<(total4 + 255) / 256, 256, 0, stream>>>(tkv, w_kvdw, vv, total4);
  }
  // 7. attention -> att (2,100,128,64)   (att aliases tkv; tkv dead)
  {
    dim3 grid(100, 2, 2);
    attn_mfma_kernel<<<grid, 512, 0, stream>>>(qn, kT, vv, att);
  }
  // 8. rev = reverse(att)
  {
    int total = (int)N_s;
    reverse_kernel<<<(total + 255) / 256, 256, 0, stream>>>(att, rev);
  }
  // 9. out = conv1(rev, w_out)
  {
    int HW = HSW;
    dim3 grid((HW + 63) / 64, 2, 2);
    conv1_kernel<128><<<grid, 256, 0, stream>>>(rev, w_out, out, HW);
  }
}

// Round 7
// 522.144 us; speedup vs baseline: 1.1612x; 1.1211x over previous
//
#include <hip/hip_runtime.h>
#include <cstdint>

#define HS 62
#define HX 248
#define HXW (HX * HX)  // 61504
#define HSW (HS * HS)  // 3844

typedef __attribute__((ext_vector_type(8))) short bf16x8;
typedef __attribute__((ext_vector_type(4))) float f32x4;

static __device__ __forceinline__ unsigned short f2bf(float f) {
  uint32_t u = __builtin_bit_cast(uint32_t, f);
  u += 0x7fff + ((u >> 16) & 1);  // RNE
  return (unsigned short)(u >> 16);
}
static __device__ __forceinline__ float bf2f(unsigned short u) {
  uint32_t x = (uint32_t)u << 16;
  return __builtin_bit_cast(float, x);
}

// ---------------------------------------------------------------------------
// Depthwise 3x3 scalar (62x62 tensors), fp32 out, bias+residual.
// ---------------------------------------------------------------------------
__global__ void dwconv3_kernel(const float* __restrict__ x, const float* __restrict__ w,
                               const float* __restrict__ bias, float* __restrict__ y,
                               int C, int H, int W, int total, int residual) {
  int i = blockIdx.x * 256 + threadIdx.x;
  if (i >= total) return;
  int wx = i % W;
  int t = i / W;
  int hy = t % H;
  int bc = t / H;
  int c = bc % C;
  const float* xb = x + (size_t)bc * H * W;
  const float* wc = w + c * 9;
  float s = bias ? bias[c] : 0.0f;
  for (int di = -1; di <= 1; di++) {
    int h2 = hy + di;
    if (h2 < 0 || h2 >= H) continue;
    for (int dj = -1; dj <= 1; dj++) {
      int w2 = wx + dj;
      if (w2 < 0 || w2 >= W) continue;
      s += xb[(size_t)h2 * W + w2] * wc[(di + 1) * 3 + (dj + 1)];
    }
  }
  if (residual) s += xb[(size_t)hy * W + wx];
  y[i] = s;
}

// ---------------------------------------------------------------------------
// Depthwise 3x3 vectorized fp32 (x -> xp), 4 pixels/thread, W%4==0.
// ---------------------------------------------------------------------------
__global__ void dwconv4_kernel(const float* __restrict__ x, const float* __restrict__ w,
                               const float* __restrict__ bias, float* __restrict__ y,
                               int C, int H, int W, int total4, int residual) {
  int i = blockIdx.x * 256 + threadIdx.x;
  if (i >= total4) return;
  int W4 = W >> 2;
  int wq = (i % W4) * 4;
  int t = i / W4;
  int hy = t % H;
  int bc = t / H;
  int c = bc % C;
  const float* xb = x + (size_t)bc * H * W;
  const float* wc = w + c * 9;
  float bv = bias ? bias[c] : 0.0f;
  float s0 = bv, s1 = bv, s2 = bv, s3 = bv;
  for (int di = -1; di <= 1; di++) {
    int h2 = hy + di;
    if (h2 < 0 || h2 >= H) continue;
    const float* row = xb + (size_t)h2 * W + wq;
    float4 cv = *(const float4*)row;
    float lf = (wq > 0) ? row[-1] : 0.0f;
    float rt = (wq + 4 < W) ? row[4] : 0.0f;
    float w0 = wc[(di + 1) * 3 + 0];
    float w1 = wc[(di + 1) * 3 + 1];
    float w2 = wc[(di + 1) * 3 + 2];
    s0 += w0 * lf   + w1 * cv.x + w2 * cv.y;
    s1 += w0 * cv.x + w1 * cv.y + w2 * cv.z;
    s2 += w0 * cv.y + w1 * cv.z + w2 * cv.w;
    s3 += w0 * cv.z + w1 * cv.w + w2 * rt;
  }
  if (residual) {
    float4 cc = *(const float4*)(xb + (size_t)hy * W + wq);
    s0 += cc.x; s1 += cc.y; s2 += cc.z; s3 += cc.w;
  }
  *(float4*)(y + (size_t)bc * H * W + (size_t)hy * W + wq) = make_float4(s0, s1, s2, s3);
}

// ---------------------------------------------------------------------------
// Depthwise 3x3 q path: fp32 NCHW in -> bf16 NHWC out, pre-scaled by 32^-0.5.
// ---------------------------------------------------------------------------
__global__ void dwconv_q_kernel(const float* __restrict__ x, const float* __restrict__ w,
                                unsigned short* __restrict__ qn, int total) {
  int i = blockIdx.x * 256 + threadIdx.x;
  if (i >= total) return;
  int wx = i % HS;
  int t = i / HS;
  int hy = t % HS;
  int bc = t / HS;
  int c = bc & 127;
  int b = bc >> 7;
  const float* xb = x + (size_t)bc * HSW;
  const float* wc = w + c * 9;
  float s = 0.0f;
  for (int di = -1; di <= 1; di++) {
    int h2 = hy + di;
    if (h2 < 0 || h2 >= HS) continue;
    for (int dj = -1; dj <= 1; dj++) {
      int w2 = wx + dj;
      if (w2 < 0 || w2 >= HS) continue;
      s += xb[(size_t)h2 * HS + w2] * wc[(di + 1) * 3 + (dj + 1)];
    }
  }
  qn[((size_t)(b * HSW + hy * HS + wx)) * 128 + c] = f2bf(s * 0.17677669529663688f);
}

// ---------------------------------------------------------------------------
// 1x1 conv for the kv path: y[b][p][o] = sum_c xp[b][c][p] * w_kv[o][c],
// output bf16 NHWC (2, 61504, 256). Block: 32 px x all 256 out-ch.
// Thread = (ty: 8 out-ch, tx: 4 px) -> acc[8][4]. Writes 512 B/px coalesced.
// Grid (1922, 2).
// ---------------------------------------------------------------------------
__global__ __launch_bounds__(256) void conv1_kv_nhwc_kernel(const float* __restrict__ x,
                                                            const float* __restrict__ w,
                                                            unsigned short* __restrict__ y) {
  __shared__ __align__(16) float ws_s[16][256];
  __shared__ __align__(16) float xs_s[16][32];
  int b = blockIdx.y;
  int p0 = blockIdx.x * 32;
  const float* xb = x + (size_t)b * 128 * HXW;
  int ty = threadIdx.x >> 3;   // 0..31 -> o = ty*8
  int tx = threadIdx.x & 7;    // 0..7  -> px = tx*4
  float acc[8][4] = {};
  for (int k0 = 0; k0 < 128; k0 += 16) {
    __syncthreads();
    {  // weight tile: thread o loads 16 k values, store transposed [k][o]
      const float* wp = w + (size_t)threadIdx.x * 128 + k0;
      float4 a = *(const float4*)(wp);
      float4 bq = *(const float4*)(wp + 4);
      float4 cq = *(const float4*)(wp + 8);
      float4 dq = *(const float4*)(wp + 12);
      ws_s[0][threadIdx.x] = a.x;  ws_s[1][threadIdx.x] = a.y;
      ws_s[2][threadIdx.x] = a.z;  ws_s[3][threadIdx.x] = a.w;
      ws_s[4][threadIdx.x] = bq.x; ws_s[5][threadIdx.x] = bq.y;
      ws_s[6][threadIdx.x] = bq.z; ws_s[7][threadIdx.x] = bq.w;
      ws_s[8][threadIdx.x] = cq.x; ws_s[9][threadIdx.x] = cq.y;
      ws_s[10][threadIdx.x] = cq.z; ws_s[11][threadIdx.x] = cq.w;
      ws_s[12][threadIdx.x] = dq.x; ws_s[13][threadIdx.x] = dq.y;
      ws_s[14][threadIdx.x] = dq.z; ws_s[15][threadIdx.x] = dq.w;
    }
    {  // x tile [k][px]
      int k = threadIdx.x >> 4;            // 0..15
      int px = (threadIdx.x & 15) * 2;     // 0..30
      float2 v = *(const float2*)(xb + (size_t)(k0 + k) * HXW + p0 + px);
      xs_s[k][px] = v.x;
      xs_s[k][px + 1] = v.y;
    }
    __syncthreads();
#pragma unroll
    for (int k = 0; k < 16; k++) {
      float4 w0 = *(const float4*)&ws_s[k][ty * 8];
      float4 w1 = *(const float4*)&ws_s[k][ty * 8 + 4];
      float4 xv = *(const float4*)&xs_s[k][tx * 4];
      acc[0][0] += w0.x * xv.x; acc[0][1] += w0.x * xv.y; acc[0][2] += w0.x * xv.z; acc[0][3] += w0.x * xv.w;
      acc[1][0] += w0.y * xv.x; acc[1][1] += w0.y * xv.y; acc[1][2] += w0.y * xv.z; acc[1][3] += w0.y * xv.w;
      acc[2][0] += w0.z * xv.x; acc[2][1] += w0.z * xv.y; acc[2][2] += w0.z * xv.z; acc[2][3] += w0.z * xv.w;
      acc[3][0] += w0.w * xv.x; acc[3][1] += w0.w * xv.y; acc[3][2] += w0.w * xv.z; acc[3][3] += w0.w * xv.w;
      acc[4][0] += w1.x * xv.x; acc[4][1] += w1.x * xv.y; acc[4][2] += w1.x * xv.z; acc[4][3] += w1.x * xv.w;
      acc[5][0] += w1.y * xv.x; acc[5][1] += w1.y * xv.y; acc[5][2] += w1.y * xv.z; acc[5][3] += w1.y * xv.w;
      acc[6][0] += w1.z * xv.x; acc[6][1] += w1.z * xv.y; acc[6][2] += w1.z * xv.z; acc[6][3] += w1.z * xv.w;
      acc[7][0] += w1.w * xv.x; acc[7][1] += w1.w * xv.y; acc[7][2] += w1.w * xv.z; acc[7][3] += w1.w * xv.w;
    }
  }
#pragma unroll
  for (int e = 0; e < 4; e++) {
    int px = p0 + tx * 4 + e;
    uint4 d;
    d.x = (uint32_t)f2bf(acc[0][e]) | ((uint32_t)f2bf(acc[1][e]) << 16);
    d.y = (uint32_t)f2bf(acc[2][e]) | ((uint32_t)f2bf(acc[3][e]) << 16);
    d.z = (uint32_t)f2bf(acc[4][e]) | ((uint32_t)f2bf(acc[5][e]) << 16);
    d.w = (uint32_t)f2bf(acc[6][e]) | ((uint32_t)f2bf(acc[7][e]) << 16);
    *(uint4*)(y + ((size_t)b * HXW + px) * 256 + ty * 8) = d;
  }
}

// ---------------------------------------------------------------------------
// Fused depthwise 3x3 for K and V from bf16 NHWC tkv (2,61504,256).
//  K (ch 0..127)  -> bf16 NHWC kT, written directly (no transpose needed)
//  V (ch 128..255)-> bf16 NCHW vv, via 16 KB LDS [px][ch] transpose
// Block = (64-px strip, 4-row group, b); lane = channel within a pixel record
// (wave reads 128 B contiguous per (y,x) record). Register-rotate along x.
// Grid (4, 62, 2), 256 thr.
// ---------------------------------------------------------------------------
__global__ __launch_bounds__(256) void dwconv_kv_kernel(const unsigned short* __restrict__ tkv,
                                                        const float* __restrict__ w,
                                                        unsigned short* __restrict__ kT,
                                                        unsigned short* __restrict__ vv) {
  int strip = blockIdx.x;                      // 0..3
  int x0 = (strip == 3) ? 184 : strip * 64;
  int g = blockIdx.y;                          // 0..61
  int b = blockIdx.z;
  int c = threadIdx.x & 127;
  int half = threadIdx.x >> 7;                 // 0 = K, 1 = V
  int ch = half * 128 + c;
  const float* wc = w + ch * 9;
  float w00 = wc[0], w01 = wc[1], w02 = wc[2];
  float w10 = wc[3], w11 = wc[4], w12 = wc[5];
  float w20 = wc[6], w21 = wc[7], w22 = wc[8];
  const unsigned short* src = tkv + ((size_t)b * HXW) * 256 + ch;
  __shared__ unsigned short vt[64 * 128];      // [px][ch] for the V transpose

#pragma unroll 1
  for (int r = 0; r < 4; r++) {
    int hy = g * 4 + r;
    bool vtop = hy > 0, vbot = hy < HX - 1;
    const unsigned short* r0 = src + ((size_t)(hy - 1) * HX) * 256;
    const unsigned short* r1 = src + ((size_t)hy * HX) * 256;
    const unsigned short* r2 = src + ((size_t)(hy + 1) * HX) * 256;
    float a0, a1, a2, b0, b1, b2;
    if (x0 > 0) {
      a0 = vtop ? bf2f(r0[(size_t)(x0 - 1) * 256]) : 0.0f;
      a1 = bf2f(r1[(size_t)(x0 - 1) * 256]);
      a2 = vbot ? bf2f(r2[(size_t)(x0 - 1) * 256]) : 0.0f;
    } else { a0 = a1 = a2 = 0.0f; }
    b0 = vtop ? bf2f(r0[(size_t)x0 * 256]) : 0.0f;
    b1 = bf2f(r1[(size_t)x0 * 256]);
    b2 = vbot ? bf2f(r2[(size_t)x0 * 256]) : 0.0f;
#pragma unroll 1
    for (int px = 0; px < 64; px++) {
      int xc = x0 + px, xn = xc + 1;
      float n0, n1, n2;
      if (xn < HX) {
        n0 = vtop ? bf2f(r0[(size_t)xn * 256]) : 0.0f;
        n1 = bf2f(r1[(size_t)xn * 256]);
        n2 = vbot ? bf2f(r2[(size_t)xn * 256]) : 0.0f;
      } else { n0 = n1 = n2 = 0.0f; }
      float s = w00 * a0 + w01 * b0 + w02 * n0 +
                w10 * a1 + w11 * b1 + w12 * n1 +
                w20 * a2 + w21 * b2 + w22 * n2;
      unsigned short sb = f2bf(s);
      if (half == 0) {
        kT[((size_t)b * HXW + (size_t)hy * HX + xc) * 128 + c] = sb;
      } else {
        vt[px * 128 + c] = sb;
      }
      a0 = b0; a1 = b1; a2 = b2;
      b0 = n0; b1 = n1; b2 = n2;
    }
    __syncthreads();
    {  // cooperative NCHW store of the V row: thread -> (cv, 32-px half)
      int cv = threadIdx.x >> 1;
      int ph = (threadIdx.x & 1) * 32;
      unsigned short* dst = vv + ((size_t)(b * 128 + cv)) * HXW + (size_t)hy * HX + x0 + ph;
#pragma unroll
      for (int jj = 0; jj < 8; jj++) {
        uint2 d;
        d.x = (uint32_t)vt[(ph + jj * 4 + 0) * 128 + cv] |
              ((uint32_t)vt[(ph + jj * 4 + 1) * 128 + cv] << 16);
        d.y = (uint32_t)vt[(ph + jj * 4 + 2) * 128 + cv] |
              ((uint32_t)vt[(ph + jj * 4 + 3) * 128 + cv] << 16);
        *(uint2*)(dst + jj * 4) = d;
      }
    }
    __syncthreads();
  }
}

// ---------------------------------------------------------------------------
// 1x1 conv tiled SGEMM (fp32) — small tensors (q path, output projection).
// ---------------------------------------------------------------------------
template <int O>
__global__ __launch_bounds__(256) void conv1_kernel(const float* __restrict__ x,
                                                    const float* __restrict__ w,
                                                    float* __restrict__ y, int HW) {
  constexpr int K = 128;
  constexpr int BK = 32;
  __shared__ __align__(16) float ws_s[BK][64];
  __shared__ __align__(16) float xs_s[BK][64];
  int b = blockIdx.z;
  int o0 = blockIdx.y * 64;
  int p0 = blockIdx.x * 64;
  const float* xb = x + (size_t)b * K * HW;
  int tx = threadIdx.x & 15;
  int ty = threadIdx.x >> 4;
  float acc[4][4] = {};
  int lo = threadIdx.x >> 2;
  int lk = (threadIdx.x & 3) * 8;
  int lc = threadIdx.x >> 3;
  int lp = (threadIdx.x & 7) * 8;

  for (int k0 = 0; k0 < K; k0 += BK) {
    __syncthreads();
    {
      const float* wp = w + (size_t)(o0 + lo) * K + k0 + lk;
      float4 a = *(const float4*)wp;
      float4 bq = *(const float4*)(wp + 4);
      ws_s[lk + 0][lo] = a.x;  ws_s[lk + 1][lo] = a.y;
      ws_s[lk + 2][lo] = a.z;  ws_s[lk + 3][lo] = a.w;
      ws_s[lk + 4][lo] = bq.x; ws_s[lk + 5][lo] = bq.y;
      ws_s[lk + 6][lo] = bq.z; ws_s[lk + 7][lo] = bq.w;
    }
    {
      int p = p0 + lp;
      const float* xp = xb + (size_t)(k0 + lc) * HW;
      float4 a, bq;
      if (p + 7 < HW) {
        a = *(const float4*)(xp + p);
        bq = *(const float4*)(xp + p + 4);
      } else {
        float tv[8];
#pragma unroll
        for (int j = 0; j < 8; j++) tv[j] = (p + j < HW) ? xp[p + j] : 0.0f;
        a = make_float4(tv[0], tv[1], tv[2], tv[3]);
        bq = make_float4(tv[4], tv[5], tv[6], tv[7]);
      }
      *(float4*)&xs_s[lc][lp] = a;
      *(float4*)&xs_s[lc][lp + 4] = bq;
    }
    __syncthreads();
#pragma unroll
    for (int k = 0; k < BK; k++) {
      float4 wv = *(const float4*)&ws_s[k][ty * 4];
      float4 xv = *(const float4*)&xs_s[k][tx * 4];
      acc[0][0] += wv.x * xv.x; acc[0][1] += wv.x * xv.y; acc[0][2] += wv.x * xv.z; acc[0][3] += wv.x * xv.w;
      acc[1][0] += wv.y * xv.x; acc[1][1] += wv.y * xv.y; acc[1][2] += wv.y * xv.z; acc[1][3] += wv.y * xv.w;
      acc[2][0] += wv.z * xv.x; acc[2][1] += wv.z * xv.y; acc[2][2] += wv.z * xv.z; acc[2][3] += wv.z * xv.w;
      acc[3][0] += wv.w * xv.x; acc[3][1] += wv.w * xv.y; acc[3][2] += wv.w * xv.z; acc[3][3] += wv.w * xv.w;
    }
  }
  int p = p0 + tx * 4;
  float* yb = y + (size_t)b * O * HW + (size_t)(o0 + ty * 4) * HW;
#pragma unroll
  for (int j = 0; j < 4; j++) {
    float* yr = yb + (size_t)j * HW + p;
    if (p + 3 < HW) {
      *(float4*)yr = make_float4(acc[j][0], acc[j][1], acc[j][2], acc[j][3]);
    } else {
#pragma unroll
      for (int e = 0; e < 4; e++) if (p + e < HW) yr[e] = acc[j][e];
    }
  }
}

// ---------------------------------------------------------------------------
// MFMA windowed attention, head-pair blocks. 512 thr = 8 waves:
//   wave = (oct<<1)|hd : head h = hp*2+hd, key rows oct*8..oct*8+7.
// No max-tracking (scores tiny by construction): p = exp(s), plain sums.
// Named prefetch buffers + x2 unroll (runtime-indexed arrays spill).
// ---------------------------------------------------------------------------
__global__ __launch_bounds__(512) void attn_mfma_kernel(
    const unsigned short* __restrict__ qn,   // (2,62,62,128) bf16, pre-scaled
    const unsigned short* __restrict__ kT,   // (2,248,248,128) bf16 NHWC
    const unsigned short* __restrict__ vp,   // (2,128,248,248) bf16 NCHW
    float* __restrict__ o) {
  int n = blockIdx.x, hp = blockIdx.y, b = blockIdx.z;
  int wi = n / 10, wj = n % 10;
  int wave = threadIdx.x >> 6;
  int hd = wave & 1, oct = wave >> 1;
  int h = hp * 2 + hd;
  int lane = threadIdx.x & 63;
  int quad = lane >> 4;
  int l15 = lane & 15;
  int y0 = 24 * wi, x0 = 24 * wj;

  __shared__ __align__(16) unsigned short lds[20480];  // 40,960 B
  unsigned short* Pw = lds + wave * 2560;              // [q][40keys] 5KB/wave

  bf16x8 QB[4];
#pragma unroll
  for (int nt = 0; nt < 4; nt++) {
    int qq = nt * 16 + l15;
    int qy = 6 * wi + (qq >> 3), qx = 6 * wj + (qq & 7);
    QB[nt] = __builtin_bit_cast(bf16x8,
        *(const uint4*)(qn + ((size_t)(b * HSW + qy * HS + qx)) * 128 + h * 32 + quad * 8));
  }

  f32x4 Oacc[2][4];
#pragma unroll
  for (int a = 0; a < 2; a++)
#pragma unroll
    for (int c = 0; c < 4; c++) Oacc[a][c] = f32x4{0.f, 0.f, 0.f, 0.f};
  float lsum[4] = {0.f, 0.f, 0.f, 0.f};

  const unsigned short* kb = kT + (size_t)b * HXW * 128 + h * 32;
  const unsigned short* vb = vp + ((size_t)(b * 128 + h * 32)) * HXW;
  const f32x4 zf = {0.f, 0.f, 0.f, 0.f};

#define LOADROW(r, K0, K1, V0, V1)                                              \
  {                                                                             \
    int y = y0 + (r);                                                           \
    const unsigned short* krow = kb + ((size_t)(y * HX + x0)) * 128;            \
    K0 = *(const uint4*)(krow + (size_t)l15 * 128 + quad * 8);                  \
    K1 = *(const uint4*)(krow + (size_t)(16 + l15) * 128 + quad * 8);           \
    const unsigned short* vrow = vb + (size_t)y * HX + x0 + quad * 8;           \
    V0 = *(const uint4*)(vrow + (size_t)l15 * HXW);                             \
    V1 = *(const uint4*)(vrow + (size_t)(16 + l15) * HXW);                      \
  }

  auto compute = [&](uint4 k0, uint4 k1, uint4 v0, uint4 v1) {
    bf16x8 KA0 = __builtin_bit_cast(bf16x8, k0);
    bf16x8 KA1 = __builtin_bit_cast(bf16x8, k1);
    bf16x8 VA0 = __builtin_bit_cast(bf16x8, v0);
    bf16x8 VA1 = __builtin_bit_cast(bf16x8, v1);
    f32x4 S[2][4];
#pragma unroll
    for (int nt = 0; nt < 4; nt++) {
      S[0][nt] = __builtin_amdgcn_mfma_f32_16x16x32_bf16(KA0, QB[nt], zf, 0, 0, 0);
      S[1][nt] = __builtin_amdgcn_mfma_f32_16x16x32_bf16(KA1, QB[nt], zf, 0, 0, 0);
    }
#pragma unroll
    for (int nt = 0; nt < 4; nt++) {
      float pv[2][4];
      float cs = 0.f;
#pragma unroll
      for (int mt = 0; mt < 2; mt++)
#pragma unroll
        for (int r = 0; r < 4; r++) {
          pv[mt][r] = __expf(S[mt][nt][r]);
          cs += pv[mt][r];
        }
      lsum[nt] += cs;
#pragma unroll
      for (int mt = 0; mt < 2; mt++) {
        uint2 d;
        d.x = (uint32_t)f2bf(pv[mt][0]) | ((uint32_t)f2bf(pv[mt][1]) << 16);
        d.y = (uint32_t)f2bf(pv[mt][2]) | ((uint32_t)f2bf(pv[mt][3]) << 16);
        *(uint2*)(Pw + (16 * nt + l15) * 40 + 16 * mt + quad * 4) = d;
      }
    }
#pragma unroll
    for (int nt = 0; nt < 4; nt++) {
      bf16x8 PB = __builtin_bit_cast(bf16x8, *(const uint4*)(Pw + (16 * nt + l15) * 40 + quad * 8));
      Oacc[0][nt] = __builtin_amdgcn_mfma_f32_16x16x32_bf16(VA0, PB, Oacc[0][nt], 0, 0, 0);
      Oacc[1][nt] = __builtin_amdgcn_mfma_f32_16x16x32_bf16(VA1, PB, Oacc[1][nt], 0, 0, 0);
    }
  };

  int rbase = oct * 8;
  uint4 kA0, kA1, vA0, vA1, kB0, kB1, vB0, vB1;
  LOADROW(rbase + 0, kA0, kA1, vA0, vA1);
  LOADROW(rbase + 1, kB0, kB1, vB0, vB1);
#pragma unroll 1
  for (int r = 0; r < 8; r += 2) {
    if (r + 2 < 8) {
      compute(kA0, kA1, vA0, vA1);
      LOADROW(rbase + r + 2, kA0, kA1, vA0, vA1);
      compute(kB0, kB1, vB0, vB1);
      LOADROW(rbase + r + 3, kB0, kB1, vB0, vB1);
    } else {
      compute(kA0, kA1, vA0, vA1);
      compute(kB0, kB1, vB0, vB1);
    }
  }
#undef LOADROW

#pragma unroll
  for (int nt = 0; nt < 4; nt++) {
    lsum[nt] += __shfl_xor(lsum[nt], 16, 64);
    lsum[nt] += __shfl_xor(lsum[nt], 32, 64);
  }

  // ---- two-phase merge: sum (acc, l) over the 4 octs of each head ----
  float* mO = (float*)lds;                 // [oct][32ch][64q]  32 KB
  float* mL = (float*)(lds + 16384);       // [oct][64q]
#pragma unroll 1
  for (int p = 0; p < 2; p++) {
    __syncthreads();
    if (hd == p) {
#pragma unroll
      for (int mt = 0; mt < 2; mt++)
#pragma unroll
        for (int nt = 0; nt < 4; nt++)
#pragma unroll
          for (int r = 0; r < 4; r++)
            mO[oct * 2048 + (16 * mt + quad * 4 + r) * 64 + 16 * nt + l15] = Oacc[mt][nt][r];
      if (quad == 0) {
#pragma unroll
        for (int nt = 0; nt < 4; nt++) mL[oct * 64 + nt * 16 + l15] = lsum[nt];
      }
    }
    __syncthreads();
    {
      int q = threadIdx.x & 63;
      int cg = threadIdx.x >> 6;  // 0..7 -> 4 ch each
      float inv = 1.0f / (mL[q] + mL[64 + q] + mL[128 + q] + mL[192 + q]);
      float* ob = o + (((size_t)(b * 100 + n)) * 128 + (hp * 2 + p) * 32 + cg * 4) * 64 + q;
#pragma unroll
      for (int e = 0; e < 4; e++) {
        int ch = cg * 4 + e;
        float s = mO[ch * 64 + q] + mO[2048 + ch * 64 + q] +
                  mO[4096 + ch * 64 + q] + mO[6144 + ch * 64 + q];
        ob[(size_t)e * 64] = s * inv;
      }
    }
  }
}

// ---------------------------------------------------------------------------
// Reverse: scatter-average overlapping 8x8 windows (step 6) into (2,128,62,62)
// ---------------------------------------------------------------------------
__global__ void reverse_kernel(const float* __restrict__ win, float* __restrict__ out) {
  int i = blockIdx.x * 256 + threadIdx.x;
  const int total = 2 * 128 * HSW;
  if (i >= total) return;
  int x = i % HS;
  int t = i / HS;
  int y = t % HS;
  t /= HS;
  int c = t % 128;
  int b = t / 128;
  int wi0 = (y >= 7) ? (y - 2) / 6 : 0;
  int wi1 = min(9, y / 6);
  int wj0 = (x >= 7) ? (x - 2) / 6 : 0;
  int wj1 = min(9, x / 6);
  float s = 0.0f;
  for (int wi = wi0; wi <= wi1; wi++)
    for (int wj = wj0; wj <= wj1; wj++) {
      int di = y - 6 * wi, dj = x - 6 * wj;
      s += win[(((size_t)(b * 100 + wi * 10 + wj)) * 128 + c) * 64 + di * 8 + dj];
    }
  float cnt = (float)((wi1 - wi0 + 1) * (wj1 - wj0 + 1));
  out[i] = s / cnt;
}

// ---------------------------------------------------------------------------
extern "C" void kernel_launch(void* const* d_in, const int* in_sizes, int n_in,
                              void* d_out, int out_size, void* d_ws, size_t ws_size,
                              hipStream_t stream) {
  const float* x      = (const float*)d_in[0];
  const float* sp     = (const float*)d_in[1];
  const float* w_pos  = (const float*)d_in[2];
  const float* b_pos  = (const float*)d_in[3];
  const float* w_q    = (const float*)d_in[4];
  const float* w_qdw  = (const float*)d_in[5];
  const float* w_kv   = (const float*)d_in[6];
  const float* w_kvdw = (const float*)d_in[7];
  const float* w_out  = (const float*)d_in[8];
  float* out = (float*)d_out;

  const size_t N_x   = (size_t)2 * 128 * HXW;  // 15,745,024 floats
  const size_t N_t   = (size_t)2 * 256 * HXW;  // tkv bf16 elements (31.5M ushorts)
  const size_t N_s   = (size_t)2 * 128 * HSW;
  const size_t N_att = (size_t)2 * 100 * 128 * 64;

  float* ws = (float*)d_ws;
  // [0, N_x floats): xp fp32; later kT (N_x ushorts) + vv (N_x ushorts)
  float* xp = ws;
  unsigned short* kT = (unsigned short*)ws;
  unsigned short* vv = kT + N_x;
  // [N_x, N_x + N_t/2 floats): tkv bf16 NHWC; later att + rev
  unsigned short* tkv = (unsigned short*)(ws + N_x);
  float* att = ws + N_x;          // alias: tkv dead after dwconv_kv
  float* rev = att + N_att;
  float* spp = ws + N_x + N_t / 2;
  float* tq  = spp + N_s;
  unsigned short* qn = (unsigned short*)(tq + N_s);
  (void)ws_size; (void)in_sizes; (void)n_in; (void)out_size;

  // 1. xp = x + dwconv3(x, w_pos, b_pos)   (fp32 NCHW)
  {
    int total4 = (int)(N_x / 4);
    dwconv4_kernel<<<(total4 + 255) / 256, 256, 0, stream>>>(x, w_pos, b_pos, xp, 128, HX, HX, total4, 1);
  }
  // 2. spp = sp + dwconv3(sp, w_pos, b_pos)
  {
    int total = (int)N_s;
    dwconv3_kernel<<<(total + 255) / 256, 256, 0, stream>>>(sp, w_pos, b_pos, spp, 128, HS, HS, total, 1);
  }
  // 3. tq = conv1(spp, w_q)
  {
    int HW = HSW;
    dim3 grid((HW + 63) / 64, 2, 2);
    conv1_kernel<128><<<grid, 256, 0, stream>>>(spp, w_q, tq, HW);
  }
  // 4. qn = bf16_nhwc(dwconv3(tq, w_qdw)) * 32^-0.5
  {
    int total = (int)N_s;
    dwconv_q_kernel<<<(total + 255) / 256, 256, 0, stream>>>(tq, w_qdw, qn, total);
  }
  // 5. tkv = bf16_nhwc(conv1(xp, w_kv))   (xp dead after)
  {
    dim3 grid(HXW / 32, 2);
    conv1_kv_nhwc_kernel<<<grid, 256, 0, stream>>>(xp, w_kv, tkv);
  }
  // 6. kT (NHWC) + vv (NCHW) = bf16(dwconv3(tkv, w_kvdw))   (overwrites xp; tkv dead after)
  {
    dim3 grid(4, 62, 2);
    dwconv_kv_kernel<<<grid, 256, 0, stream>>>(tkv, w_kvdw, kT, vv);
  }
  // 7. attention -> att (2,100,128,64)   (att aliases tkv region)
  {
    dim3 grid(100, 2, 2);
    attn_mfma_kernel<<<grid, 512, 0, stream>>>(qn, kT, vv, att);
  }
  // 8. rev = reverse(att)
  {
    int total = (int)N_s;
    reverse_kernel<<<(total + 255) / 256, 256, 0, stream>>>(att, rev);
  }
  // 9. out = conv1(rev, w_out)
  {
    int HW = HSW;
    dim3 grid((HW + 63) / 64, 2, 2);
    conv1_kernel<128><<<grid, 256, 0, stream>>>(rev, w_out, out, HW);
  }
}

// Round 8
// 434.588 us; speedup vs baseline: 1.3952x; 1.2015x over previous
//
#include <hip/hip_runtime.h>
#include <cstdint>

#define HS 62
#define HX 248
#define HXW (HX * HX)  // 61504
#define HSW (HS * HS)  // 3844

typedef __attribute__((ext_vector_type(8))) short bf16x8;
typedef __attribute__((ext_vector_type(4))) float f32x4;

static __device__ __forceinline__ unsigned short f2bf(float f) {
  uint32_t u = __builtin_bit_cast(uint32_t, f);
  u += 0x7fff + ((u >> 16) & 1);  // RNE
  return (unsigned short)(u >> 16);
}
static __device__ __forceinline__ float bf2f(unsigned short u) {
  uint32_t x = (uint32_t)u << 16;
  return __builtin_bit_cast(float, x);
}

// ---------------------------------------------------------------------------
// Depthwise 3x3 scalar (62x62 tensors), fp32 out, bias+residual.
// ---------------------------------------------------------------------------
__global__ void dwconv3_kernel(const float* __restrict__ x, const float* __restrict__ w,
                               const float* __restrict__ bias, float* __restrict__ y,
                               int C, int H, int W, int total, int residual) {
  int i = blockIdx.x * 256 + threadIdx.x;
  if (i >= total) return;
  int wx = i % W;
  int t = i / W;
  int hy = t % H;
  int bc = t / H;
  int c = bc % C;
  const float* xb = x + (size_t)bc * H * W;
  const float* wc = w + c * 9;
  float s = bias ? bias[c] : 0.0f;
  for (int di = -1; di <= 1; di++) {
    int h2 = hy + di;
    if (h2 < 0 || h2 >= H) continue;
    for (int dj = -1; dj <= 1; dj++) {
      int w2 = wx + dj;
      if (w2 < 0 || w2 >= W) continue;
      s += xb[(size_t)h2 * W + w2] * wc[(di + 1) * 3 + (dj + 1)];
    }
  }
  if (residual) s += xb[(size_t)hy * W + wx];
  y[i] = s;
}

// ---------------------------------------------------------------------------
// Depthwise 3x3 vectorized fp32 (x -> xp), 4 pixels/thread, W%4==0.
// ---------------------------------------------------------------------------
__global__ void dwconv4_kernel(const float* __restrict__ x, const float* __restrict__ w,
                               const float* __restrict__ bias, float* __restrict__ y,
                               int C, int H, int W, int total4, int residual) {
  int i = blockIdx.x * 256 + threadIdx.x;
  if (i >= total4) return;
  int W4 = W >> 2;
  int wq = (i % W4) * 4;
  int t = i / W4;
  int hy = t % H;
  int bc = t / H;
  int c = bc % C;
  const float* xb = x + (size_t)bc * H * W;
  const float* wc = w + c * 9;
  float bv = bias ? bias[c] : 0.0f;
  float s0 = bv, s1 = bv, s2 = bv, s3 = bv;
  for (int di = -1; di <= 1; di++) {
    int h2 = hy + di;
    if (h2 < 0 || h2 >= H) continue;
    const float* row = xb + (size_t)h2 * W + wq;
    float4 cv = *(const float4*)row;
    float lf = (wq > 0) ? row[-1] : 0.0f;
    float rt = (wq + 4 < W) ? row[4] : 0.0f;
    float w0 = wc[(di + 1) * 3 + 0];
    float w1 = wc[(di + 1) * 3 + 1];
    float w2 = wc[(di + 1) * 3 + 2];
    s0 += w0 * lf   + w1 * cv.x + w2 * cv.y;
    s1 += w0 * cv.x + w1 * cv.y + w2 * cv.z;
    s2 += w0 * cv.y + w1 * cv.z + w2 * cv.w;
    s3 += w0 * cv.z + w1 * cv.w + w2 * rt;
  }
  if (residual) {
    float4 cc = *(const float4*)(xb + (size_t)hy * W + wq);
    s0 += cc.x; s1 += cc.y; s2 += cc.z; s3 += cc.w;
  }
  *(float4*)(y + (size_t)bc * H * W + (size_t)hy * W + wq) = make_float4(s0, s1, s2, s3);
}

// ---------------------------------------------------------------------------
// Depthwise 3x3 q path: fp32 NCHW in -> bf16 NHWC out, pre-scaled by 32^-0.5.
// ---------------------------------------------------------------------------
__global__ void dwconv_q_kernel(const float* __restrict__ x, const float* __restrict__ w,
                                unsigned short* __restrict__ qn, int total) {
  int i = blockIdx.x * 256 + threadIdx.x;
  if (i >= total) return;
  int wx = i % HS;
  int t = i / HS;
  int hy = t % HS;
  int bc = t / HS;
  int c = bc & 127;
  int b = bc >> 7;
  const float* xb = x + (size_t)bc * HSW;
  const float* wc = w + c * 9;
  float s = 0.0f;
  for (int di = -1; di <= 1; di++) {
    int h2 = hy + di;
    if (h2 < 0 || h2 >= HS) continue;
    for (int dj = -1; dj <= 1; dj++) {
      int w2 = wx + dj;
      if (w2 < 0 || w2 >= HS) continue;
      s += xb[(size_t)h2 * HS + w2] * wc[(di + 1) * 3 + (dj + 1)];
    }
  }
  qn[((size_t)(b * HSW + hy * HS + wx)) * 128 + c] = f2bf(s * 0.17677669529663688f);
}

// ---------------------------------------------------------------------------
// 1x1 conv for the kv path: y[b][p][o] = sum_c xp[b][c][p] * w_kv[o][c],
// output bf16 NHWC (2, 61504, 256). Block: 32 px x all 256 out-ch.
// ---------------------------------------------------------------------------
__global__ __launch_bounds__(256) void conv1_kv_nhwc_kernel(const float* __restrict__ x,
                                                            const float* __restrict__ w,
                                                            unsigned short* __restrict__ y) {
  __shared__ __align__(16) float ws_s[16][256];
  __shared__ __align__(16) float xs_s[16][32];
  int b = blockIdx.y;
  int p0 = blockIdx.x * 32;
  const float* xb = x + (size_t)b * 128 * HXW;
  int ty = threadIdx.x >> 3;   // 0..31 -> o = ty*8
  int tx = threadIdx.x & 7;    // 0..7  -> px = tx*4
  float acc[8][4] = {};
  for (int k0 = 0; k0 < 128; k0 += 16) {
    __syncthreads();
    {
      const float* wp = w + (size_t)threadIdx.x * 128 + k0;
      float4 a = *(const float4*)(wp);
      float4 bq = *(const float4*)(wp + 4);
      float4 cq = *(const float4*)(wp + 8);
      float4 dq = *(const float4*)(wp + 12);
      ws_s[0][threadIdx.x] = a.x;  ws_s[1][threadIdx.x] = a.y;
      ws_s[2][threadIdx.x] = a.z;  ws_s[3][threadIdx.x] = a.w;
      ws_s[4][threadIdx.x] = bq.x; ws_s[5][threadIdx.x] = bq.y;
      ws_s[6][threadIdx.x] = bq.z; ws_s[7][threadIdx.x] = bq.w;
      ws_s[8][threadIdx.x] = cq.x; ws_s[9][threadIdx.x] = cq.y;
      ws_s[10][threadIdx.x] = cq.z; ws_s[11][threadIdx.x] = cq.w;
      ws_s[12][threadIdx.x] = dq.x; ws_s[13][threadIdx.x] = dq.y;
      ws_s[14][threadIdx.x] = dq.z; ws_s[15][threadIdx.x] = dq.w;
    }
    {
      int k = threadIdx.x >> 4;
      int px = (threadIdx.x & 15) * 2;
      float2 v = *(const float2*)(xb + (size_t)(k0 + k) * HXW + p0 + px);
      xs_s[k][px] = v.x;
      xs_s[k][px + 1] = v.y;
    }
    __syncthreads();
#pragma unroll
    for (int k = 0; k < 16; k++) {
      float4 w0 = *(const float4*)&ws_s[k][ty * 8];
      float4 w1 = *(const float4*)&ws_s[k][ty * 8 + 4];
      float4 xv = *(const float4*)&xs_s[k][tx * 4];
      acc[0][0] += w0.x * xv.x; acc[0][1] += w0.x * xv.y; acc[0][2] += w0.x * xv.z; acc[0][3] += w0.x * xv.w;
      acc[1][0] += w0.y * xv.x; acc[1][1] += w0.y * xv.y; acc[1][2] += w0.y * xv.z; acc[1][3] += w0.y * xv.w;
      acc[2][0] += w0.z * xv.x; acc[2][1] += w0.z * xv.y; acc[2][2] += w0.z * xv.z; acc[2][3] += w0.z * xv.w;
      acc[3][0] += w0.w * xv.x; acc[3][1] += w0.w * xv.y; acc[3][2] += w0.w * xv.z; acc[3][3] += w0.w * xv.w;
      acc[4][0] += w1.x * xv.x; acc[4][1] += w1.x * xv.y; acc[4][2] += w1.x * xv.z; acc[4][3] += w1.x * xv.w;
      acc[5][0] += w1.y * xv.x; acc[5][1] += w1.y * xv.y; acc[5][2] += w1.y * xv.z; acc[5][3] += w1.y * xv.w;
      acc[6][0] += w1.z * xv.x; acc[6][1] += w1.z * xv.y; acc[6][2] += w1.z * xv.z; acc[6][3] += w1.z * xv.w;
      acc[7][0] += w1.w * xv.x; acc[7][1] += w1.w * xv.y; acc[7][2] += w1.w * xv.z; acc[7][3] += w1.w * xv.w;
    }
  }
#pragma unroll
  for (int e = 0; e < 4; e++) {
    int px = p0 + tx * 4 + e;
    uint4 d;
    d.x = (uint32_t)f2bf(acc[0][e]) | ((uint32_t)f2bf(acc[1][e]) << 16);
    d.y = (uint32_t)f2bf(acc[2][e]) | ((uint32_t)f2bf(acc[3][e]) << 16);
    d.z = (uint32_t)f2bf(acc[4][e]) | ((uint32_t)f2bf(acc[5][e]) << 16);
    d.w = (uint32_t)f2bf(acc[6][e]) | ((uint32_t)f2bf(acc[7][e]) << 16);
    *(uint4*)(y + ((size_t)b * HXW + px) * 256 + ty * 8) = d;
  }
}

// ---------------------------------------------------------------------------
// Fused depthwise 3x3 for K and V from bf16 NHWC tkv (2,61504,256).
//  K (ch 0..127)  -> bf16 NHWC kT (direct)
//  V (ch 128..255)-> bf16 NCHW vv via LDS [ch][px] stride-66 (conflict-free)
// Block = (64-px strip, 2-row group, b); lane = channel. px loop processes
// 4 px/iter with software-pipelined 12-load batches (nA/nB) for MLP.
// Grid (4, 124, 2), 256 thr.
// ---------------------------------------------------------------------------
__global__ __launch_bounds__(256) void dwconv_kv_kernel(const unsigned short* __restrict__ tkv,
                                                        const float* __restrict__ w,
                                                        unsigned short* __restrict__ kT,
                                                        unsigned short* __restrict__ vv) {
  int strip = blockIdx.x;                      // 0..3
  int x0 = (strip == 3) ? 184 : strip * 64;
  int g = blockIdx.y;                          // 0..123
  int b = blockIdx.z;
  int c = threadIdx.x & 127;
  int half = threadIdx.x >> 7;                 // 0 = K, 1 = V
  int ch = half * 128 + c;
  const float* wc = w + ch * 9;
  float w00 = wc[0], w01 = wc[1], w02 = wc[2];
  float w10 = wc[3], w11 = wc[4], w12 = wc[5];
  float w20 = wc[6], w21 = wc[7], w22 = wc[8];
  const unsigned short* src = tkv + ((size_t)b * HXW) * 256 + ch;
  __shared__ unsigned short vt[128 * 66];      // [ch][px] stride 66 (16.9 KB)

#pragma unroll 1
  for (int r = 0; r < 2; r++) {
    int hy = g * 2 + r;
    bool vtop = hy > 0, vbot = hy < HX - 1;
    const unsigned short* r0 = src + ((size_t)(hy - 1) * HX) * 256;
    const unsigned short* r1 = src + ((size_t)hy * HX) * 256;
    const unsigned short* r2 = src + ((size_t)(hy + 1) * HX) * 256;
    float a0, a1, a2, b0, b1, b2;
    if (x0 > 0) {
      a0 = vtop ? bf2f(r0[(size_t)(x0 - 1) * 256]) : 0.0f;
      a1 = bf2f(r1[(size_t)(x0 - 1) * 256]);
      a2 = vbot ? bf2f(r2[(size_t)(x0 - 1) * 256]) : 0.0f;
    } else { a0 = a1 = a2 = 0.0f; }
    b0 = vtop ? bf2f(r0[(size_t)x0 * 256]) : 0.0f;
    b1 = bf2f(r1[(size_t)x0 * 256]);
    b2 = vbot ? bf2f(r2[(size_t)x0 * 256]) : 0.0f;

    float nA[12], nB[12];
#define LOADB(DST, PX4)                                                        \
    {                                                                          \
      _Pragma("unroll")                                                        \
      for (int j = 0; j < 4; j++) {                                            \
        int xn = x0 + (PX4) + j + 1;                                           \
        if (xn < HX) {                                                         \
          DST[j * 3 + 0] = vtop ? bf2f(r0[(size_t)xn * 256]) : 0.0f;           \
          DST[j * 3 + 1] = bf2f(r1[(size_t)xn * 256]);                         \
          DST[j * 3 + 2] = vbot ? bf2f(r2[(size_t)xn * 256]) : 0.0f;           \
        } else {                                                               \
          DST[j * 3 + 0] = DST[j * 3 + 1] = DST[j * 3 + 2] = 0.0f;             \
        }                                                                      \
      }                                                                        \
    }
#define COMPB(SRCN, PX4)                                                       \
    {                                                                          \
      _Pragma("unroll")                                                        \
      for (int j = 0; j < 4; j++) {                                            \
        float s = w00 * a0 + w01 * b0 + w02 * SRCN[j * 3 + 0] +                \
                  w10 * a1 + w11 * b1 + w12 * SRCN[j * 3 + 1] +                \
                  w20 * a2 + w21 * b2 + w22 * SRCN[j * 3 + 2];                 \
        unsigned short sb = f2bf(s);                                           \
        if (half == 0) {                                                       \
          kT[((size_t)b * HXW + (size_t)hy * HX + x0 + (PX4) + j) * 128 + c] = sb; \
        } else {                                                               \
          vt[c * 66 + (PX4) + j] = sb;                                         \
        }                                                                      \
        a0 = b0; a1 = b1; a2 = b2;                                             \
        b0 = SRCN[j * 3 + 0]; b1 = SRCN[j * 3 + 1]; b2 = SRCN[j * 3 + 2];      \
      }                                                                        \
    }

    LOADB(nA, 0);
#pragma unroll 1
    for (int px4 = 0; px4 < 64; px4 += 8) {
      if (px4 + 4 < 64) LOADB(nB, px4 + 4);
      COMPB(nA, px4);
      if (px4 + 8 < 64) LOADB(nA, px4 + 8);
      COMPB(nB, px4 + 4);
    }
#undef LOADB
#undef COMPB
    __syncthreads();
    {  // cooperative NCHW store of the V row: lane = channel, conflict-free
      int cv = threadIdx.x & 127;
      int phx = (threadIdx.x >> 7) * 32;
      unsigned short* dst = vv + ((size_t)(b * 128 + cv)) * HXW + (size_t)hy * HX + x0 + phx;
      const unsigned short* srcv = vt + cv * 66 + phx;
#pragma unroll
      for (int jj = 0; jj < 8; jj++) {
        uint2 d;
        d.x = (uint32_t)srcv[jj * 4 + 0] | ((uint32_t)srcv[jj * 4 + 1] << 16);
        d.y = (uint32_t)srcv[jj * 4 + 2] | ((uint32_t)srcv[jj * 4 + 3] << 16);
        *(uint2*)(dst + jj * 4) = d;
      }
    }
    __syncthreads();
  }
}

// ---------------------------------------------------------------------------
// 1x1 conv tiled SGEMM (fp32) — small tensors (q path, output projection).
// ---------------------------------------------------------------------------
template <int O>
__global__ __launch_bounds__(256) void conv1_kernel(const float* __restrict__ x,
                                                    const float* __restrict__ w,
                                                    float* __restrict__ y, int HW) {
  constexpr int K = 128;
  constexpr int BK = 32;
  __shared__ __align__(16) float ws_s[BK][64];
  __shared__ __align__(16) float xs_s[BK][64];
  int b = blockIdx.z;
  int o0 = blockIdx.y * 64;
  int p0 = blockIdx.x * 64;
  const float* xb = x + (size_t)b * K * HW;
  int tx = threadIdx.x & 15;
  int ty = threadIdx.x >> 4;
  float acc[4][4] = {};
  int lo = threadIdx.x >> 2;
  int lk = (threadIdx.x & 3) * 8;
  int lc = threadIdx.x >> 3;
  int lp = (threadIdx.x & 7) * 8;

  for (int k0 = 0; k0 < K; k0 += BK) {
    __syncthreads();
    {
      const float* wp = w + (size_t)(o0 + lo) * K + k0 + lk;
      float4 a = *(const float4*)wp;
      float4 bq = *(const float4*)(wp + 4);
      ws_s[lk + 0][lo] = a.x;  ws_s[lk + 1][lo] = a.y;
      ws_s[lk + 2][lo] = a.z;  ws_s[lk + 3][lo] = a.w;
      ws_s[lk + 4][lo] = bq.x; ws_s[lk + 5][lo] = bq.y;
      ws_s[lk + 6][lo] = bq.z; ws_s[lk + 7][lo] = bq.w;
    }
    {
      int p = p0 + lp;
      const float* xp = xb + (size_t)(k0 + lc) * HW;
      float4 a, bq;
      if (p + 7 < HW) {
        a = *(const float4*)(xp + p);
        bq = *(const float4*)(xp + p + 4);
      } else {
        float tv[8];
#pragma unroll
        for (int j = 0; j < 8; j++) tv[j] = (p + j < HW) ? xp[p + j] : 0.0f;
        a = make_float4(tv[0], tv[1], tv[2], tv[3]);
        bq = make_float4(tv[4], tv[5], tv[6], tv[7]);
      }
      *(float4*)&xs_s[lc][lp] = a;
      *(float4*)&xs_s[lc][lp + 4] = bq;
    }
    __syncthreads();
#pragma unroll
    for (int k = 0; k < BK; k++) {
      float4 wv = *(const float4*)&ws_s[k][ty * 4];
      float4 xv = *(const float4*)&xs_s[k][tx * 4];
      acc[0][0] += wv.x * xv.x; acc[0][1] += wv.x * xv.y; acc[0][2] += wv.x * xv.z; acc[0][3] += wv.x * xv.w;
      acc[1][0] += wv.y * xv.x; acc[1][1] += wv.y * xv.y; acc[1][2] += wv.y * xv.z; acc[1][3] += wv.y * xv.w;
      acc[2][0] += wv.z * xv.x; acc[2][1] += wv.z * xv.y; acc[2][2] += wv.z * xv.z; acc[2][3] += wv.z * xv.w;
      acc[3][0] += wv.w * xv.x; acc[3][1] += wv.w * xv.y; acc[3][2] += wv.w * xv.z; acc[3][3] += wv.w * xv.w;
    }
  }
  int p = p0 + tx * 4;
  float* yb = y + (size_t)b * O * HW + (size_t)(o0 + ty * 4) * HW;
#pragma unroll
  for (int j = 0; j < 4; j++) {
    float* yr = yb + (size_t)j * HW + p;
    if (p + 3 < HW) {
      *(float4*)yr = make_float4(acc[j][0], acc[j][1], acc[j][2], acc[j][3]);
    } else {
#pragma unroll
      for (int e = 0; e < 4; e++) if (p + e < HW) yr[e] = acc[j][e];
    }
  }
}

// ---------------------------------------------------------------------------
// MFMA windowed attention, head-pair blocks. 512 thr = 8 waves.
// ---------------------------------------------------------------------------
__global__ __launch_bounds__(512) void attn_mfma_kernel(
    const unsigned short* __restrict__ qn,   // (2,62,62,128) bf16, pre-scaled
    const unsigned short* __restrict__ kT,   // (2,248,248,128) bf16 NHWC
    const unsigned short* __restrict__ vp,   // (2,128,248,248) bf16 NCHW
    float* __restrict__ o) {
  int n = blockIdx.x, hp = blockIdx.y, b = blockIdx.z;
  int wi = n / 10, wj = n % 10;
  int wave = threadIdx.x >> 6;
  int hd = wave & 1, oct = wave >> 1;
  int h = hp * 2 + hd;
  int lane = threadIdx.x & 63;
  int quad = lane >> 4;
  int l15 = lane & 15;
  int y0 = 24 * wi, x0 = 24 * wj;

  __shared__ __align__(16) unsigned short lds[20480];  // 40,960 B
  unsigned short* Pw = lds + wave * 2560;              // [q][40keys] 5KB/wave

  bf16x8 QB[4];
#pragma unroll
  for (int nt = 0; nt < 4; nt++) {
    int qq = nt * 16 + l15;
    int qy = 6 * wi + (qq >> 3), qx = 6 * wj + (qq & 7);
    QB[nt] = __builtin_bit_cast(bf16x8,
        *(const uint4*)(qn + ((size_t)(b * HSW + qy * HS + qx)) * 128 + h * 32 + quad * 8));
  }

  f32x4 Oacc[2][4];
#pragma unroll
  for (int a = 0; a < 2; a++)
#pragma unroll
    for (int c = 0; c < 4; c++) Oacc[a][c] = f32x4{0.f, 0.f, 0.f, 0.f};
  float lsum[4] = {0.f, 0.f, 0.f, 0.f};

  const unsigned short* kb = kT + (size_t)b * HXW * 128 + h * 32;
  const unsigned short* vb = vp + ((size_t)(b * 128 + h * 32)) * HXW;
  const f32x4 zf = {0.f, 0.f, 0.f, 0.f};

#define LOADROW(r, K0, K1, V0, V1)                                              \
  {                                                                             \
    int y = y0 + (r);                                                           \
    const unsigned short* krow = kb + ((size_t)(y * HX + x0)) * 128;            \
    K0 = *(const uint4*)(krow + (size_t)l15 * 128 + quad * 8);                  \
    K1 = *(const uint4*)(krow + (size_t)(16 + l15) * 128 + quad * 8);           \
    const unsigned short* vrow = vb + (size_t)y * HX + x0 + quad * 8;           \
    V0 = *(const uint4*)(vrow + (size_t)l15 * HXW);                             \
    V1 = *(const uint4*)(vrow + (size_t)(16 + l15) * HXW);                      \
  }

  auto compute = [&](uint4 k0, uint4 k1, uint4 v0, uint4 v1) {
    bf16x8 KA0 = __builtin_bit_cast(bf16x8, k0);
    bf16x8 KA1 = __builtin_bit_cast(bf16x8, k1);
    bf16x8 VA0 = __builtin_bit_cast(bf16x8, v0);
    bf16x8 VA1 = __builtin_bit_cast(bf16x8, v1);
    f32x4 S[2][4];
#pragma unroll
    for (int nt = 0; nt < 4; nt++) {
      S[0][nt] = __builtin_amdgcn_mfma_f32_16x16x32_bf16(KA0, QB[nt], zf, 0, 0, 0);
      S[1][nt] = __builtin_amdgcn_mfma_f32_16x16x32_bf16(KA1, QB[nt], zf, 0, 0, 0);
    }
#pragma unroll
    for (int nt = 0; nt < 4; nt++) {
      float pv[2][4];
      float cs = 0.f;
#pragma unroll
      for (int mt = 0; mt < 2; mt++)
#pragma unroll
        for (int r = 0; r < 4; r++) {
          pv[mt][r] = __expf(S[mt][nt][r]);
          cs += pv[mt][r];
        }
      lsum[nt] += cs;
#pragma unroll
      for (int mt = 0; mt < 2; mt++) {
        uint2 d;
        d.x = (uint32_t)f2bf(pv[mt][0]) | ((uint32_t)f2bf(pv[mt][1]) << 16);
        d.y = (uint32_t)f2bf(pv[mt][2]) | ((uint32_t)f2bf(pv[mt][3]) << 16);
        *(uint2*)(Pw + (16 * nt + l15) * 40 + 16 * mt + quad * 4) = d;
      }
    }
#pragma unroll
    for (int nt = 0; nt < 4; nt++) {
      bf16x8 PB = __builtin_bit_cast(bf16x8, *(const uint4*)(Pw + (16 * nt + l15) * 40 + quad * 8));
      Oacc[0][nt] = __builtin_amdgcn_mfma_f32_16x16x32_bf16(VA0, PB, Oacc[0][nt], 0, 0, 0);
      Oacc[1][nt] = __builtin_amdgcn_mfma_f32_16x16x32_bf16(VA1, PB, Oacc[1][nt], 0, 0, 0);
    }
  };

  int rbase = oct * 8;
  uint4 kA0, kA1, vA0, vA1, kB0, kB1, vB0, vB1;
  LOADROW(rbase + 0, kA0, kA1, vA0, vA1);
  LOADROW(rbase + 1, kB0, kB1, vB0, vB1);
#pragma unroll 1
  for (int r = 0; r < 8; r += 2) {
    if (r + 2 < 8) {
      compute(kA0, kA1, vA0, vA1);
      LOADROW(rbase + r + 2, kA0, kA1, vA0, vA1);
      compute(kB0, kB1, vB0, vB1);
      LOADROW(rbase + r + 3, kB0, kB1, vB0, vB1);
    } else {
      compute(kA0, kA1, vA0, vA1);
      compute(kB0, kB1, vB0, vB1);
    }
  }
#undef LOADROW

#pragma unroll
  for (int nt = 0; nt < 4; nt++) {
    lsum[nt] += __shfl_xor(lsum[nt], 16, 64);
    lsum[nt] += __shfl_xor(lsum[nt], 32, 64);
  }

  float* mO = (float*)lds;                 // [oct][32ch][64q]  32 KB
  float* mL = (float*)(lds + 16384);       // [oct][64q]
#pragma unroll 1
  for (int p = 0; p < 2; p++) {
    __syncthreads();
    if (hd == p) {
#pragma unroll
      for (int mt = 0; mt < 2; mt++)
#pragma unroll
        for (int nt = 0; nt < 4; nt++)
#pragma unroll
          for (int r = 0; r < 4; r++)
            mO[oct * 2048 + (16 * mt + quad * 4 + r) * 64 + 16 * nt + l15] = Oacc[mt][nt][r];
      if (quad == 0) {
#pragma unroll
        for (int nt = 0; nt < 4; nt++) mL[oct * 64 + nt * 16 + l15] = lsum[nt];
      }
    }
    __syncthreads();
    {
      int q = threadIdx.x & 63;
      int cg = threadIdx.x >> 6;  // 0..7 -> 4 ch each
      float inv = 1.0f / (mL[q] + mL[64 + q] + mL[128 + q] + mL[192 + q]);
      float* ob = o + (((size_t)(b * 100 + n)) * 128 + (hp * 2 + p) * 32 + cg * 4) * 64 + q;
#pragma unroll
      for (int e = 0; e < 4; e++) {
        int ch = cg * 4 + e;
        float s = mO[ch * 64 + q] + mO[2048 + ch * 64 + q] +
                  mO[4096 + ch * 64 + q] + mO[6144 + ch * 64 + q];
        ob[(size_t)e * 64] = s * inv;
      }
    }
  }
}

// ---------------------------------------------------------------------------
// Reverse: scatter-average overlapping 8x8 windows (step 6) into (2,128,62,62)
// ---------------------------------------------------------------------------
__global__ void reverse_kernel(const float* __restrict__ win, float* __restrict__ out) {
  int i = blockIdx.x * 256 + threadIdx.x;
  const int total = 2 * 128 * HSW;
  if (i >= total) return;
  int x = i % HS;
  int t = i / HS;
  int y = t % HS;
  t /= HS;
  int c = t % 128;
  int b = t / 128;
  int wi0 = (y >= 7) ? (y - 2) / 6 : 0;
  int wi1 = min(9, y / 6);
  int wj0 = (x >= 7) ? (x - 2) / 6 : 0;
  int wj1 = min(9, x / 6);
  float s = 0.0f;
  for (int wi = wi0; wi <= wi1; wi++)
    for (int wj = wj0; wj <= wj1; wj++) {
      int di = y - 6 * wi, dj = x - 6 * wj;
      s += win[(((size_t)(b * 100 + wi * 10 + wj)) * 128 + c) * 64 + di * 8 + dj];
    }
  float cnt = (float)((wi1 - wi0 + 1) * (wj1 - wj0 + 1));
  out[i] = s / cnt;
}

// ---------------------------------------------------------------------------
extern "C" void kernel_launch(void* const* d_in, const int* in_sizes, int n_in,
                              void* d_out, int out_size, void* d_ws, size_t ws_size,
                              hipStream_t stream) {
  const float* x      = (const float*)d_in[0];
  const float* sp     = (const float*)d_in[1];
  const float* w_pos  = (const float*)d_in[2];
  const float* b_pos  = (const float*)d_in[3];
  const float* w_q    = (const float*)d_in[4];
  const float* w_qdw  = (const float*)d_in[5];
  const float* w_kv   = (const float*)d_in[6];
  const float* w_kvdw = (const float*)d_in[7];
  const float* w_out  = (const float*)d_in[8];
  float* out = (float*)d_out;

  const size_t N_x   = (size_t)2 * 128 * HXW;  // 15,745,024 floats
  const size_t N_t   = (size_t)2 * 256 * HXW;  // tkv bf16 elements
  const size_t N_s   = (size_t)2 * 128 * HSW;
  const size_t N_att = (size_t)2 * 100 * 128 * 64;

  float* ws = (float*)d_ws;
  float* xp = ws;
  unsigned short* kT = (unsigned short*)ws;
  unsigned short* vv = kT + N_x;
  unsigned short* tkv = (unsigned short*)(ws + N_x);
  float* att = ws + N_x;          // alias: tkv dead after dwconv_kv
  float* rev = att + N_att;
  float* spp = ws + N_x + N_t / 2;
  float* tq  = spp + N_s;
  unsigned short* qn = (unsigned short*)(tq + N_s);
  (void)ws_size; (void)in_sizes; (void)n_in; (void)out_size;

  // 1. xp = x + dwconv3(x, w_pos, b_pos)   (fp32 NCHW)
  {
    int total4 = (int)(N_x / 4);
    dwconv4_kernel<<<(total4 + 255) / 256, 256, 0, stream>>>(x, w_pos, b_pos, xp, 128, HX, HX, total4, 1);
  }
  // 2. spp = sp + dwconv3(sp, w_pos, b_pos)
  {
    int total = (int)N_s;
    dwconv3_kernel<<<(total + 255) / 256, 256, 0, stream>>>(sp, w_pos, b_pos, spp, 128, HS, HS, total, 1);
  }
  // 3. tq = conv1(spp, w_q)
  {
    int HW = HSW;
    dim3 grid((HW + 63) / 64, 2, 2);
    conv1_kernel<128><<<grid, 256, 0, stream>>>(spp, w_q, tq, HW);
  }
  // 4. qn = bf16_nhwc(dwconv3(tq, w_qdw)) * 32^-0.5
  {
    int total = (int)N_s;
    dwconv_q_kernel<<<(total + 255) / 256, 256, 0, stream>>>(tq, w_qdw, qn, total);
  }
  // 5. tkv = bf16_nhwc(conv1(xp, w_kv))   (xp dead after)
  {
    dim3 grid(HXW / 32, 2);
    conv1_kv_nhwc_kernel<<<grid, 256, 0, stream>>>(xp, w_kv, tkv);
  }
  // 6. kT (NHWC) + vv (NCHW) = bf16(dwconv3(tkv, w_kvdw))   (overwrites xp)
  {
    dim3 grid(4, 124, 2);
    dwconv_kv_kernel<<<grid, 256, 0, stream>>>(tkv, w_kvdw, kT, vv);
  }
  // 7. attention -> att (2,100,128,64)
  {
    dim3 grid(100, 2, 2);
    attn_mfma_kernel<<<grid, 512, 0, stream>>>(qn, kT, vv, att);
  }
  // 8. rev = reverse(att)
  {
    int total = (int)N_s;
    reverse_kernel<<<(total + 255) / 256, 256, 0, stream>>>(att, rev);
  }
  // 9. out = conv1(rev, w_out)
  {
    int HW = HSW;
    dim3 grid((HW + 63) / 64, 2, 2);
    conv1_kernel<128><<<grid, 256, 0, stream>>>(rev, w_out, out, HW);
  }
}

// Round 9
// 401.889 us; speedup vs baseline: 1.5087x; 1.0814x over previous
//
#include <hip/hip_runtime.h>
#include <cstdint>

#define HS 62
#define HX 248
#define HXW (HX * HX)  // 61504
#define HSW (HS * HS)  // 3844

typedef __attribute__((ext_vector_type(8))) short bf16x8;
typedef __attribute__((ext_vector_type(4))) float f32x4;

static __device__ __forceinline__ unsigned short f2bf(float f) {
  uint32_t u = __builtin_bit_cast(uint32_t, f);
  u += 0x7fff + ((u >> 16) & 1);  // RNE
  return (unsigned short)(u >> 16);
}
static __device__ __forceinline__ float bf2f(unsigned short u) {
  uint32_t x = (uint32_t)u << 16;
  return __builtin_bit_cast(float, x);
}

// ---------------------------------------------------------------------------
// Depthwise 3x3 scalar (62x62 tensors), fp32 out, bias+residual.
// ---------------------------------------------------------------------------
__global__ void dwconv3_kernel(const float* __restrict__ x, const float* __restrict__ w,
                               const float* __restrict__ bias, float* __restrict__ y,
                               int C, int H, int W, int total, int residual) {
  int i = blockIdx.x * 256 + threadIdx.x;
  if (i >= total) return;
  int wx = i % W;
  int t = i / W;
  int hy = t % H;
  int bc = t / H;
  int c = bc % C;
  const float* xb = x + (size_t)bc * H * W;
  const float* wc = w + c * 9;
  float s = bias ? bias[c] : 0.0f;
  for (int di = -1; di <= 1; di++) {
    int h2 = hy + di;
    if (h2 < 0 || h2 >= H) continue;
    for (int dj = -1; dj <= 1; dj++) {
      int w2 = wx + dj;
      if (w2 < 0 || w2 >= W) continue;
      s += xb[(size_t)h2 * W + w2] * wc[(di + 1) * 3 + (dj + 1)];
    }
  }
  if (residual) s += xb[(size_t)hy * W + wx];
  y[i] = s;
}

// ---------------------------------------------------------------------------
// Depthwise 3x3 x-path: fp32 NCHW in -> bf16 NCHW out, residual. 4 px/thread.
// ---------------------------------------------------------------------------
__global__ void dwconv4_bf16_kernel(const float* __restrict__ x, const float* __restrict__ w,
                                    const float* __restrict__ bias,
                                    unsigned short* __restrict__ y, int total4) {
  int i = blockIdx.x * 256 + threadIdx.x;
  if (i >= total4) return;
  int W4 = HX >> 2;
  int wq = (i % W4) * 4;
  int t = i / W4;
  int hy = t % HX;
  int bc = t / HX;
  int c = bc & 127;
  const float* xb = x + (size_t)bc * HXW;
  const float* wc = w + c * 9;
  float bv = bias[c];
  float s0 = bv, s1 = bv, s2 = bv, s3 = bv;
  for (int di = -1; di <= 1; di++) {
    int h2 = hy + di;
    if (h2 < 0 || h2 >= HX) continue;
    const float* row = xb + (size_t)h2 * HX + wq;
    float4 cv = *(const float4*)row;
    float lf = (wq > 0) ? row[-1] : 0.0f;
    float rt = (wq + 4 < HX) ? row[4] : 0.0f;
    float w0 = wc[(di + 1) * 3 + 0];
    float w1 = wc[(di + 1) * 3 + 1];
    float w2 = wc[(di + 1) * 3 + 2];
    s0 += w0 * lf   + w1 * cv.x + w2 * cv.y;
    s1 += w0 * cv.x + w1 * cv.y + w2 * cv.z;
    s2 += w0 * cv.y + w1 * cv.z + w2 * cv.w;
    s3 += w0 * cv.z + w1 * cv.w + w2 * rt;
  }
  {
    float4 cc = *(const float4*)(xb + (size_t)hy * HX + wq);
    s0 += cc.x; s1 += cc.y; s2 += cc.z; s3 += cc.w;
  }
  uint2 d;
  d.x = (uint32_t)f2bf(s0) | ((uint32_t)f2bf(s1) << 16);
  d.y = (uint32_t)f2bf(s2) | ((uint32_t)f2bf(s3) << 16);
  *(uint2*)(y + (size_t)bc * HXW + (size_t)hy * HX + wq) = d;
}

// ---------------------------------------------------------------------------
// fp32 -> bf16 flat convert (for w_kv).
// ---------------------------------------------------------------------------
__global__ void cvt_bf16_kernel(const float* __restrict__ src, unsigned short* __restrict__ dst,
                                int n) {
  int i = blockIdx.x * 256 + threadIdx.x;
  if (i < n) dst[i] = f2bf(src[i]);
}

// ---------------------------------------------------------------------------
// Depthwise 3x3 q path: fp32 NCHW in -> bf16 NHWC out, pre-scaled by 32^-0.5.
// ---------------------------------------------------------------------------
__global__ void dwconv_q_kernel(const float* __restrict__ x, const float* __restrict__ w,
                                unsigned short* __restrict__ qn, int total) {
  int i = blockIdx.x * 256 + threadIdx.x;
  if (i >= total) return;
  int wx = i % HS;
  int t = i / HS;
  int hy = t % HS;
  int bc = t / HS;
  int c = bc & 127;
  int b = bc >> 7;
  const float* xb = x + (size_t)bc * HSW;
  const float* wc = w + c * 9;
  float s = 0.0f;
  for (int di = -1; di <= 1; di++) {
    int h2 = hy + di;
    if (h2 < 0 || h2 >= HS) continue;
    for (int dj = -1; dj <= 1; dj++) {
      int w2 = wx + dj;
      if (w2 < 0 || w2 >= HS) continue;
      s += xb[(size_t)h2 * HS + w2] * wc[(di + 1) * 3 + (dj + 1)];
    }
  }
  qn[((size_t)(b * HSW + hy * HS + wx)) * 128 + c] = f2bf(s * 0.17677669529663688f);
}

// ---------------------------------------------------------------------------
// MFMA 1x1 conv kv path: tkv[b][p][o] = sum_c xpb[b][c][p] * wkb[o][c].
// Inputs bf16 (xpb NCHW, wkb [o][c]); output bf16 NHWC (2,61504,256).
// Block = 64 px x 256 out-ch, 4 waves (wave = 16-px tile). K=128 in 4 blocks.
// X-tile staged LDS [px][c] (pad 136); A-frags in regs; B-frags straight from
// global wkb (L2-resident, [o][c] row IS the B-fragment layout); D staged to
// LDS [px][o] (pad 264) and flushed as coalesced 512B/px NHWC rows.
// Grid (961, 2).
// ---------------------------------------------------------------------------
__global__ __launch_bounds__(256) void conv1_kv_mfma_kernel(
    const unsigned short* __restrict__ xpb,  // (2,128,61504) bf16 NCHW
    const unsigned short* __restrict__ wkb,  // (256,128) bf16
    unsigned short* __restrict__ y) {        // (2,61504,256) bf16 NHWC
  int b = blockIdx.y;
  int p0 = blockIdx.x * 64;
  int tid = threadIdx.x;
  int wave = tid >> 6, lane = tid & 63, quad = lane >> 4, l15 = lane & 15;
  __shared__ __align__(16) unsigned short lds[64 * 264];  // 33,792 B

  // phase 1: stage X-tile as xs[px][c], stride 136
  {
    int c = tid >> 1, half = tid & 1;
    const unsigned short* src = xpb + ((size_t)(b * 128 + c)) * HXW + p0 + half * 32;
#pragma unroll
    for (int j = 0; j < 8; j++) {
      uint2 v = *(const uint2*)(src + j * 4);
      int px = half * 32 + j * 4;
      lds[(px + 0) * 136 + c] = (unsigned short)(v.x & 0xffff);
      lds[(px + 1) * 136 + c] = (unsigned short)(v.x >> 16);
      lds[(px + 2) * 136 + c] = (unsigned short)(v.y & 0xffff);
      lds[(px + 3) * 136 + c] = (unsigned short)(v.y >> 16);
    }
  }
  __syncthreads();
  bf16x8 A[4];
#pragma unroll
  for (int kb = 0; kb < 4; kb++)
    A[kb] = __builtin_bit_cast(bf16x8,
        *(const uint4*)&lds[(wave * 16 + l15) * 136 + kb * 32 + quad * 8]);
  __syncthreads();  // xs dead; lds becomes os[px][o] stride 264

  const f32x4 zf = {0.f, 0.f, 0.f, 0.f};
#pragma unroll 1
  for (int ot = 0; ot < 16; ot++) {
    const unsigned short* wb = wkb + (size_t)(ot * 16 + l15) * 128 + quad * 8;
    f32x4 D = zf;
#pragma unroll
    for (int kb = 0; kb < 4; kb++) {
      bf16x8 B = __builtin_bit_cast(bf16x8, *(const uint4*)(wb + kb * 32));
      D = __builtin_amdgcn_mfma_f32_16x16x32_bf16(A[kb], B, D, 0, 0, 0);
    }
#pragma unroll
    for (int r = 0; r < 4; r++)
      lds[(wave * 16 + quad * 4 + r) * 264 + ot * 16 + l15] = f2bf(D[r]);
  }
  __syncthreads();
  // flush 64px x 256o, coalesced
  {
    int px = tid >> 2, og = (tid & 3) * 64;
    const uint4* srcp = (const uint4*)&lds[px * 264 + og];
    uint4* dstp = (uint4*)(y + ((size_t)b * HXW + p0 + px) * 256 + og);
#pragma unroll
    for (int j = 0; j < 8; j++) dstp[j] = srcp[j];
  }
}

// ---------------------------------------------------------------------------
// Fused depthwise 3x3 for K and V from bf16 NHWC tkv (2,61504,256).
//  K (ch 0..127)  -> bf16 NHWC kT (direct)
//  V (ch 128..255)-> bf16 NCHW vv via LDS [ch][px] stride-66 (conflict-free)
// Block = (64-px strip, 2-row group, b); lane = channel. px loop processes
// 4 px/iter with software-pipelined 12-load batches (nA/nB) for MLP.
// Grid (4, 124, 2), 256 thr.
// ---------------------------------------------------------------------------
__global__ __launch_bounds__(256) void dwconv_kv_kernel(const unsigned short* __restrict__ tkv,
                                                        const float* __restrict__ w,
                                                        unsigned short* __restrict__ kT,
                                                        unsigned short* __restrict__ vv) {
  int strip = blockIdx.x;                      // 0..3
  int x0 = (strip == 3) ? 184 : strip * 64;
  int g = blockIdx.y;                          // 0..123
  int b = blockIdx.z;
  int c = threadIdx.x & 127;
  int half = threadIdx.x >> 7;                 // 0 = K, 1 = V
  int ch = half * 128 + c;
  const float* wc = w + ch * 9;
  float w00 = wc[0], w01 = wc[1], w02 = wc[2];
  float w10 = wc[3], w11 = wc[4], w12 = wc[5];
  float w20 = wc[6], w21 = wc[7], w22 = wc[8];
  const unsigned short* src = tkv + ((size_t)b * HXW) * 256 + ch;
  __shared__ unsigned short vt[128 * 66];      // [ch][px] stride 66 (16.9 KB)

#pragma unroll 1
  for (int r = 0; r < 2; r++) {
    int hy = g * 2 + r;
    bool vtop = hy > 0, vbot = hy < HX - 1;
    const unsigned short* r0 = src + ((size_t)(hy - 1) * HX) * 256;
    const unsigned short* r1 = src + ((size_t)hy * HX) * 256;
    const unsigned short* r2 = src + ((size_t)(hy + 1) * HX) * 256;
    float a0, a1, a2, b0, b1, b2;
    if (x0 > 0) {
      a0 = vtop ? bf2f(r0[(size_t)(x0 - 1) * 256]) : 0.0f;
      a1 = bf2f(r1[(size_t)(x0 - 1) * 256]);
      a2 = vbot ? bf2f(r2[(size_t)(x0 - 1) * 256]) : 0.0f;
    } else { a0 = a1 = a2 = 0.0f; }
    b0 = vtop ? bf2f(r0[(size_t)x0 * 256]) : 0.0f;
    b1 = bf2f(r1[(size_t)x0 * 256]);
    b2 = vbot ? bf2f(r2[(size_t)x0 * 256]) : 0.0f;

    float nA[12], nB[12];
#define LOADB(DST, PX4)                                                        \
    {                                                                          \
      _Pragma("unroll")                                                        \
      for (int j = 0; j < 4; j++) {                                            \
        int xn = x0 + (PX4) + j + 1;                                           \
        if (xn < HX) {                                                         \
          DST[j * 3 + 0] = vtop ? bf2f(r0[(size_t)xn * 256]) : 0.0f;           \
          DST[j * 3 + 1] = bf2f(r1[(size_t)xn * 256]);                         \
          DST[j * 3 + 2] = vbot ? bf2f(r2[(size_t)xn * 256]) : 0.0f;           \
        } else {                                                               \
          DST[j * 3 + 0] = DST[j * 3 + 1] = DST[j * 3 + 2] = 0.0f;             \
        }                                                                      \
      }                                                                        \
    }
#define COMPB(SRCN, PX4)                                                       \
    {                                                                          \
      _Pragma("unroll")                                                        \
      for (int j = 0; j < 4; j++) {                                            \
        float s = w00 * a0 + w01 * b0 + w02 * SRCN[j * 3 + 0] +                \
                  w10 * a1 + w11 * b1 + w12 * SRCN[j * 3 + 1] +                \
                  w20 * a2 + w21 * b2 + w22 * SRCN[j * 3 + 2];                 \
        unsigned short sb = f2bf(s);                                           \
        if (half == 0) {                                                       \
          kT[((size_t)b * HXW + (size_t)hy * HX + x0 + (PX4) + j) * 128 + c] = sb; \
        } else {                                                               \
          vt[c * 66 + (PX4) + j] = sb;                                         \
        }                                                                      \
        a0 = b0; a1 = b1; a2 = b2;                                             \
        b0 = SRCN[j * 3 + 0]; b1 = SRCN[j * 3 + 1]; b2 = SRCN[j * 3 + 2];      \
      }                                                                        \
    }

    LOADB(nA, 0);
#pragma unroll 1
    for (int px4 = 0; px4 < 64; px4 += 8) {
      if (px4 + 4 < 64) LOADB(nB, px4 + 4);
      COMPB(nA, px4);
      if (px4 + 8 < 64) LOADB(nA, px4 + 8);
      COMPB(nB, px4 + 4);
    }
#undef LOADB
#undef COMPB
    __syncthreads();
    {  // cooperative NCHW store of the V row: lane = channel, conflict-free
      int cv = threadIdx.x & 127;
      int phx = (threadIdx.x >> 7) * 32;
      unsigned short* dst = vv + ((size_t)(b * 128 + cv)) * HXW + (size_t)hy * HX + x0 + phx;
      const unsigned short* srcv = vt + cv * 66 + phx;
#pragma unroll
      for (int jj = 0; jj < 8; jj++) {
        uint2 d;
        d.x = (uint32_t)srcv[jj * 4 + 0] | ((uint32_t)srcv[jj * 4 + 1] << 16);
        d.y = (uint32_t)srcv[jj * 4 + 2] | ((uint32_t)srcv[jj * 4 + 3] << 16);
        *(uint2*)(dst + jj * 4) = d;
      }
    }
    __syncthreads();
  }
}

// ---------------------------------------------------------------------------
// 1x1 conv tiled SGEMM (fp32) — small tensors (q path, output projection).
// ---------------------------------------------------------------------------
template <int O>
__global__ __launch_bounds__(256) void conv1_kernel(const float* __restrict__ x,
                                                    const float* __restrict__ w,
                                                    float* __restrict__ y, int HW) {
  constexpr int K = 128;
  constexpr int BK = 32;
  __shared__ __align__(16) float ws_s[BK][64];
  __shared__ __align__(16) float xs_s[BK][64];
  int b = blockIdx.z;
  int o0 = blockIdx.y * 64;
  int p0 = blockIdx.x * 64;
  const float* xb = x + (size_t)b * K * HW;
  int tx = threadIdx.x & 15;
  int ty = threadIdx.x >> 4;
  float acc[4][4] = {};
  int lo = threadIdx.x >> 2;
  int lk = (threadIdx.x & 3) * 8;
  int lc = threadIdx.x >> 3;
  int lp = (threadIdx.x & 7) * 8;

  for (int k0 = 0; k0 < K; k0 += BK) {
    __syncthreads();
    {
      const float* wp = w + (size_t)(o0 + lo) * K + k0 + lk;
      float4 a = *(const float4*)wp;
      float4 bq = *(const float4*)(wp + 4);
      ws_s[lk + 0][lo] = a.x;  ws_s[lk + 1][lo] = a.y;
      ws_s[lk + 2][lo] = a.z;  ws_s[lk + 3][lo] = a.w;
      ws_s[lk + 4][lo] = bq.x; ws_s[lk + 5][lo] = bq.y;
      ws_s[lk + 6][lo] = bq.z; ws_s[lk + 7][lo] = bq.w;
    }
    {
      int p = p0 + lp;
      const float* xp = xb + (size_t)(k0 + lc) * HW;
      float4 a, bq;
      if (p + 7 < HW) {
        a = *(const float4*)(xp + p);
        bq = *(const float4*)(xp + p + 4);
      } else {
        float tv[8];
#pragma unroll
        for (int j = 0; j < 8; j++) tv[j] = (p + j < HW) ? xp[p + j] : 0.0f;
        a = make_float4(tv[0], tv[1], tv[2], tv[3]);
        bq = make_float4(tv[4], tv[5], tv[6], tv[7]);
      }
      *(float4*)&xs_s[lc][lp] = a;
      *(float4*)&xs_s[lc][lp + 4] = bq;
    }
    __syncthreads();
#pragma unroll
    for (int k = 0; k < BK; k++) {
      float4 wv = *(const float4*)&ws_s[k][ty * 4];
      float4 xv = *(const float4*)&xs_s[k][tx * 4];
      acc[0][0] += wv.x * xv.x; acc[0][1] += wv.x * xv.y; acc[0][2] += wv.x * xv.z; acc[0][3] += wv.x * xv.w;
      acc[1][0] += wv.y * xv.x; acc[1][1] += wv.y * xv.y; acc[1][2] += wv.y * xv.z; acc[1][3] += wv.y * xv.w;
      acc[2][0] += wv.z * xv.x; acc[2][1] += wv.z * xv.y; acc[2][2] += wv.z * xv.z; acc[2][3] += wv.z * xv.w;
      acc[3][0] += wv.w * xv.x; acc[3][1] += wv.w * xv.y; acc[3][2] += wv.w * xv.z; acc[3][3] += wv.w * xv.w;
    }
  }
  int p = p0 + tx * 4;
  float* yb = y + (size_t)b * O * HW + (size_t)(o0 + ty * 4) * HW;
#pragma unroll
  for (int j = 0; j < 4; j++) {
    float* yr = yb + (size_t)j * HW + p;
    if (p + 3 < HW) {
      *(float4*)yr = make_float4(acc[j][0], acc[j][1], acc[j][2], acc[j][3]);
    } else {
#pragma unroll
      for (int e = 0; e < 4; e++) if (p + e < HW) yr[e] = acc[j][e];
    }
  }
}

// ---------------------------------------------------------------------------
// MFMA windowed attention, head-pair blocks. 512 thr = 8 waves.
// ---------------------------------------------------------------------------
__global__ __launch_bounds__(512) void attn_mfma_kernel(
    const unsigned short* __restrict__ qn,   // (2,62,62,128) bf16, pre-scaled
    const unsigned short* __restrict__ kT,   // (2,248,248,128) bf16 NHWC
    const unsigned short* __restrict__ vp,   // (2,128,248,248) bf16 NCHW
    float* __restrict__ o) {
  int n = blockIdx.x, hp = blockIdx.y, b = blockIdx.z;
  int wi = n / 10, wj = n % 10;
  int wave = threadIdx.x >> 6;
  int hd = wave & 1, oct = wave >> 1;
  int h = hp * 2 + hd;
  int lane = threadIdx.x & 63;
  int quad = lane >> 4;
  int l15 = lane & 15;
  int y0 = 24 * wi, x0 = 24 * wj;

  __shared__ __align__(16) unsigned short lds[20480];  // 40,960 B
  unsigned short* Pw = lds + wave * 2560;              // [q][40keys] 5KB/wave

  bf16x8 QB[4];
#pragma unroll
  for (int nt = 0; nt < 4; nt++) {
    int qq = nt * 16 + l15;
    int qy = 6 * wi + (qq >> 3), qx = 6 * wj + (qq & 7);
    QB[nt] = __builtin_bit_cast(bf16x8,
        *(const uint4*)(qn + ((size_t)(b * HSW + qy * HS + qx)) * 128 + h * 32 + quad * 8));
  }

  f32x4 Oacc[2][4];
#pragma unroll
  for (int a = 0; a < 2; a++)
#pragma unroll
    for (int c = 0; c < 4; c++) Oacc[a][c] = f32x4{0.f, 0.f, 0.f, 0.f};
  float lsum[4] = {0.f, 0.f, 0.f, 0.f};

  const unsigned short* kb = kT + (size_t)b * HXW * 128 + h * 32;
  const unsigned short* vb = vp + ((size_t)(b * 128 + h * 32)) * HXW;
  const f32x4 zf = {0.f, 0.f, 0.f, 0.f};

#define LOADROW(r, K0, K1, V0, V1)                                              \
  {                                                                             \
    int y = y0 + (r);                                                           \
    const unsigned short* krow = kb + ((size_t)(y * HX + x0)) * 128;            \
    K0 = *(const uint4*)(krow + (size_t)l15 * 128 + quad * 8);                  \
    K1 = *(const uint4*)(krow + (size_t)(16 + l15) * 128 + quad * 8);           \
    const unsigned short* vrow = vb + (size_t)y * HX + x0 + quad * 8;           \
    V0 = *(const uint4*)(vrow + (size_t)l15 * HXW);                             \
    V1 = *(const uint4*)(vrow + (size_t)(16 + l15) * HXW);                      \
  }

  auto compute = [&](uint4 k0, uint4 k1, uint4 v0, uint4 v1) {
    bf16x8 KA0 = __builtin_bit_cast(bf16x8, k0);
    bf16x8 KA1 = __builtin_bit_cast(bf16x8, k1);
    bf16x8 VA0 = __builtin_bit_cast(bf16x8, v0);
    bf16x8 VA1 = __builtin_bit_cast(bf16x8, v1);
    f32x4 S[2][4];
#pragma unroll
    for (int nt = 0; nt < 4; nt++) {
      S[0][nt] = __builtin_amdgcn_mfma_f32_16x16x32_bf16(KA0, QB[nt], zf, 0, 0, 0);
      S[1][nt] = __builtin_amdgcn_mfma_f32_16x16x32_bf16(KA1, QB[nt], zf, 0, 0, 0);
    }
#pragma unroll
    for (int nt = 0; nt < 4; nt++) {
      float pv[2][4];
      float cs = 0.f;
#pragma unroll
      for (int mt = 0; mt < 2; mt++)
#pragma unroll
        for (int r = 0; r < 4; r++) {
          pv[mt][r] = __expf(S[mt][nt][r]);
          cs += pv[mt][r];
        }
      lsum[nt] += cs;
#pragma unroll
      for (int mt = 0; mt < 2; mt++) {
        uint2 d;
        d.x = (uint32_t)f2bf(pv[mt][0]) | ((uint32_t)f2bf(pv[mt][1]) << 16);
        d.y = (uint32_t)f2bf(pv[mt][2]) | ((uint32_t)f2bf(pv[mt][3]) << 16);
        *(uint2*)(Pw + (16 * nt + l15) * 40 + 16 * mt + quad * 4) = d;
      }
    }
#pragma unroll
    for (int nt = 0; nt < 4; nt++) {
      bf16x8 PB = __builtin_bit_cast(bf16x8, *(const uint4*)(Pw + (16 * nt + l15) * 40 + quad * 8));
      Oacc[0][nt] = __builtin_amdgcn_mfma_f32_16x16x32_bf16(VA0, PB, Oacc[0][nt], 0, 0, 0);
      Oacc[1][nt] = __builtin_amdgcn_mfma_f32_16x16x32_bf16(VA1, PB, Oacc[1][nt], 0, 0, 0);
    }
  };

  int rbase = oct * 8;
  uint4 kA0, kA1, vA0, vA1, kB0, kB1, vB0, vB1;
  LOADROW(rbase + 0, kA0, kA1, vA0, vA1);
  LOADROW(rbase + 1, kB0, kB1, vB0, vB1);
#pragma unroll 1
  for (int r = 0; r < 8; r += 2) {
    if (r + 2 < 8) {
      compute(kA0, kA1, vA0, vA1);
      LOADROW(rbase + r + 2, kA0, kA1, vA0, vA1);
      compute(kB0, kB1, vB0, vB1);
      LOADROW(rbase + r + 3, kB0, kB1, vB0, vB1);
    } else {
      compute(kA0, kA1, vA0, vA1);
      compute(kB0, kB1, vB0, vB1);
    }
  }
#undef LOADROW

#pragma unroll
  for (int nt = 0; nt < 4; nt++) {
    lsum[nt] += __shfl_xor(lsum[nt], 16, 64);
    lsum[nt] += __shfl_xor(lsum[nt], 32, 64);
  }

  float* mO = (float*)lds;                 // [oct][32ch][64q]  32 KB
  float* mL = (float*)(lds + 16384);       // [oct][64q]
#pragma unroll 1
  for (int p = 0; p < 2; p++) {
    __syncthreads();
    if (hd == p) {
#pragma unroll
      for (int mt = 0; mt < 2; mt++)
#pragma unroll
        for (int nt = 0; nt < 4; nt++)
#pragma unroll
          for (int r = 0; r < 4; r++)
            mO[oct * 2048 + (16 * mt + quad * 4 + r) * 64 + 16 * nt + l15] = Oacc[mt][nt][r];
      if (quad == 0) {
#pragma unroll
        for (int nt = 0; nt < 4; nt++) mL[oct * 64 + nt * 16 + l15] = lsum[nt];
      }
    }
    __syncthreads();
    {
      int q = threadIdx.x & 63;
      int cg = threadIdx.x >> 6;  // 0..7 -> 4 ch each
      float inv = 1.0f / (mL[q] + mL[64 + q] + mL[128 + q] + mL[192 + q]);
      float* ob = o + (((size_t)(b * 100 + n)) * 128 + (hp * 2 + p) * 32 + cg * 4) * 64 + q;
#pragma unroll
      for (int e = 0; e < 4; e++) {
        int ch = cg * 4 + e;
        float s = mO[ch * 64 + q] + mO[2048 + ch * 64 + q] +
                  mO[4096 + ch * 64 + q] + mO[6144 + ch * 64 + q];
        ob[(size_t)e * 64] = s * inv;
      }
    }
  }
}

// ---------------------------------------------------------------------------
// Reverse: scatter-average overlapping 8x8 windows (step 6) into (2,128,62,62)
// ---------------------------------------------------------------------------
__global__ void reverse_kernel(const float* __restrict__ win, float* __restrict__ out) {
  int i = blockIdx.x * 256 + threadIdx.x;
  const int total = 2 * 128 * HSW;
  if (i >= total) return;
  int x = i % HS;
  int t = i / HS;
  int y = t % HS;
  t /= HS;
  int c = t % 128;
  int b = t / 128;
  int wi0 = (y >= 7) ? (y - 2) / 6 : 0;
  int wi1 = min(9, y / 6);
  int wj0 = (x >= 7) ? (x - 2) / 6 : 0;
  int wj1 = min(9, x / 6);
  float s = 0.0f;
  for (int wi = wi0; wi <= wi1; wi++)
    for (int wj = wj0; wj <= wj1; wj++) {
      int di = y - 6 * wi, dj = x - 6 * wj;
      s += win[(((size_t)(b * 100 + wi * 10 + wj)) * 128 + c) * 64 + di * 8 + dj];
    }
  float cnt = (float)((wi1 - wi0 + 1) * (wj1 - wj0 + 1));
  out[i] = s / cnt;
}

// ---------------------------------------------------------------------------
extern "C" void kernel_launch(void* const* d_in, const int* in_sizes, int n_in,
                              void* d_out, int out_size, void* d_ws, size_t ws_size,
                              hipStream_t stream) {
  const float* x      = (const float*)d_in[0];
  const float* sp     = (const float*)d_in[1];
  const float* w_pos  = (const float*)d_in[2];
  const float* b_pos  = (const float*)d_in[3];
  const float* w_q    = (const float*)d_in[4];
  const float* w_qdw  = (const float*)d_in[5];
  const float* w_kv   = (const float*)d_in[6];
  const float* w_kvdw = (const float*)d_in[7];
  const float* w_out  = (const float*)d_in[8];
  float* out = (float*)d_out;

  const size_t N_x   = (size_t)2 * 128 * HXW;  // 15,745,024
  const size_t N_t   = (size_t)2 * 256 * HXW;  // tkv bf16 elements
  const size_t N_s   = (size_t)2 * 128 * HSW;
  const size_t N_att = (size_t)2 * 100 * 128 * 64;

  float* ws = (float*)d_ws;
  // region A: [0, N_x floats) = 2*N_x ushorts: xpb (N_x ushorts, dead after
  // conv1_kv_mfma) -> kT; then vv in the second half.
  unsigned short* xpb = (unsigned short*)ws;
  unsigned short* kT  = (unsigned short*)ws;
  unsigned short* vv  = kT + N_x;
  // region B: tkv bf16 NHWC; att/rev alias after dwconv_kv.
  unsigned short* tkv = (unsigned short*)(ws + N_x);
  float* att = ws + N_x;
  float* rev = att + N_att;
  // region C: small tensors
  float* spp = ws + N_x + N_t / 2;
  float* tq  = spp + N_s;
  unsigned short* qn  = (unsigned short*)(tq + N_s);
  unsigned short* wkb = qn + N_s;              // 32768 ushorts
  (void)ws_size; (void)in_sizes; (void)n_in; (void)out_size;

  // 0. wkb = bf16(w_kv)
  cvt_bf16_kernel<<<128, 256, 0, stream>>>(w_kv, wkb, 256 * 128);
  // 1. xpb = bf16(x + dwconv3(x, w_pos, b_pos))   (bf16 NCHW)
  {
    int total4 = (int)(N_x / 4);
    dwconv4_bf16_kernel<<<(total4 + 255) / 256, 256, 0, stream>>>(x, w_pos, b_pos, xpb, total4);
  }
  // 2. spp = sp + dwconv3(sp, w_pos, b_pos)
  {
    int total = (int)N_s;
    dwconv3_kernel<<<(total + 255) / 256, 256, 0, stream>>>(sp, w_pos, b_pos, spp, 128, HS, HS, total, 1);
  }
  // 3. tq = conv1(spp, w_q)
  {
    int HW = HSW;
    dim3 grid((HW + 63) / 64, 2, 2);
    conv1_kernel<128><<<grid, 256, 0, stream>>>(spp, w_q, tq, HW);
  }
  // 4. qn = bf16_nhwc(dwconv3(tq, w_qdw)) * 32^-0.5
  {
    int total = (int)N_s;
    dwconv_q_kernel<<<(total + 255) / 256, 256, 0, stream>>>(tq, w_qdw, qn, total);
  }
  // 5. tkv = bf16_nhwc(mfma_conv1(xpb, wkb))   (xpb dead after)
  {
    dim3 grid(HXW / 64, 2);
    conv1_kv_mfma_kernel<<<grid, 256, 0, stream>>>(xpb, wkb, tkv);
  }
  // 6. kT (NHWC) + vv (NCHW) = bf16(dwconv3(tkv, w_kvdw))   (overwrites xpb)
  {
    dim3 grid(4, 124, 2);
    dwconv_kv_kernel<<<grid, 256, 0, stream>>>(tkv, w_kvdw, kT, vv);
  }
  // 7. attention -> att (2,100,128,64)
  {
    dim3 grid(100, 2, 2);
    attn_mfma_kernel<<<grid, 512, 0, stream>>>(qn, kT, vv, att);
  }
  // 8. rev = reverse(att)
  {
    int total = (int)N_s;
    reverse_kernel<<<(total + 255) / 256, 256, 0, stream>>>(att, rev);
  }
  // 9. out = conv1(rev, w_out)
  {
    int HW = HSW;
    dim3 grid((HW + 63) / 64, 2, 2);
    conv1_kernel<128><<<grid, 256, 0, stream>>>(rev, w_out, out, HW);
  }
}

// Round 10
// 380.958 us; speedup vs baseline: 1.5916x; 1.0549x over previous
//
#include <hip/hip_runtime.h>
#include <cstdint>

#define HS 62
#define HX 248
#define HXW (HX * HX)  // 61504
#define HSW (HS * HS)  // 3844

typedef __attribute__((ext_vector_type(8))) short bf16x8;
typedef __attribute__((ext_vector_type(4))) float f32x4;

static __device__ __forceinline__ unsigned short f2bf(float f) {
  uint32_t u = __builtin_bit_cast(uint32_t, f);
  u += 0x7fff + ((u >> 16) & 1);  // RNE
  return (unsigned short)(u >> 16);
}
static __device__ __forceinline__ float bf2f(unsigned short u) {
  uint32_t x = (uint32_t)u << 16;
  return __builtin_bit_cast(float, x);
}
static __device__ __forceinline__ float bflo(uint32_t u) {
  return __builtin_bit_cast(float, u << 16);
}
static __device__ __forceinline__ float bfhi(uint32_t u) {
  return __builtin_bit_cast(float, u & 0xffff0000u);
}

// ---------------------------------------------------------------------------
// Depthwise 3x3 scalar (62x62 tensors), fp32 out, bias+residual.
// ---------------------------------------------------------------------------
__global__ void dwconv3_kernel(const float* __restrict__ x, const float* __restrict__ w,
                               const float* __restrict__ bias, float* __restrict__ y,
                               int C, int H, int W, int total, int residual) {
  int i = blockIdx.x * 256 + threadIdx.x;
  if (i >= total) return;
  int wx = i % W;
  int t = i / W;
  int hy = t % H;
  int bc = t / H;
  int c = bc % C;
  const float* xb = x + (size_t)bc * H * W;
  const float* wc = w + c * 9;
  float s = bias ? bias[c] : 0.0f;
  for (int di = -1; di <= 1; di++) {
    int h2 = hy + di;
    if (h2 < 0 || h2 >= H) continue;
    for (int dj = -1; dj <= 1; dj++) {
      int w2 = wx + dj;
      if (w2 < 0 || w2 >= W) continue;
      s += xb[(size_t)h2 * W + w2] * wc[(di + 1) * 3 + (dj + 1)];
    }
  }
  if (residual) s += xb[(size_t)hy * W + wx];
  y[i] = s;
}

// ---------------------------------------------------------------------------
// Depthwise 3x3 x-path: fp32 NCHW in -> bf16 NCHW out, residual. 4 px/thread.
// ---------------------------------------------------------------------------
__global__ void dwconv4_bf16_kernel(const float* __restrict__ x, const float* __restrict__ w,
                                    const float* __restrict__ bias,
                                    unsigned short* __restrict__ y, int total4) {
  int i = blockIdx.x * 256 + threadIdx.x;
  if (i >= total4) return;
  int W4 = HX >> 2;
  int wq = (i % W4) * 4;
  int t = i / W4;
  int hy = t % HX;
  int bc = t / HX;
  int c = bc & 127;
  const float* xb = x + (size_t)bc * HXW;
  const float* wc = w + c * 9;
  float bv = bias[c];
  float s0 = bv, s1 = bv, s2 = bv, s3 = bv;
  for (int di = -1; di <= 1; di++) {
    int h2 = hy + di;
    if (h2 < 0 || h2 >= HX) continue;
    const float* row = xb + (size_t)h2 * HX + wq;
    float4 cv = *(const float4*)row;
    float lf = (wq > 0) ? row[-1] : 0.0f;
    float rt = (wq + 4 < HX) ? row[4] : 0.0f;
    float w0 = wc[(di + 1) * 3 + 0];
    float w1 = wc[(di + 1) * 3 + 1];
    float w2 = wc[(di + 1) * 3 + 2];
    s0 += w0 * lf   + w1 * cv.x + w2 * cv.y;
    s1 += w0 * cv.x + w1 * cv.y + w2 * cv.z;
    s2 += w0 * cv.y + w1 * cv.z + w2 * cv.w;
    s3 += w0 * cv.z + w1 * cv.w + w2 * rt;
  }
  {
    float4 cc = *(const float4*)(xb + (size_t)hy * HX + wq);
    s0 += cc.x; s1 += cc.y; s2 += cc.z; s3 += cc.w;
  }
  uint2 d;
  d.x = (uint32_t)f2bf(s0) | ((uint32_t)f2bf(s1) << 16);
  d.y = (uint32_t)f2bf(s2) | ((uint32_t)f2bf(s3) << 16);
  *(uint2*)(y + (size_t)bc * HXW + (size_t)hy * HX + wq) = d;
}

// ---------------------------------------------------------------------------
// fp32 -> bf16 flat convert (for w_kv).
// ---------------------------------------------------------------------------
__global__ void cvt_bf16_kernel(const float* __restrict__ src, unsigned short* __restrict__ dst,
                                int n) {
  int i = blockIdx.x * 256 + threadIdx.x;
  if (i < n) dst[i] = f2bf(src[i]);
}

// ---------------------------------------------------------------------------
// Depthwise 3x3 q path: fp32 NCHW in -> bf16 NHWC out, pre-scaled by 32^-0.5.
// ---------------------------------------------------------------------------
__global__ void dwconv_q_kernel(const float* __restrict__ x, const float* __restrict__ w,
                                unsigned short* __restrict__ qn, int total) {
  int i = blockIdx.x * 256 + threadIdx.x;
  if (i >= total) return;
  int wx = i % HS;
  int t = i / HS;
  int hy = t % HS;
  int bc = t / HS;
  int c = bc & 127;
  int b = bc >> 7;
  const float* xb = x + (size_t)bc * HSW;
  const float* wc = w + c * 9;
  float s = 0.0f;
  for (int di = -1; di <= 1; di++) {
    int h2 = hy + di;
    if (h2 < 0 || h2 >= HS) continue;
    for (int dj = -1; dj <= 1; dj++) {
      int w2 = wx + dj;
      if (w2 < 0 || w2 >= HS) continue;
      s += xb[(size_t)h2 * HS + w2] * wc[(di + 1) * 3 + (dj + 1)];
    }
  }
  qn[((size_t)(b * HSW + hy * HS + wx)) * 128 + c] = f2bf(s * 0.17677669529663688f);
}

// ---------------------------------------------------------------------------
// MFMA 1x1 conv kv path (unchanged from round 9).
// ---------------------------------------------------------------------------
__global__ __launch_bounds__(256) void conv1_kv_mfma_kernel(
    const unsigned short* __restrict__ xpb,  // (2,128,61504) bf16 NCHW
    const unsigned short* __restrict__ wkb,  // (256,128) bf16
    unsigned short* __restrict__ y) {        // (2,61504,256) bf16 NHWC
  int b = blockIdx.y;
  int p0 = blockIdx.x * 64;
  int tid = threadIdx.x;
  int wave = tid >> 6, lane = tid & 63, quad = lane >> 4, l15 = lane & 15;
  __shared__ __align__(16) unsigned short lds[64 * 264];  // 33,792 B

  {
    int c = tid >> 1, half = tid & 1;
    const unsigned short* src = xpb + ((size_t)(b * 128 + c)) * HXW + p0 + half * 32;
#pragma unroll
    for (int j = 0; j < 8; j++) {
      uint2 v = *(const uint2*)(src + j * 4);
      int px = half * 32 + j * 4;
      lds[(px + 0) * 136 + c] = (unsigned short)(v.x & 0xffff);
      lds[(px + 1) * 136 + c] = (unsigned short)(v.x >> 16);
      lds[(px + 2) * 136 + c] = (unsigned short)(v.y & 0xffff);
      lds[(px + 3) * 136 + c] = (unsigned short)(v.y >> 16);
    }
  }
  __syncthreads();
  bf16x8 A[4];
#pragma unroll
  for (int kb = 0; kb < 4; kb++)
    A[kb] = __builtin_bit_cast(bf16x8,
        *(const uint4*)&lds[(wave * 16 + l15) * 136 + kb * 32 + quad * 8]);
  __syncthreads();

  const f32x4 zf = {0.f, 0.f, 0.f, 0.f};
#pragma unroll 1
  for (int ot = 0; ot < 16; ot++) {
    const unsigned short* wb = wkb + (size_t)(ot * 16 + l15) * 128 + quad * 8;
    f32x4 D = zf;
#pragma unroll
    for (int kb = 0; kb < 4; kb++) {
      bf16x8 B = __builtin_bit_cast(bf16x8, *(const uint4*)(wb + kb * 32));
      D = __builtin_amdgcn_mfma_f32_16x16x32_bf16(A[kb], B, D, 0, 0, 0);
    }
#pragma unroll
    for (int r = 0; r < 4; r++)
      lds[(wave * 16 + quad * 4 + r) * 264 + ot * 16 + l15] = f2bf(D[r]);
  }
  __syncthreads();
  {
    int px = tid >> 2, og = (tid & 3) * 64;
    const uint4* srcp = (const uint4*)&lds[px * 264 + og];
    uint4* dstp = (uint4*)(y + ((size_t)b * HXW + p0 + px) * 256 + og);
#pragma unroll
    for (int j = 0; j < 8; j++) dstp[j] = srcp[j];
  }
}

// ---------------------------------------------------------------------------
// Fused depthwise 3x3 K/V from bf16 NHWC tkv, channel-quad lanes.
// Thread = (cq = tid&63 -> 4 channels, pg = tid>>6 -> pixels pg, pg+4, ...).
// Every load is uint2 (8 B/lane; a wave covers one full 512 B pixel record).
// 9 independent loads per pixel -> MLP without software pipelining.
//  K (cq<32):  store uint2 direct to NHWC kT (256 B/wave coalesced)
//  V (cq>=32): LDS [ch][px] stride-67 transpose -> NCHW vv
// Grid (4, 124, 2), 256 thr.
// ---------------------------------------------------------------------------
__global__ __launch_bounds__(256) void dwconv_kv_kernel(const unsigned short* __restrict__ tkv,
                                                        const float* __restrict__ w,
                                                        unsigned short* __restrict__ kT,
                                                        unsigned short* __restrict__ vv) {
  int strip = blockIdx.x;                      // 0..3
  int x0 = (strip == 3) ? 184 : strip * 64;
  int g = blockIdx.y;                          // 0..123
  int b = blockIdx.z;
  int tid = threadIdx.x;
  int cq = tid & 63;                           // channel quad (lane)
  int pg = tid >> 6;                           // 0..3 (wave-uniform)
  int ch0 = cq * 4;
  float wr[4][9];
#pragma unroll
  for (int j = 0; j < 4; j++)
#pragma unroll
    for (int t9 = 0; t9 < 9; t9++) wr[j][t9] = w[(ch0 + j) * 9 + t9];

  __shared__ unsigned short vt[128 * 67];      // [ch][px] stride 67
  const unsigned short* base = tkv + (size_t)b * HXW * 256 + ch0;
  const uint2 z2 = {0u, 0u};

#pragma unroll 1
  for (int r = 0; r < 2; r++) {
    int hy = g * 2 + r;
    bool vtop = hy > 0, vbot = hy < HX - 1;
    const unsigned short* r0 = base + ((size_t)(hy - 1) * HX) * 256;
    const unsigned short* r1 = base + ((size_t)hy * HX) * 256;
    const unsigned short* r2 = base + ((size_t)(hy + 1) * HX) * 256;

#pragma unroll 1
    for (int i = 0; i < 16; i++) {
      int px = pg + i * 4;      // 0..63, wave-uniform
      int xc = x0 + px;
      bool vl = xc > 0, vr = xc < HX - 1;
      size_t off = (size_t)xc * 256;
      // 9 independent uint2 loads
      uint2 u00 = (vtop && vl) ? *(const uint2*)(r0 + off - 256) : z2;
      uint2 u01 = vtop ? *(const uint2*)(r0 + off) : z2;
      uint2 u02 = (vtop && vr) ? *(const uint2*)(r0 + off + 256) : z2;
      uint2 u10 = vl ? *(const uint2*)(r1 + off - 256) : z2;
      uint2 u11 = *(const uint2*)(r1 + off);
      uint2 u12 = vr ? *(const uint2*)(r1 + off + 256) : z2;
      uint2 u20 = (vbot && vl) ? *(const uint2*)(r2 + off - 256) : z2;
      uint2 u21 = vbot ? *(const uint2*)(r2 + off) : z2;
      uint2 u22 = (vbot && vr) ? *(const uint2*)(r2 + off + 256) : z2;

      float o0 = 0.f, o1 = 0.f, o2 = 0.f, o3 = 0.f;
#define TAP(U, T)                                                              \
      o0 += wr[0][T] * bflo(U.x); o1 += wr[1][T] * bfhi(U.x);                  \
      o2 += wr[2][T] * bflo(U.y); o3 += wr[3][T] * bfhi(U.y);
      TAP(u00, 0) TAP(u01, 1) TAP(u02, 2)
      TAP(u10, 3) TAP(u11, 4) TAP(u12, 5)
      TAP(u20, 6) TAP(u21, 7) TAP(u22, 8)
#undef TAP
      if (cq < 32) {
        uint2 d;
        d.x = (uint32_t)f2bf(o0) | ((uint32_t)f2bf(o1) << 16);
        d.y = (uint32_t)f2bf(o2) | ((uint32_t)f2bf(o3) << 16);
        *(uint2*)(kT + ((size_t)b * HXW + (size_t)hy * HX + xc) * 128 + ch0) = d;
      } else {
        int c0 = ch0 - 128;
        vt[(c0 + 0) * 67 + px] = f2bf(o0);
        vt[(c0 + 1) * 67 + px] = f2bf(o1);
        vt[(c0 + 2) * 67 + px] = f2bf(o2);
        vt[(c0 + 3) * 67 + px] = f2bf(o3);
      }
    }
    __syncthreads();
    {  // cooperative NCHW store of the V row
      int cv = tid & 127;
      int phx = (tid >> 7) * 32;
      unsigned short* dst = vv + ((size_t)(b * 128 + cv)) * HXW + (size_t)hy * HX + x0 + phx;
      const unsigned short* srcv = vt + cv * 67 + phx;
#pragma unroll
      for (int jj = 0; jj < 8; jj++) {
        uint2 d;
        d.x = (uint32_t)srcv[jj * 4 + 0] | ((uint32_t)srcv[jj * 4 + 1] << 16);
        d.y = (uint32_t)srcv[jj * 4 + 2] | ((uint32_t)srcv[jj * 4 + 3] << 16);
        *(uint2*)(dst + jj * 4) = d;
      }
    }
    __syncthreads();
  }
}

// ---------------------------------------------------------------------------
// 1x1 conv tiled SGEMM (fp32) — small tensors (q path, output projection).
// ---------------------------------------------------------------------------
template <int O>
__global__ __launch_bounds__(256) void conv1_kernel(const float* __restrict__ x,
                                                    const float* __restrict__ w,
                                                    float* __restrict__ y, int HW) {
  constexpr int K = 128;
  constexpr int BK = 32;
  __shared__ __align__(16) float ws_s[BK][64];
  __shared__ __align__(16) float xs_s[BK][64];
  int b = blockIdx.z;
  int o0 = blockIdx.y * 64;
  int p0 = blockIdx.x * 64;
  const float* xb = x + (size_t)b * K * HW;
  int tx = threadIdx.x & 15;
  int ty = threadIdx.x >> 4;
  float acc[4][4] = {};
  int lo = threadIdx.x >> 2;
  int lk = (threadIdx.x & 3) * 8;
  int lc = threadIdx.x >> 3;
  int lp = (threadIdx.x & 7) * 8;

  for (int k0 = 0; k0 < K; k0 += BK) {
    __syncthreads();
    {
      const float* wp = w + (size_t)(o0 + lo) * K + k0 + lk;
      float4 a = *(const float4*)wp;
      float4 bq = *(const float4*)(wp + 4);
      ws_s[lk + 0][lo] = a.x;  ws_s[lk + 1][lo] = a.y;
      ws_s[lk + 2][lo] = a.z;  ws_s[lk + 3][lo] = a.w;
      ws_s[lk + 4][lo] = bq.x; ws_s[lk + 5][lo] = bq.y;
      ws_s[lk + 6][lo] = bq.z; ws_s[lk + 7][lo] = bq.w;
    }
    {
      int p = p0 + lp;
      const float* xp = xb + (size_t)(k0 + lc) * HW;
      float4 a, bq;
      if (p + 7 < HW) {
        a = *(const float4*)(xp + p);
        bq = *(const float4*)(xp + p + 4);
      } else {
        float tv[8];
#pragma unroll
        for (int j = 0; j < 8; j++) tv[j] = (p + j < HW) ? xp[p + j] : 0.0f;
        a = make_float4(tv[0], tv[1], tv[2], tv[3]);
        bq = make_float4(tv[4], tv[5], tv[6], tv[7]);
      }
      *(float4*)&xs_s[lc][lp] = a;
      *(float4*)&xs_s[lc][lp + 4] = bq;
    }
    __syncthreads();
#pragma unroll
    for (int k = 0; k < BK; k++) {
      float4 wv = *(const float4*)&ws_s[k][ty * 4];
      float4 xv = *(const float4*)&xs_s[k][tx * 4];
      acc[0][0] += wv.x * xv.x; acc[0][1] += wv.x * xv.y; acc[0][2] += wv.x * xv.z; acc[0][3] += wv.x * xv.w;
      acc[1][0] += wv.y * xv.x; acc[1][1] += wv.y * xv.y; acc[1][2] += wv.y * xv.z; acc[1][3] += wv.y * xv.w;
      acc[2][0] += wv.z * xv.x; acc[2][1] += wv.z * xv.y; acc[2][2] += wv.z * xv.z; acc[2][3] += wv.z * xv.w;
      acc[3][0] += wv.w * xv.x; acc[3][1] += wv.w * xv.y; acc[3][2] += wv.w * xv.z; acc[3][3] += wv.w * xv.w;
    }
  }
  int p = p0 + tx * 4;
  float* yb = y + (size_t)b * O * HW + (size_t)(o0 + ty * 4) * HW;
#pragma unroll
  for (int j = 0; j < 4; j++) {
    float* yr = yb + (size_t)j * HW + p;
    if (p + 3 < HW) {
      *(float4*)yr = make_float4(acc[j][0], acc[j][1], acc[j][2], acc[j][3]);
    } else {
#pragma unroll
      for (int e = 0; e < 4; e++) if (p + e < HW) yr[e] = acc[j][e];
    }
  }
}

// ---------------------------------------------------------------------------
// MFMA windowed attention, head-pair blocks. 512 thr = 8 waves.
// ---------------------------------------------------------------------------
__global__ __launch_bounds__(512) void attn_mfma_kernel(
    const unsigned short* __restrict__ qn,   // (2,62,62,128) bf16, pre-scaled
    const unsigned short* __restrict__ kT,   // (2,248,248,128) bf16 NHWC
    const unsigned short* __restrict__ vp,   // (2,128,248,248) bf16 NCHW
    float* __restrict__ o) {
  int n = blockIdx.x, hp = blockIdx.y, b = blockIdx.z;
  int wi = n / 10, wj = n % 10;
  int wave = threadIdx.x >> 6;
  int hd = wave & 1, oct = wave >> 1;
  int h = hp * 2 + hd;
  int lane = threadIdx.x & 63;
  int quad = lane >> 4;
  int l15 = lane & 15;
  int y0 = 24 * wi, x0 = 24 * wj;

  __shared__ __align__(16) unsigned short lds[20480];  // 40,960 B
  unsigned short* Pw = lds + wave * 2560;              // [q][40keys] 5KB/wave

  bf16x8 QB[4];
#pragma unroll
  for (int nt = 0; nt < 4; nt++) {
    int qq = nt * 16 + l15;
    int qy = 6 * wi + (qq >> 3), qx = 6 * wj + (qq & 7);
    QB[nt] = __builtin_bit_cast(bf16x8,
        *(const uint4*)(qn + ((size_t)(b * HSW + qy * HS + qx)) * 128 + h * 32 + quad * 8));
  }

  f32x4 Oacc[2][4];
#pragma unroll
  for (int a = 0; a < 2; a++)
#pragma unroll
    for (int c = 0; c < 4; c++) Oacc[a][c] = f32x4{0.f, 0.f, 0.f, 0.f};
  float lsum[4] = {0.f, 0.f, 0.f, 0.f};

  const unsigned short* kb = kT + (size_t)b * HXW * 128 + h * 32;
  const unsigned short* vb = vp + ((size_t)(b * 128 + h * 32)) * HXW;
  const f32x4 zf = {0.f, 0.f, 0.f, 0.f};

#define LOADROW(r, K0, K1, V0, V1)                                              \
  {                                                                             \
    int y = y0 + (r);                                                           \
    const unsigned short* krow = kb + ((size_t)(y * HX + x0)) * 128;            \
    K0 = *(const uint4*)(krow + (size_t)l15 * 128 + quad * 8);                  \
    K1 = *(const uint4*)(krow + (size_t)(16 + l15) * 128 + quad * 8);           \
    const unsigned short* vrow = vb + (size_t)y * HX + x0 + quad * 8;           \
    V0 = *(const uint4*)(vrow + (size_t)l15 * HXW);                             \
    V1 = *(const uint4*)(vrow + (size_t)(16 + l15) * HXW);                      \
  }

  auto compute = [&](uint4 k0, uint4 k1, uint4 v0, uint4 v1) {
    bf16x8 KA0 = __builtin_bit_cast(bf16x8, k0);
    bf16x8 KA1 = __builtin_bit_cast(bf16x8, k1);
    bf16x8 VA0 = __builtin_bit_cast(bf16x8, v0);
    bf16x8 VA1 = __builtin_bit_cast(bf16x8, v1);
    f32x4 S[2][4];
#pragma unroll
    for (int nt = 0; nt < 4; nt++) {
      S[0][nt] = __builtin_amdgcn_mfma_f32_16x16x32_bf16(KA0, QB[nt], zf, 0, 0, 0);
      S[1][nt] = __builtin_amdgcn_mfma_f32_16x16x32_bf16(KA1, QB[nt], zf, 0, 0, 0);
    }
#pragma unroll
    for (int nt = 0; nt < 4; nt++) {
      float pv[2][4];
      float cs = 0.f;
#pragma unroll
      for (int mt = 0; mt < 2; mt++)
#pragma unroll
        for (int r = 0; r < 4; r++) {
          pv[mt][r] = __expf(S[mt][nt][r]);
          cs += pv[mt][r];
        }
      lsum[nt] += cs;
#pragma unroll
      for (int mt = 0; mt < 2; mt++) {
        uint2 d;
        d.x = (uint32_t)f2bf(pv[mt][0]) | ((uint32_t)f2bf(pv[mt][1]) << 16);
        d.y = (uint32_t)f2bf(pv[mt][2]) | ((uint32_t)f2bf(pv[mt][3]) << 16);
        *(uint2*)(Pw + (16 * nt + l15) * 40 + 16 * mt + quad * 4) = d;
      }
    }
#pragma unroll
    for (int nt = 0; nt < 4; nt++) {
      bf16x8 PB = __builtin_bit_cast(bf16x8, *(const uint4*)(Pw + (16 * nt + l15) * 40 + quad * 8));
      Oacc[0][nt] = __builtin_amdgcn_mfma_f32_16x16x32_bf16(VA0, PB, Oacc[0][nt], 0, 0, 0);
      Oacc[1][nt] = __builtin_amdgcn_mfma_f32_16x16x32_bf16(VA1, PB, Oacc[1][nt], 0, 0, 0);
    }
  };

  int rbase = oct * 8;
  uint4 kA0, kA1, vA0, vA1, kB0, kB1, vB0, vB1;
  LOADROW(rbase + 0, kA0, kA1, vA0, vA1);
  LOADROW(rbase + 1, kB0, kB1, vB0, vB1);
#pragma unroll 1
  for (int r = 0; r < 8; r += 2) {
    if (r + 2 < 8) {
      compute(kA0, kA1, vA0, vA1);
      LOADROW(rbase + r + 2, kA0, kA1, vA0, vA1);
      compute(kB0, kB1, vB0, vB1);
      LOADROW(rbase + r + 3, kB0, kB1, vB0, vB1);
    } else {
      compute(kA0, kA1, vA0, vA1);
      compute(kB0, kB1, vB0, vB1);
    }
  }
#undef LOADROW

#pragma unroll
  for (int nt = 0; nt < 4; nt++) {
    lsum[nt] += __shfl_xor(lsum[nt], 16, 64);
    lsum[nt] += __shfl_xor(lsum[nt], 32, 64);
  }

  float* mO = (float*)lds;                 // [oct][32ch][64q]  32 KB
  float* mL = (float*)(lds + 16384);       // [oct][64q]
#pragma unroll 1
  for (int p = 0; p < 2; p++) {
    __syncthreads();
    if (hd == p) {
#pragma unroll
      for (int mt = 0; mt < 2; mt++)
#pragma unroll
        for (int nt = 0; nt < 4; nt++)
#pragma unroll
          for (int r = 0; r < 4; r++)
            mO[oct * 2048 + (16 * mt + quad * 4 + r) * 64 + 16 * nt + l15] = Oacc[mt][nt][r];
      if (quad == 0) {
#pragma unroll
        for (int nt = 0; nt < 4; nt++) mL[oct * 64 + nt * 16 + l15] = lsum[nt];
      }
    }
    __syncthreads();
    {
      int q = threadIdx.x & 63;
      int cg = threadIdx.x >> 6;  // 0..7 -> 4 ch each
      float inv = 1.0f / (mL[q] + mL[64 + q] + mL[128 + q] + mL[192 + q]);
      float* ob = o + (((size_t)(b * 100 + n)) * 128 + (hp * 2 + p) * 32 + cg * 4) * 64 + q;
#pragma unroll
      for (int e = 0; e < 4; e++) {
        int ch = cg * 4 + e;
        float s = mO[ch * 64 + q] + mO[2048 + ch * 64 + q] +
                  mO[4096 + ch * 64 + q] + mO[6144 + ch * 64 + q];
        ob[(size_t)e * 64] = s * inv;
      }
    }
  }
}

// ---------------------------------------------------------------------------
// Reverse: scatter-average overlapping 8x8 windows (step 6) into (2,128,62,62)
// ---------------------------------------------------------------------------
__global__ void reverse_kernel(const float* __restrict__ win, float* __restrict__ out) {
  int i = blockIdx.x * 256 + threadIdx.x;
  const int total = 2 * 128 * HSW;
  if (i >= total) return;
  int x = i % HS;
  int t = i / HS;
  int y = t % HS;
  t /= HS;
  int c = t % 128;
  int b = t / 128;
  int wi0 = (y >= 7) ? (y - 2) / 6 : 0;
  int wi1 = min(9, y / 6);
  int wj0 = (x >= 7) ? (x - 2) / 6 : 0;
  int wj1 = min(9, x / 6);
  float s = 0.0f;
  for (int wi = wi0; wi <= wi1; wi++)
    for (int wj = wj0; wj <= wj1; wj++) {
      int di = y - 6 * wi, dj = x - 6 * wj;
      s += win[(((size_t)(b * 100 + wi * 10 + wj)) * 128 + c) * 64 + di * 8 + dj];
    }
  float cnt = (float)((wi1 - wi0 + 1) * (wj1 - wj0 + 1));
  out[i] = s / cnt;
}

// ---------------------------------------------------------------------------
extern "C" void kernel_launch(void* const* d_in, const int* in_sizes, int n_in,
                              void* d_out, int out_size, void* d_ws, size_t ws_size,
                              hipStream_t stream) {
  const float* x      = (const float*)d_in[0];
  const float* sp     = (const float*)d_in[1];
  const float* w_pos  = (const float*)d_in[2];
  const float* b_pos  = (const float*)d_in[3];
  const float* w_q    = (const float*)d_in[4];
  const float* w_qdw  = (const float*)d_in[5];
  const float* w_kv   = (const float*)d_in[6];
  const float* w_kvdw = (const float*)d_in[7];
  const float* w_out  = (const float*)d_in[8];
  float* out = (float*)d_out;

  const size_t N_x   = (size_t)2 * 128 * HXW;  // 15,745,024
  const size_t N_t   = (size_t)2 * 256 * HXW;
  const size_t N_s   = (size_t)2 * 128 * HSW;
  const size_t N_att = (size_t)2 * 100 * 128 * 64;

  float* ws = (float*)d_ws;
  unsigned short* xpb = (unsigned short*)ws;
  unsigned short* kT  = (unsigned short*)ws;
  unsigned short* vv  = kT + N_x;
  unsigned short* tkv = (unsigned short*)(ws + N_x);
  float* att = ws + N_x;
  float* rev = att + N_att;
  float* spp = ws + N_x + N_t / 2;
  float* tq  = spp + N_s;
  unsigned short* qn  = (unsigned short*)(tq + N_s);
  unsigned short* wkb = qn + N_s;              // 32768 ushorts
  (void)ws_size; (void)in_sizes; (void)n_in; (void)out_size;

  // 0. wkb = bf16(w_kv)
  cvt_bf16_kernel<<<128, 256, 0, stream>>>(w_kv, wkb, 256 * 128);
  // 1. xpb = bf16(x + dwconv3(x, w_pos, b_pos))   (bf16 NCHW)
  {
    int total4 = (int)(N_x / 4);
    dwconv4_bf16_kernel<<<(total4 + 255) / 256, 256, 0, stream>>>(x, w_pos, b_pos, xpb, total4);
  }
  // 2. spp = sp + dwconv3(sp, w_pos, b_pos)
  {
    int total = (int)N_s;
    dwconv3_kernel<<<(total + 255) / 256, 256, 0, stream>>>(sp, w_pos, b_pos, spp, 128, HS, HS, total, 1);
  }
  // 3. tq = conv1(spp, w_q)
  {
    int HW = HSW;
    dim3 grid((HW + 63) / 64, 2, 2);
    conv1_kernel<128><<<grid, 256, 0, stream>>>(spp, w_q, tq, HW);
  }
  // 4. qn = bf16_nhwc(dwconv3(tq, w_qdw)) * 32^-0.5
  {
    int total = (int)N_s;
    dwconv_q_kernel<<<(total + 255) / 256, 256, 0, stream>>>(tq, w_qdw, qn, total);
  }
  // 5. tkv = bf16_nhwc(mfma_conv1(xpb, wkb))   (xpb dead after)
  {
    dim3 grid(HXW / 64, 2);
    conv1_kv_mfma_kernel<<<grid, 256, 0, stream>>>(xpb, wkb, tkv);
  }
  // 6. kT (NHWC) + vv (NCHW) = bf16(dwconv3(tkv, w_kvdw))   (overwrites xpb)
  {
    dim3 grid(4, 124, 2);
    dwconv_kv_kernel<<<grid, 256, 0, stream>>>(tkv, w_kvdw, kT, vv);
  }
  // 7. attention -> att (2,100,128,64)
  {
    dim3 grid(100, 2, 2);
    attn_mfma_kernel<<<grid, 512, 0, stream>>>(qn, kT, vv, att);
  }
  // 8. rev = reverse(att)
  {
    int total = (int)N_s;
    reverse_kernel<<<(total + 255) / 256, 256, 0, stream>>>(att, rev);
  }
  // 9. out = conv1(rev, w_out)
  {
    int HW = HSW;
    dim3 grid((HW + 63) / 64, 2, 2);
    conv1_kernel<128><<<grid, 256, 0, stream>>>(rev, w_out, out, HW);
  }
}

// Round 12
// 380.224 us; speedup vs baseline: 1.5946x; 1.0019x over previous
//
#include <hip/hip_runtime.h>
#include <cstdint>

#define HS 62
#define HX 248
#define HXW (HX * HX)  // 61504
#define HSW (HS * HS)  // 3844

typedef __attribute__((ext_vector_type(8))) short bf16x8;
typedef __attribute__((ext_vector_type(4))) float f32x4;

static __device__ __forceinline__ unsigned short f2bf(float f) {
  uint32_t u = __builtin_bit_cast(uint32_t, f);
  u += 0x7fff + ((u >> 16) & 1);  // RNE
  return (unsigned short)(u >> 16);
}
static __device__ __forceinline__ float bf2f(unsigned short u) {
  uint32_t x = (uint32_t)u << 16;
  return __builtin_bit_cast(float, x);
}
static __device__ __forceinline__ float bflo(uint32_t u) {
  return __builtin_bit_cast(float, u << 16);
}
static __device__ __forceinline__ float bfhi(uint32_t u) {
  return __builtin_bit_cast(float, u & 0xffff0000u);
}

// ---------------------------------------------------------------------------
// Depthwise 3x3 scalar (62x62 tensors), fp32 out, bias+residual.
// ---------------------------------------------------------------------------
__global__ void dwconv3_kernel(const float* __restrict__ x, const float* __restrict__ w,
                               const float* __restrict__ bias, float* __restrict__ y,
                               int C, int H, int W, int total, int residual) {
  int i = blockIdx.x * 256 + threadIdx.x;
  if (i >= total) return;
  int wx = i % W;
  int t = i / W;
  int hy = t % H;
  int bc = t / H;
  int c = bc % C;
  const float* xb = x + (size_t)bc * H * W;
  const float* wc = w + c * 9;
  float s = bias ? bias[c] : 0.0f;
  for (int di = -1; di <= 1; di++) {
    int h2 = hy + di;
    if (h2 < 0 || h2 >= H) continue;
    for (int dj = -1; dj <= 1; dj++) {
      int w2 = wx + dj;
      if (w2 < 0 || w2 >= W) continue;
      s += xb[(size_t)h2 * W + w2] * wc[(di + 1) * 3 + (dj + 1)];
    }
  }
  if (residual) s += xb[(size_t)hy * W + wx];
  y[i] = s;
}

// ---------------------------------------------------------------------------
// Depthwise 3x3 x-path: fp32 NCHW in -> bf16 NCHW out, residual. 4 px/thread.
// ---------------------------------------------------------------------------
__global__ void dwconv4_bf16_kernel(const float* __restrict__ x, const float* __restrict__ w,
                                    const float* __restrict__ bias,
                                    unsigned short* __restrict__ y, int total4) {
  int i = blockIdx.x * 256 + threadIdx.x;
  if (i >= total4) return;
  int W4 = HX >> 2;
  int wq = (i % W4) * 4;
  int t = i / W4;
  int hy = t % HX;
  int bc = t / HX;
  int c = bc & 127;
  const float* xb = x + (size_t)bc * HXW;
  const float* wc = w + c * 9;
  float bv = bias[c];
  float s0 = bv, s1 = bv, s2 = bv, s3 = bv;
  for (int di = -1; di <= 1; di++) {
    int h2 = hy + di;
    if (h2 < 0 || h2 >= HX) continue;
    const float* row = xb + (size_t)h2 * HX + wq;
    float4 cv = *(const float4*)row;
    float lf = (wq > 0) ? row[-1] : 0.0f;
    float rt = (wq + 4 < HX) ? row[4] : 0.0f;
    float w0 = wc[(di + 1) * 3 + 0];
    float w1 = wc[(di + 1) * 3 + 1];
    float w2 = wc[(di + 1) * 3 + 2];
    s0 += w0 * lf   + w1 * cv.x + w2 * cv.y;
    s1 += w0 * cv.x + w1 * cv.y + w2 * cv.z;
    s2 += w0 * cv.y + w1 * cv.z + w2 * cv.w;
    s3 += w0 * cv.z + w1 * cv.w + w2 * rt;
  }
  {
    float4 cc = *(const float4*)(xb + (size_t)hy * HX + wq);
    s0 += cc.x; s1 += cc.y; s2 += cc.z; s3 += cc.w;
  }
  uint2 d;
  d.x = (uint32_t)f2bf(s0) | ((uint32_t)f2bf(s1) << 16);
  d.y = (uint32_t)f2bf(s2) | ((uint32_t)f2bf(s3) << 16);
  *(uint2*)(y + (size_t)bc * HXW + (size_t)hy * HX + wq) = d;
}

// ---------------------------------------------------------------------------
// fp32 -> bf16 flat convert (for w_kv).
// ---------------------------------------------------------------------------
__global__ void cvt_bf16_kernel(const float* __restrict__ src, unsigned short* __restrict__ dst,
                                int n) {
  int i = blockIdx.x * 256 + threadIdx.x;
  if (i < n) dst[i] = f2bf(src[i]);
}

// ---------------------------------------------------------------------------
// Depthwise 3x3 q path: fp32 NCHW in -> bf16 NHWC out, pre-scaled by 32^-0.5.
// ---------------------------------------------------------------------------
__global__ void dwconv_q_kernel(const float* __restrict__ x, const float* __restrict__ w,
                                unsigned short* __restrict__ qn, int total) {
  int i = blockIdx.x * 256 + threadIdx.x;
  if (i >= total) return;
  int wx = i % HS;
  int t = i / HS;
  int hy = t % HS;
  int bc = t / HS;
  int c = bc & 127;
  int b = bc >> 7;
  const float* xb = x + (size_t)bc * HSW;
  const float* wc = w + c * 9;
  float s = 0.0f;
  for (int di = -1; di <= 1; di++) {
    int h2 = hy + di;
    if (h2 < 0 || h2 >= HS) continue;
    for (int dj = -1; dj <= 1; dj++) {
      int w2 = wx + dj;
      if (w2 < 0 || w2 >= HS) continue;
      s += xb[(size_t)h2 * HS + w2] * wc[(di + 1) * 3 + (dj + 1)];
    }
  }
  qn[((size_t)(b * HSW + hy * HS + wx)) * 128 + c] = f2bf(s * 0.17677669529663688f);
}

// ---------------------------------------------------------------------------
// MFMA 1x1 conv kv path.
// ---------------------------------------------------------------------------
__global__ __launch_bounds__(256) void conv1_kv_mfma_kernel(
    const unsigned short* __restrict__ xpb,  // (2,128,61504) bf16 NCHW
    const unsigned short* __restrict__ wkb,  // (256,128) bf16
    unsigned short* __restrict__ y) {        // (2,61504,256) bf16 NHWC
  int b = blockIdx.y;
  int p0 = blockIdx.x * 64;
  int tid = threadIdx.x;
  int wave = tid >> 6, lane = tid & 63, quad = lane >> 4, l15 = lane & 15;
  __shared__ __align__(16) unsigned short lds[64 * 264];  // 33,792 B

  {
    int c = tid >> 1, half = tid & 1;
    const unsigned short* src = xpb + ((size_t)(b * 128 + c)) * HXW + p0 + half * 32;
#pragma unroll
    for (int j = 0; j < 8; j++) {
      uint2 v = *(const uint2*)(src + j * 4);
      int px = half * 32 + j * 4;
      lds[(px + 0) * 136 + c] = (unsigned short)(v.x & 0xffff);
      lds[(px + 1) * 136 + c] = (unsigned short)(v.x >> 16);
      lds[(px + 2) * 136 + c] = (unsigned short)(v.y & 0xffff);
      lds[(px + 3) * 136 + c] = (unsigned short)(v.y >> 16);
    }
  }
  __syncthreads();
  bf16x8 A[4];
#pragma unroll
  for (int kb = 0; kb < 4; kb++)
    A[kb] = __builtin_bit_cast(bf16x8,
        *(const uint4*)&lds[(wave * 16 + l15) * 136 + kb * 32 + quad * 8]);
  __syncthreads();

  const f32x4 zf = {0.f, 0.f, 0.f, 0.f};
#pragma unroll 1
  for (int ot = 0; ot < 16; ot++) {
    const unsigned short* wb = wkb + (size_t)(ot * 16 + l15) * 128 + quad * 8;
    f32x4 D = zf;
#pragma unroll
    for (int kb = 0; kb < 4; kb++) {
      bf16x8 B = __builtin_bit_cast(bf16x8, *(const uint4*)(wb + kb * 32));
      D = __builtin_amdgcn_mfma_f32_16x16x32_bf16(A[kb], B, D, 0, 0, 0);
    }
#pragma unroll
    for (int r = 0; r < 4; r++)
      lds[(wave * 16 + quad * 4 + r) * 264 + ot * 16 + l15] = f2bf(D[r]);
  }
  __syncthreads();
  {
    int px = tid >> 2, og = (tid & 3) * 64;
    const uint4* srcp = (const uint4*)&lds[px * 264 + og];
    uint4* dstp = (uint4*)(y + ((size_t)b * HXW + p0 + px) * 256 + og);
#pragma unroll
    for (int j = 0; j < 8; j++) dstp[j] = srcp[j];
  }
}

// ---------------------------------------------------------------------------
// Fused depthwise 3x3 K/V from bf16 NHWC tkv, channel-quad lanes.
// 32-px strips, 2-row groups -> grid (8,124,2) = 1984 blocks (~31 waves/CU).
// Pixel loop unrolled x2 with named A/B load sets: 18 uint2 loads in flight.
//  K (cq<32):  uint2 direct to NHWC kT (coalesced 256 B/wave)
//  V (cq>=32): LDS [ch][px] stride-35 transpose -> NCHW vv (9 KB LDS)
// ---------------------------------------------------------------------------
__global__ __launch_bounds__(256) void dwconv_kv_kernel(const unsigned short* __restrict__ tkv,
                                                        const float* __restrict__ w,
                                                        unsigned short* __restrict__ kT,
                                                        unsigned short* __restrict__ vv) {
  int strip = blockIdx.x;                      // 0..7
  int x0 = (strip == 7) ? 216 : strip * 32;
  int g = blockIdx.y;                          // 0..123
  int b = blockIdx.z;
  int tid = threadIdx.x;
  int cq = tid & 63;                           // channel quad (lane)
  int pg = tid >> 6;                           // 0..3 (wave-uniform)
  int ch0 = cq * 4;
  float wr[4][9];
#pragma unroll
  for (int j = 0; j < 4; j++)
#pragma unroll
    for (int t9 = 0; t9 < 9; t9++) wr[j][t9] = w[(ch0 + j) * 9 + t9];

  __shared__ unsigned short vt[128 * 35];      // [ch][px] stride 35 (9 KB)
  const unsigned short* base = tkv + (size_t)b * HXW * 256 + ch0;
  const uint2 z2 = {0u, 0u};

#define LOAD9(P, px)                                                           \
  uint2 P##_00, P##_01, P##_02, P##_10, P##_11, P##_12, P##_20, P##_21, P##_22;\
  {                                                                            \
    int xc = x0 + (px);                                                        \
    bool vl = xc > 0, vr = xc < HX - 1;                                        \
    size_t off = (size_t)xc * 256;                                             \
    P##_00 = (vtop && vl) ? *(const uint2*)(r0 + off - 256) : z2;              \
    P##_01 = vtop ? *(const uint2*)(r0 + off) : z2;                            \
    P##_02 = (vtop && vr) ? *(const uint2*)(r0 + off + 256) : z2;              \
    P##_10 = vl ? *(const uint2*)(r1 + off - 256) : z2;                        \
    P##_11 = *(const uint2*)(r1 + off);                                        \
    P##_12 = vr ? *(const uint2*)(r1 + off + 256) : z2;                        \
    P##_20 = (vbot && vl) ? *(const uint2*)(r2 + off - 256) : z2;              \
    P##_21 = vbot ? *(const uint2*)(r2 + off) : z2;                            \
    P##_22 = (vbot && vr) ? *(const uint2*)(r2 + off + 256) : z2;              \
  }
#define COMP9(P, px)                                                           \
  {                                                                            \
    float o0 = 0.f, o1 = 0.f, o2 = 0.f, o3 = 0.f;                              \
    o0 += wr[0][0] * bflo(P##_00.x); o1 += wr[1][0] * bfhi(P##_00.x);          \
    o2 += wr[2][0] * bflo(P##_00.y); o3 += wr[3][0] * bfhi(P##_00.y);          \
    o0 += wr[0][1] * bflo(P##_01.x); o1 += wr[1][1] * bfhi(P##_01.x);          \
    o2 += wr[2][1] * bflo(P##_01.y); o3 += wr[3][1] * bfhi(P##_01.y);          \
    o0 += wr[0][2] * bflo(P##_02.x); o1 += wr[1][2] * bfhi(P##_02.x);          \
    o2 += wr[2][2] * bflo(P##_02.y); o3 += wr[3][2] * bfhi(P##_02.y);          \
    o0 += wr[0][3] * bflo(P##_10.x); o1 += wr[1][3] * bfhi(P##_10.x);          \
    o2 += wr[2][3] * bflo(P##_10.y); o3 += wr[3][3] * bfhi(P##_10.y);          \
    o0 += wr[0][4] * bflo(P##_11.x); o1 += wr[1][4] * bfhi(P##_11.x);          \
    o2 += wr[2][4] * bflo(P##_11.y); o3 += wr[3][4] * bfhi(P##_11.y);          \
    o0 += wr[0][5] * bflo(P##_12.x); o1 += wr[1][5] * bfhi(P##_12.x);          \
    o2 += wr[2][5] * bflo(P##_12.y); o3 += wr[3][5] * bfhi(P##_12.y);          \
    o0 += wr[0][6] * bflo(P##_20.x); o1 += wr[1][6] * bfhi(P##_20.x);          \
    o2 += wr[2][6] * bflo(P##_20.y); o3 += wr[3][6] * bfhi(P##_20.y);          \
    o0 += wr[0][7] * bflo(P##_21.x); o1 += wr[1][7] * bfhi(P##_21.x);          \
    o2 += wr[2][7] * bflo(P##_21.y); o3 += wr[3][7] * bfhi(P##_21.y);          \
    o0 += wr[0][8] * bflo(P##_22.x); o1 += wr[1][8] * bfhi(P##_22.x);          \
    o2 += wr[2][8] * bflo(P##_22.y); o3 += wr[3][8] * bfhi(P##_22.y);          \
    if (cq < 32) {                                                             \
      uint2 d;                                                                 \
      d.x = (uint32_t)f2bf(o0) | ((uint32_t)f2bf(o1) << 16);                   \
      d.y = (uint32_t)f2bf(o2) | ((uint32_t)f2bf(o3) << 16);                   \
      *(uint2*)(kT + ((size_t)b * HXW + (size_t)hy * HX + x0 + (px)) * 128 + ch0) = d; \
    } else {                                                                   \
      int c0 = ch0 - 128;                                                      \
      vt[(c0 + 0) * 35 + (px)] = f2bf(o0);                                     \
      vt[(c0 + 1) * 35 + (px)] = f2bf(o1);                                     \
      vt[(c0 + 2) * 35 + (px)] = f2bf(o2);                                     \
      vt[(c0 + 3) * 35 + (px)] = f2bf(o3);                                     \
    }                                                                          \
  }

#pragma unroll 1
  for (int r = 0; r < 2; r++) {
    int hy = g * 2 + r;
    bool vtop = hy > 0, vbot = hy < HX - 1;
    const unsigned short* r0 = base + ((size_t)(hy - 1) * HX) * 256;
    const unsigned short* r1 = base + ((size_t)hy * HX) * 256;
    const unsigned short* r2 = base + ((size_t)(hy + 1) * HX) * 256;

#pragma unroll 1
    for (int i = 0; i < 8; i += 2) {
      int pxA = pg + i * 4;
      int pxB = pg + (i + 1) * 4;
      LOAD9(A, pxA)
      LOAD9(B, pxB)
      COMP9(A, pxA)
      COMP9(B, pxB)
    }
    __syncthreads();
    {  // cooperative NCHW store of the V row
      int cv = tid & 127;
      int phx = (tid >> 7) * 16;
      unsigned short* dst = vv + ((size_t)(b * 128 + cv)) * HXW + (size_t)hy * HX + x0 + phx;
      const unsigned short* srcv = vt + cv * 35 + phx;
#pragma unroll
      for (int jj = 0; jj < 4; jj++) {
        uint2 d;
        d.x = (uint32_t)srcv[jj * 4 + 0] | ((uint32_t)srcv[jj * 4 + 1] << 16);
        d.y = (uint32_t)srcv[jj * 4 + 2] | ((uint32_t)srcv[jj * 4 + 3] << 16);
        *(uint2*)(dst + jj * 4) = d;
      }
    }
    __syncthreads();
  }
#undef LOAD9
#undef COMP9
}

// ---------------------------------------------------------------------------
// 1x1 conv tiled SGEMM (fp32) — small tensors (q path, output projection).
// ---------------------------------------------------------------------------
template <int O>
__global__ __launch_bounds__(256) void conv1_kernel(const float* __restrict__ x,
                                                    const float* __restrict__ w,
                                                    float* __restrict__ y, int HW) {
  constexpr int K = 128;
  constexpr int BK = 32;
  __shared__ __align__(16) float ws_s[BK][64];
  __shared__ __align__(16) float xs_s[BK][64];
  int b = blockIdx.z;
  int o0 = blockIdx.y * 64;
  int p0 = blockIdx.x * 64;
  const float* xb = x + (size_t)b * K * HW;
  int tx = threadIdx.x & 15;
  int ty = threadIdx.x >> 4;
  float acc[4][4] = {};
  int lo = threadIdx.x >> 2;
  int lk = (threadIdx.x & 3) * 8;
  int lc = threadIdx.x >> 3;
  int lp = (threadIdx.x & 7) * 8;

  for (int k0 = 0; k0 < K; k0 += BK) {
    __syncthreads();
    {
      const float* wp = w + (size_t)(o0 + lo) * K + k0 + lk;
      float4 a = *(const float4*)wp;
      float4 bq = *(const float4*)(wp + 4);
      ws_s[lk + 0][lo] = a.x;  ws_s[lk + 1][lo] = a.y;
      ws_s[lk + 2][lo] = a.z;  ws_s[lk + 3][lo] = a.w;
      ws_s[lk + 4][lo] = bq.x; ws_s[lk + 5][lo] = bq.y;
      ws_s[lk + 6][lo] = bq.z; ws_s[lk + 7][lo] = bq.w;
    }
    {
      int p = p0 + lp;
      const float* xp = xb + (size_t)(k0 + lc) * HW;
      float4 a, bq;
      if (p + 7 < HW) {
        a = *(const float4*)(xp + p);
        bq = *(const float4*)(xp + p + 4);
      } else {
        float tv[8];
#pragma unroll
        for (int j = 0; j < 8; j++) tv[j] = (p + j < HW) ? xp[p + j] : 0.0f;
        a = make_float4(tv[0], tv[1], tv[2], tv[3]);
        bq = make_float4(tv[4], tv[5], tv[6], tv[7]);
      }
      *(float4*)&xs_s[lc][lp] = a;
      *(float4*)&xs_s[lc][lp + 4] = bq;
    }
    __syncthreads();
#pragma unroll
    for (int k = 0; k < BK; k++) {
      float4 wv = *(const float4*)&ws_s[k][ty * 4];
      float4 xv = *(const float4*)&xs_s[k][tx * 4];
      acc[0][0] += wv.x * xv.x; acc[0][1] += wv.x * xv.y; acc[0][2] += wv.x * xv.z; acc[0][3] += wv.x * xv.w;
      acc[1][0] += wv.y * xv.x; acc[1][1] += wv.y * xv.y; acc[1][2] += wv.y * xv.z; acc[1][3] += wv.y * xv.w;
      acc[2][0] += wv.z * xv.x; acc[2][1] += wv.z * xv.y; acc[2][2] += wv.z * xv.z; acc[2][3] += wv.z * xv.w;
      acc[3][0] += wv.w * xv.x; acc[3][1] += wv.w * xv.y; acc[3][2] += wv.w * xv.z; acc[3][3] += wv.w * xv.w;
    }
  }
  int p = p0 + tx * 4;
  float* yb = y + (size_t)b * O * HW + (size_t)(o0 + ty * 4) * HW;
#pragma unroll
  for (int j = 0; j < 4; j++) {
    float* yr = yb + (size_t)j * HW + p;
    if (p + 3 < HW) {
      *(float4*)yr = make_float4(acc[j][0], acc[j][1], acc[j][2], acc[j][3]);
    } else {
#pragma unroll
      for (int e = 0; e < 4; e++) if (p + e < HW) yr[e] = acc[j][e];
    }
  }
}

// ---------------------------------------------------------------------------
// MFMA windowed attention, head-pair blocks. 512 thr = 8 waves.
// ---------------------------------------------------------------------------
__global__ __launch_bounds__(512) void attn_mfma_kernel(
    const unsigned short* __restrict__ qn,   // (2,62,62,128) bf16, pre-scaled
    const unsigned short* __restrict__ kT,   // (2,248,248,128) bf16 NHWC
    const unsigned short* __restrict__ vp,   // (2,128,248,248) bf16 NCHW
    float* __restrict__ o) {
  int n = blockIdx.x, hp = blockIdx.y, b = blockIdx.z;
  int wi = n / 10, wj = n % 10;
  int wave = threadIdx.x >> 6;
  int hd = wave & 1, oct = wave >> 1;
  int h = hp * 2 + hd;
  int lane = threadIdx.x & 63;
  int quad = lane >> 4;
  int l15 = lane & 15;
  int y0 = 24 * wi, x0 = 24 * wj;

  __shared__ __align__(16) unsigned short lds[20480];  // 40,960 B
  unsigned short* Pw = lds + wave * 2560;              // [q][40keys] 5KB/wave

  bf16x8 QB[4];
#pragma unroll
  for (int nt = 0; nt < 4; nt++) {
    int qq = nt * 16 + l15;
    int qy = 6 * wi + (qq >> 3), qx = 6 * wj + (qq & 7);
    QB[nt] = __builtin_bit_cast(bf16x8,
        *(const uint4*)(qn + ((size_t)(b * HSW + qy * HS + qx)) * 128 + h * 32 + quad * 8));
  }

  f32x4 Oacc[2][4];
#pragma unroll
  for (int a = 0; a < 2; a++)
#pragma unroll
    for (int c = 0; c < 4; c++) Oacc[a][c] = f32x4{0.f, 0.f, 0.f, 0.f};
  float lsum[4] = {0.f, 0.f, 0.f, 0.f};

  const unsigned short* kb = kT + (size_t)b * HXW * 128 + h * 32;
  const unsigned short* vb = vp + ((size_t)(b * 128 + h * 32)) * HXW;
  const f32x4 zf = {0.f, 0.f, 0.f, 0.f};

#define LOADROW(r, K0, K1, V0, V1)                                              \
  {                                                                             \
    int y = y0 + (r);                                                           \
    const unsigned short* krow = kb + ((size_t)(y * HX + x0)) * 128;            \
    K0 = *(const uint4*)(krow + (size_t)l15 * 128 + quad * 8);                  \
    K1 = *(const uint4*)(krow + (size_t)(16 + l15) * 128 + quad * 8);           \
    const unsigned short* vrow = vb + (size_t)y * HX + x0 + quad * 8;           \
    V0 = *(const uint4*)(vrow + (size_t)l15 * HXW);                             \
    V1 = *(const uint4*)(vrow + (size_t)(16 + l15) * HXW);                      \
  }

  auto compute = [&](uint4 k0, uint4 k1, uint4 v0, uint4 v1) {
    bf16x8 KA0 = __builtin_bit_cast(bf16x8, k0);
    bf16x8 KA1 = __builtin_bit_cast(bf16x8, k1);
    bf16x8 VA0 = __builtin_bit_cast(bf16x8, v0);
    bf16x8 VA1 = __builtin_bit_cast(bf16x8, v1);
    f32x4 S[2][4];
#pragma unroll
    for (int nt = 0; nt < 4; nt++) {
      S[0][nt] = __builtin_amdgcn_mfma_f32_16x16x32_bf16(KA0, QB[nt], zf, 0, 0, 0);
      S[1][nt] = __builtin_amdgcn_mfma_f32_16x16x32_bf16(KA1, QB[nt], zf, 0, 0, 0);
    }
#pragma unroll
    for (int nt = 0; nt < 4; nt++) {
      float pv[2][4];
      float cs = 0.f;
#pragma unroll
      for (int mt = 0; mt < 2; mt++)
#pragma unroll
        for (int r = 0; r < 4; r++) {
          pv[mt][r] = __expf(S[mt][nt][r]);
          cs += pv[mt][r];
        }
      lsum[nt] += cs;
#pragma unroll
      for (int mt = 0; mt < 2; mt++) {
        uint2 d;
        d.x = (uint32_t)f2bf(pv[mt][0]) | ((uint32_t)f2bf(pv[mt][1]) << 16);
        d.y = (uint32_t)f2bf(pv[mt][2]) | ((uint32_t)f2bf(pv[mt][3]) << 16);
        *(uint2*)(Pw + (16 * nt + l15) * 40 + 16 * mt + quad * 4) = d;
      }
    }
#pragma unroll
    for (int nt = 0; nt < 4; nt++) {
      bf16x8 PB = __builtin_bit_cast(bf16x8, *(const uint4*)(Pw + (16 * nt + l15) * 40 + quad * 8));
      Oacc[0][nt] = __builtin_amdgcn_mfma_f32_16x16x32_bf16(VA0, PB, Oacc[0][nt], 0, 0, 0);
      Oacc[1][nt] = __builtin_amdgcn_mfma_f32_16x16x32_bf16(VA1, PB, Oacc[1][nt], 0, 0, 0);
    }
  };

  int rbase = oct * 8;
  uint4 kA0, kA1, vA0, vA1, kB0, kB1, vB0, vB1;
  LOADROW(rbase + 0, kA0, kA1, vA0, vA1);
  LOADROW(rbase + 1, kB0, kB1, vB0, vB1);
#pragma unroll 1
  for (int r = 0; r < 8; r += 2) {
    if (r + 2 < 8) {
      compute(kA0, kA1, vA0, vA1);
      LOADROW(rbase + r + 2, kA0, kA1, vA0, vA1);
      compute(kB0, kB1, vB0, vB1);
      LOADROW(rbase + r + 3, kB0, kB1, vB0, vB1);
    } else {
      compute(kA0, kA1, vA0, vA1);
      compute(kB0, kB1, vB0, vB1);
    }
  }
#undef LOADROW

#pragma unroll
  for (int nt = 0; nt < 4; nt++) {
    lsum[nt] += __shfl_xor(lsum[nt], 16, 64);
    lsum[nt] += __shfl_xor(lsum[nt], 32, 64);
  }

  float* mO = (float*)lds;                 // [oct][32ch][64q]  32 KB
  float* mL = (float*)(lds + 16384);       // [oct][64q]
#pragma unroll 1
  for (int p = 0; p < 2; p++) {
    __syncthreads();
    if (hd == p) {
#pragma unroll
      for (int mt = 0; mt < 2; mt++)
#pragma unroll
        for (int nt = 0; nt < 4; nt++)
#pragma unroll
          for (int r = 0; r < 4; r++)
            mO[oct * 2048 + (16 * mt + quad * 4 + r) * 64 + 16 * nt + l15] = Oacc[mt][nt][r];
      if (quad == 0) {
#pragma unroll
        for (int nt = 0; nt < 4; nt++) mL[oct * 64 + nt * 16 + l15] = lsum[nt];
      }
    }
    __syncthreads();
    {
      int q = threadIdx.x & 63;
      int cg = threadIdx.x >> 6;  // 0..7 -> 4 ch each
      float inv = 1.0f / (mL[q] + mL[64 + q] + mL[128 + q] + mL[192 + q]);
      float* ob = o + (((size_t)(b * 100 + n)) * 128 + (hp * 2 + p) * 32 + cg * 4) * 64 + q;
#pragma unroll
      for (int e = 0; e < 4; e++) {
        int ch = cg * 4 + e;
        float s = mO[ch * 64 + q] + mO[2048 + ch * 64 + q] +
                  mO[4096 + ch * 64 + q] + mO[6144 + ch * 64 + q];
        ob[(size_t)e * 64] = s * inv;
      }
    }
  }
}

// ---------------------------------------------------------------------------
// Reverse: scatter-average overlapping 8x8 windows (step 6) into (2,128,62,62)
// ---------------------------------------------------------------------------
__global__ void reverse_kernel(const float* __restrict__ win, float* __restrict__ out) {
  int i = blockIdx.x * 256 + threadIdx.x;
  const int total = 2 * 128 * HSW;
  if (i >= total) return;
  int x = i % HS;
  int t = i / HS;
  int y = t % HS;
  t /= HS;
  int c = t % 128;
  int b = t / 128;
  int wi0 = (y >= 7) ? (y - 2) / 6 : 0;
  int wi1 = min(9, y / 6);
  int wj0 = (x >= 7) ? (x - 2) / 6 : 0;
  int wj1 = min(9, x / 6);
  float s = 0.0f;
  for (int wi = wi0; wi <= wi1; wi++)
    for (int wj = wj0; wj <= wj1; wj++) {
      int di = y - 6 * wi, dj = x - 6 * wj;
      s += win[(((size_t)(b * 100 + wi * 10 + wj)) * 128 + c) * 64 + di * 8 + dj];
    }
  float cnt = (float)((wi1 - wi0 + 1) * (wj1 - wj0 + 1));
  out[i] = s / cnt;
}

// ---------------------------------------------------------------------------
extern "C" void kernel_launch(void* const* d_in, const int* in_sizes, int n_in,
                              void* d_out, int out_size, void* d_ws, size_t ws_size,
                              hipStream_t stream) {
  const float* x      = (const float*)d_in[0];
  const float* sp     = (const float*)d_in[1];
  const float* w_pos  = (const float*)d_in[2];
  const float* b_pos  = (const float*)d_in[3];
  const float* w_q    = (const float*)d_in[4];
  const float* w_qdw  = (const float*)d_in[5];
  const float* w_kv   = (const float*)d_in[6];
  const float* w_kvdw = (const float*)d_in[7];
  const float* w_out  = (const float*)d_in[8];
  float* out = (float*)d_out;

  const size_t N_x   = (size_t)2 * 128 * HXW;  // 15,745,024
  const size_t N_t   = (size_t)2 * 256 * HXW;
  const size_t N_s   = (size_t)2 * 128 * HSW;
  const size_t N_att = (size_t)2 * 100 * 128 * 64;

  float* ws = (float*)d_ws;
  unsigned short* xpb = (unsigned short*)ws;
  unsigned short* kT  = (unsigned short*)ws;
  unsigned short* vv  = kT + N_x;
  unsigned short* tkv = (unsigned short*)(ws + N_x);
  float* att = ws + N_x;
  float* rev = att + N_att;
  float* spp = ws + N_x + N_t / 2;
  float* tq  = spp + N_s;
  unsigned short* qn  = (unsigned short*)(tq + N_s);
  unsigned short* wkb = qn + N_s;              // 32768 ushorts
  (void)ws_size; (void)in_sizes; (void)n_in; (void)out_size;

  // 0. wkb = bf16(w_kv)
  cvt_bf16_kernel<<<128, 256, 0, stream>>>(w_kv, wkb, 256 * 128);
  // 1. xpb = bf16(x + dwconv3(x, w_pos, b_pos))   (bf16 NCHW)
  {
    int total4 = (int)(N_x / 4);
    dwconv4_bf16_kernel<<<(total4 + 255) / 256, 256, 0, stream>>>(x, w_pos, b_pos, xpb, total4);
  }
  // 2. spp = sp + dwconv3(sp, w_pos, b_pos)
  {
    int total = (int)N_s;
    dwconv3_kernel<<<(total + 255) / 256, 256, 0, stream>>>(sp, w_pos, b_pos, spp, 128, HS, HS, total, 1);
  }
  // 3. tq = conv1(spp, w_q)
  {
    int HW = HSW;
    dim3 grid((HW + 63) / 64, 2, 2);
    conv1_kernel<128><<<grid, 256, 0, stream>>>(spp, w_q, tq, HW);
  }
  // 4. qn = bf16_nhwc(dwconv3(tq, w_qdw)) * 32^-0.5
  {
    int total = (int)N_s;
    dwconv_q_kernel<<<(total + 255) / 256, 256, 0, stream>>>(tq, w_qdw, qn, total);
  }
  // 5. tkv = bf16_nhwc(mfma_conv1(xpb, wkb))   (xpb dead after)
  {
    dim3 grid(HXW / 64, 2);
    conv1_kv_mfma_kernel<<<grid, 256, 0, stream>>>(xpb, wkb, tkv);
  }
  // 6. kT (NHWC) + vv (NCHW) = bf16(dwconv3(tkv, w_kvdw))   (overwrites xpb)
  {
    dim3 grid(8, 124, 2);
    dwconv_kv_kernel<<<grid, 256, 0, stream>>>(tkv, w_kvdw, kT, vv);
  }
  // 7. attention -> att (2,100,128,64)
  {
    dim3 grid(100, 2, 2);
    attn_mfma_kernel<<<grid, 512, 0, stream>>>(qn, kT, vv, att);
  }
  // 8. rev = reverse(att)
  {
    int total = (int)N_s;
    reverse_kernel<<<(total + 255) / 256, 256, 0, stream>>>(att, rev);
  }
  // 9. out = conv1(rev, w_out)
  {
    int HW = HSW;
    dim3 grid((HW + 63) / 64, 2, 2);
    conv1_kernel<128><<<grid, 256, 0, stream>>>(rev, w_out, out, HW);
  }
}

// Round 13
// 360.586 us; speedup vs baseline: 1.6815x; 1.0545x over previous
//
#include <hip/hip_runtime.h>
#include <cstdint>

#define HS 62
#define HX 248
#define HXW (HX * HX)  // 61504
#define HSW (HS * HS)  // 3844

typedef __attribute__((ext_vector_type(8))) short bf16x8;
typedef __attribute__((ext_vector_type(4))) float f32x4;

static __device__ __forceinline__ unsigned short f2bf(float f) {
  uint32_t u = __builtin_bit_cast(uint32_t, f);
  u += 0x7fff + ((u >> 16) & 1);  // RNE
  return (unsigned short)(u >> 16);
}
static __device__ __forceinline__ float bf2f(unsigned short u) {
  uint32_t x = (uint32_t)u << 16;
  return __builtin_bit_cast(float, x);
}
static __device__ __forceinline__ float bflo(uint32_t u) {
  return __builtin_bit_cast(float, u << 16);
}
static __device__ __forceinline__ float bfhi(uint32_t u) {
  return __builtin_bit_cast(float, u & 0xffff0000u);
}

// ---------------------------------------------------------------------------
// Depthwise 3x3 scalar (62x62 tensors), fp32 out, bias+residual.
// ---------------------------------------------------------------------------
__global__ void dwconv3_kernel(const float* __restrict__ x, const float* __restrict__ w,
                               const float* __restrict__ bias, float* __restrict__ y,
                               int C, int H, int W, int total, int residual) {
  int i = blockIdx.x * 256 + threadIdx.x;
  if (i >= total) return;
  int wx = i % W;
  int t = i / W;
  int hy = t % H;
  int bc = t / H;
  int c = bc % C;
  const float* xb = x + (size_t)bc * H * W;
  const float* wc = w + c * 9;
  float s = bias ? bias[c] : 0.0f;
  for (int di = -1; di <= 1; di++) {
    int h2 = hy + di;
    if (h2 < 0 || h2 >= H) continue;
    for (int dj = -1; dj <= 1; dj++) {
      int w2 = wx + dj;
      if (w2 < 0 || w2 >= W) continue;
      s += xb[(size_t)h2 * W + w2] * wc[(di + 1) * 3 + (dj + 1)];
    }
  }
  if (residual) s += xb[(size_t)hy * W + wx];
  y[i] = s;
}

// ---------------------------------------------------------------------------
// Depthwise 3x3 x-path: fp32 NCHW in -> bf16 NCHW out, residual. 4 px/thread.
// ---------------------------------------------------------------------------
__global__ void dwconv4_bf16_kernel(const float* __restrict__ x, const float* __restrict__ w,
                                    const float* __restrict__ bias,
                                    unsigned short* __restrict__ y, int total4) {
  int i = blockIdx.x * 256 + threadIdx.x;
  if (i >= total4) return;
  int W4 = HX >> 2;
  int wq = (i % W4) * 4;
  int t = i / W4;
  int hy = t % HX;
  int bc = t / HX;
  int c = bc & 127;
  const float* xb = x + (size_t)bc * HXW;
  const float* wc = w + c * 9;
  float bv = bias[c];
  float s0 = bv, s1 = bv, s2 = bv, s3 = bv;
  for (int di = -1; di <= 1; di++) {
    int h2 = hy + di;
    if (h2 < 0 || h2 >= HX) continue;
    const float* row = xb + (size_t)h2 * HX + wq;
    float4 cv = *(const float4*)row;
    float lf = (wq > 0) ? row[-1] : 0.0f;
    float rt = (wq + 4 < HX) ? row[4] : 0.0f;
    float w0 = wc[(di + 1) * 3 + 0];
    float w1 = wc[(di + 1) * 3 + 1];
    float w2 = wc[(di + 1) * 3 + 2];
    s0 += w0 * lf   + w1 * cv.x + w2 * cv.y;
    s1 += w0 * cv.x + w1 * cv.y + w2 * cv.z;
    s2 += w0 * cv.y + w1 * cv.z + w2 * cv.w;
    s3 += w0 * cv.z + w1 * cv.w + w2 * rt;
  }
  {
    float4 cc = *(const float4*)(xb + (size_t)hy * HX + wq);
    s0 += cc.x; s1 += cc.y; s2 += cc.z; s3 += cc.w;
  }
  uint2 d;
  d.x = (uint32_t)f2bf(s0) | ((uint32_t)f2bf(s1) << 16);
  d.y = (uint32_t)f2bf(s2) | ((uint32_t)f2bf(s3) << 16);
  *(uint2*)(y + (size_t)bc * HXW + (size_t)hy * HX + wq) = d;
}

// ---------------------------------------------------------------------------
// fp32 -> bf16 flat convert (for w_kv).
// ---------------------------------------------------------------------------
__global__ void cvt_bf16_kernel(const float* __restrict__ src, unsigned short* __restrict__ dst,
                                int n) {
  int i = blockIdx.x * 256 + threadIdx.x;
  if (i < n) dst[i] = f2bf(src[i]);
}

// ---------------------------------------------------------------------------
// Depthwise 3x3 q path: fp32 NCHW in -> bf16 NHWC out, pre-scaled by 32^-0.5.
// ---------------------------------------------------------------------------
__global__ void dwconv_q_kernel(const float* __restrict__ x, const float* __restrict__ w,
                                unsigned short* __restrict__ qn, int total) {
  int i = blockIdx.x * 256 + threadIdx.x;
  if (i >= total) return;
  int wx = i % HS;
  int t = i / HS;
  int hy = t % HS;
  int bc = t / HS;
  int c = bc & 127;
  int b = bc >> 7;
  const float* xb = x + (size_t)bc * HSW;
  const float* wc = w + c * 9;
  float s = 0.0f;
  for (int di = -1; di <= 1; di++) {
    int h2 = hy + di;
    if (h2 < 0 || h2 >= HS) continue;
    for (int dj = -1; dj <= 1; dj++) {
      int w2 = wx + dj;
      if (w2 < 0 || w2 >= HS) continue;
      s += xb[(size_t)h2 * HS + w2] * wc[(di + 1) * 3 + (dj + 1)];
    }
  }
  qn[((size_t)(b * HSW + hy * HS + wx)) * 128 + c] = f2bf(s * 0.17677669529663688f);
}

// ---------------------------------------------------------------------------
// MFMA 1x1 conv kv path.
// ---------------------------------------------------------------------------
__global__ __launch_bounds__(256) void conv1_kv_mfma_kernel(
    const unsigned short* __restrict__ xpb,  // (2,128,61504) bf16 NCHW
    const unsigned short* __restrict__ wkb,  // (256,128) bf16
    unsigned short* __restrict__ y) {        // (2,61504,256) bf16 NHWC
  int b = blockIdx.y;
  int p0 = blockIdx.x * 64;
  int tid = threadIdx.x;
  int wave = tid >> 6, lane = tid & 63, quad = lane >> 4, l15 = lane & 15;
  __shared__ __align__(16) unsigned short lds[64 * 264];  // 33,792 B

  {
    int c = tid >> 1, half = tid & 1;
    const unsigned short* src = xpb + ((size_t)(b * 128 + c)) * HXW + p0 + half * 32;
#pragma unroll
    for (int j = 0; j < 8; j++) {
      uint2 v = *(const uint2*)(src + j * 4);
      int px = half * 32 + j * 4;
      lds[(px + 0) * 136 + c] = (unsigned short)(v.x & 0xffff);
      lds[(px + 1) * 136 + c] = (unsigned short)(v.x >> 16);
      lds[(px + 2) * 136 + c] = (unsigned short)(v.y & 0xffff);
      lds[(px + 3) * 136 + c] = (unsigned short)(v.y >> 16);
    }
  }
  __syncthreads();
  bf16x8 A[4];
#pragma unroll
  for (int kb = 0; kb < 4; kb++)
    A[kb] = __builtin_bit_cast(bf16x8,
        *(const uint4*)&lds[(wave * 16 + l15) * 136 + kb * 32 + quad * 8]);
  __syncthreads();

  const f32x4 zf = {0.f, 0.f, 0.f, 0.f};
#pragma unroll 1
  for (int ot = 0; ot < 16; ot++) {
    const unsigned short* wb = wkb + (size_t)(ot * 16 + l15) * 128 + quad * 8;
    f32x4 D = zf;
#pragma unroll
    for (int kb = 0; kb < 4; kb++) {
      bf16x8 B = __builtin_bit_cast(bf16x8, *(const uint4*)(wb + kb * 32));
      D = __builtin_amdgcn_mfma_f32_16x16x32_bf16(A[kb], B, D, 0, 0, 0);
    }
#pragma unroll
    for (int r = 0; r < 4; r++)
      lds[(wave * 16 + quad * 4 + r) * 264 + ot * 16 + l15] = f2bf(D[r]);
  }
  __syncthreads();
  {
    int px = tid >> 2, og = (tid & 3) * 64;
    const uint4* srcp = (const uint4*)&lds[px * 264 + og];
    uint4* dstp = (uint4*)(y + ((size_t)b * HXW + p0 + px) * 256 + og);
#pragma unroll
    for (int j = 0; j < 8; j++) dstp[j] = srcp[j];
  }
}

// ---------------------------------------------------------------------------
// Fused depthwise 3x3 K/V from bf16 NHWC tkv, channel-quad lanes.
// BRANCH-FREE tap loads: row pointers and x-offsets are clamped to safe
// addresses (scalar cselect), all 9 uint2 loads issue unconditionally and
// batch; edge zeroing happens on the loaded REGISTERS in rarely-taken
// uniform ifs. (Round 10/12 stall: branch-around-load at wave-uniform
// ternaries forced conservative vmcnt waits at merges.)
//  K (cq<32):  uint2 direct to NHWC kT (coalesced 256 B/wave)
//  V (cq>=32): LDS [ch][px] stride-35 transpose -> NCHW vv (9 KB LDS)
// Grid (8, 124, 2), 256 thr.
// ---------------------------------------------------------------------------
struct Tap9 { uint2 u00, u01, u02, u10, u11, u12, u20, u21, u22; };

__global__ __launch_bounds__(256) void dwconv_kv_kernel(const unsigned short* __restrict__ tkv,
                                                        const float* __restrict__ w,
                                                        unsigned short* __restrict__ kT,
                                                        unsigned short* __restrict__ vv) {
  int strip = blockIdx.x;                      // 0..7
  int x0 = (strip == 7) ? 216 : strip * 32;
  int g = blockIdx.y;                          // 0..123
  int b = blockIdx.z;
  int tid = threadIdx.x;
  int cq = tid & 63;                           // channel quad (lane)
  int pg = tid >> 6;                           // 0..3 (wave-uniform)
  int ch0 = cq * 4;
  float wr[4][9];
#pragma unroll
  for (int j = 0; j < 4; j++)
#pragma unroll
    for (int t9 = 0; t9 < 9; t9++) wr[j][t9] = w[(ch0 + j) * 9 + t9];

  __shared__ unsigned short vt[128 * 35];      // [ch][px] stride 35 (9 KB)
  const unsigned short* base = tkv + (size_t)b * HXW * 256 + ch0;
  const uint2 z2 = {0u, 0u};

#pragma unroll 1
  for (int r = 0; r < 2; r++) {
    int hy = g * 2 + r;
    const unsigned short* r1 = base + (size_t)hy * HX * 256;
    const unsigned short* r0 = (hy > 0) ? (r1 - (size_t)HX * 256) : r1;       // clamped
    const unsigned short* r2 = (hy < HX - 1) ? (r1 + (size_t)HX * 256) : r1;  // clamped
    bool vtop = hy > 0, vbot = hy < HX - 1;

    auto load9 = [&](int px) {
      Tap9 t;
      int xc = x0 + px;
      size_t offC = (size_t)xc * 256;
      size_t offL = offC - ((xc > 0) ? 256 : 0);        // clamped
      size_t offR = offC + ((xc < HX - 1) ? 256 : 0);   // clamped
      t.u00 = *(const uint2*)(r0 + offL);
      t.u01 = *(const uint2*)(r0 + offC);
      t.u02 = *(const uint2*)(r0 + offR);
      t.u10 = *(const uint2*)(r1 + offL);
      t.u11 = *(const uint2*)(r1 + offC);
      t.u12 = *(const uint2*)(r1 + offR);
      t.u20 = *(const uint2*)(r2 + offL);
      t.u21 = *(const uint2*)(r2 + offC);
      t.u22 = *(const uint2*)(r2 + offR);
      return t;
    };
    auto maskcomp9 = [&](Tap9 t, int px) {
      int xc = x0 + px;
      if (!vtop) { t.u00 = z2; t.u01 = z2; t.u02 = z2; }
      if (!vbot) { t.u20 = z2; t.u21 = z2; t.u22 = z2; }
      if (xc == 0) { t.u00 = z2; t.u10 = z2; t.u20 = z2; }
      if (xc == HX - 1) { t.u02 = z2; t.u12 = z2; t.u22 = z2; }
      float o0 = 0.f, o1 = 0.f, o2 = 0.f, o3 = 0.f;
      o0 += wr[0][0] * bflo(t.u00.x); o1 += wr[1][0] * bfhi(t.u00.x);
      o2 += wr[2][0] * bflo(t.u00.y); o3 += wr[3][0] * bfhi(t.u00.y);
      o0 += wr[0][1] * bflo(t.u01.x); o1 += wr[1][1] * bfhi(t.u01.x);
      o2 += wr[2][1] * bflo(t.u01.y); o3 += wr[3][1] * bfhi(t.u01.y);
      o0 += wr[0][2] * bflo(t.u02.x); o1 += wr[1][2] * bfhi(t.u02.x);
      o2 += wr[2][2] * bflo(t.u02.y); o3 += wr[3][2] * bfhi(t.u02.y);
      o0 += wr[0][3] * bflo(t.u10.x); o1 += wr[1][3] * bfhi(t.u10.x);
      o2 += wr[2][3] * bflo(t.u10.y); o3 += wr[3][3] * bfhi(t.u10.y);
      o0 += wr[0][4] * bflo(t.u11.x); o1 += wr[1][4] * bfhi(t.u11.x);
      o2 += wr[2][4] * bflo(t.u11.y); o3 += wr[3][4] * bfhi(t.u11.y);
      o0 += wr[0][5] * bflo(t.u12.x); o1 += wr[1][5] * bfhi(t.u12.x);
      o2 += wr[2][5] * bflo(t.u12.y); o3 += wr[3][5] * bfhi(t.u12.y);
      o0 += wr[0][6] * bflo(t.u20.x); o1 += wr[1][6] * bfhi(t.u20.x);
      o2 += wr[2][6] * bflo(t.u20.y); o3 += wr[3][6] * bfhi(t.u20.y);
      o0 += wr[0][7] * bflo(t.u21.x); o1 += wr[1][7] * bfhi(t.u21.x);
      o2 += wr[2][7] * bflo(t.u21.y); o3 += wr[3][7] * bfhi(t.u21.y);
      o0 += wr[0][8] * bflo(t.u22.x); o1 += wr[1][8] * bfhi(t.u22.x);
      o2 += wr[2][8] * bflo(t.u22.y); o3 += wr[3][8] * bfhi(t.u22.y);
      if (cq < 32) {
        uint2 d;
        d.x = (uint32_t)f2bf(o0) | ((uint32_t)f2bf(o1) << 16);
        d.y = (uint32_t)f2bf(o2) | ((uint32_t)f2bf(o3) << 16);
        *(uint2*)(kT + ((size_t)b * HXW + (size_t)hy * HX + xc) * 128 + ch0) = d;
      } else {
        int c0 = ch0 - 128;
        vt[(c0 + 0) * 35 + px] = f2bf(o0);
        vt[(c0 + 1) * 35 + px] = f2bf(o1);
        vt[(c0 + 2) * 35 + px] = f2bf(o2);
        vt[(c0 + 3) * 35 + px] = f2bf(o3);
      }
    };

#pragma unroll 1
    for (int i = 0; i < 8; i += 2) {
      int pxA = pg + i * 4;
      int pxB = pg + (i + 1) * 4;
      Tap9 ta = load9(pxA);
      Tap9 tb = load9(pxB);
      maskcomp9(ta, pxA);
      maskcomp9(tb, pxB);
    }
    __syncthreads();
    {  // cooperative NCHW store of the V row
      int cv = tid & 127;
      int phx = (tid >> 7) * 16;
      unsigned short* dst = vv + ((size_t)(b * 128 + cv)) * HXW + (size_t)hy * HX + x0 + phx;
      const unsigned short* srcv = vt + cv * 35 + phx;
#pragma unroll
      for (int jj = 0; jj < 4; jj++) {
        uint2 d;
        d.x = (uint32_t)srcv[jj * 4 + 0] | ((uint32_t)srcv[jj * 4 + 1] << 16);
        d.y = (uint32_t)srcv[jj * 4 + 2] | ((uint32_t)srcv[jj * 4 + 3] << 16);
        *(uint2*)(dst + jj * 4) = d;
      }
    }
    __syncthreads();
  }
}

// ---------------------------------------------------------------------------
// 1x1 conv tiled SGEMM (fp32) — small tensors (q path, output projection).
// ---------------------------------------------------------------------------
template <int O>
__global__ __launch_bounds__(256) void conv1_kernel(const float* __restrict__ x,
                                                    const float* __restrict__ w,
                                                    float* __restrict__ y, int HW) {
  constexpr int K = 128;
  constexpr int BK = 32;
  __shared__ __align__(16) float ws_s[BK][64];
  __shared__ __align__(16) float xs_s[BK][64];
  int b = blockIdx.z;
  int o0 = blockIdx.y * 64;
  int p0 = blockIdx.x * 64;
  const float* xb = x + (size_t)b * K * HW;
  int tx = threadIdx.x & 15;
  int ty = threadIdx.x >> 4;
  float acc[4][4] = {};
  int lo = threadIdx.x >> 2;
  int lk = (threadIdx.x & 3) * 8;
  int lc = threadIdx.x >> 3;
  int lp = (threadIdx.x & 7) * 8;

  for (int k0 = 0; k0 < K; k0 += BK) {
    __syncthreads();
    {
      const float* wp = w + (size_t)(o0 + lo) * K + k0 + lk;
      float4 a = *(const float4*)wp;
      float4 bq = *(const float4*)(wp + 4);
      ws_s[lk + 0][lo] = a.x;  ws_s[lk + 1][lo] = a.y;
      ws_s[lk + 2][lo] = a.z;  ws_s[lk + 3][lo] = a.w;
      ws_s[lk + 4][lo] = bq.x; ws_s[lk + 5][lo] = bq.y;
      ws_s[lk + 6][lo] = bq.z; ws_s[lk + 7][lo] = bq.w;
    }
    {
      int p = p0 + lp;
      const float* xp = xb + (size_t)(k0 + lc) * HW;
      float4 a, bq;
      if (p + 7 < HW) {
        a = *(const float4*)(xp + p);
        bq = *(const float4*)(xp + p + 4);
      } else {
        float tv[8];
#pragma unroll
        for (int j = 0; j < 8; j++) tv[j] = (p + j < HW) ? xp[p + j] : 0.0f;
        a = make_float4(tv[0], tv[1], tv[2], tv[3]);
        bq = make_float4(tv[4], tv[5], tv[6], tv[7]);
      }
      *(float4*)&xs_s[lc][lp] = a;
      *(float4*)&xs_s[lc][lp + 4] = bq;
    }
    __syncthreads();
#pragma unroll
    for (int k = 0; k < BK; k++) {
      float4 wv = *(const float4*)&ws_s[k][ty * 4];
      float4 xv = *(const float4*)&xs_s[k][tx * 4];
      acc[0][0] += wv.x * xv.x; acc[0][1] += wv.x * xv.y; acc[0][2] += wv.x * xv.z; acc[0][3] += wv.x * xv.w;
      acc[1][0] += wv.y * xv.x; acc[1][1] += wv.y * xv.y; acc[1][2] += wv.y * xv.z; acc[1][3] += wv.y * xv.w;
      acc[2][0] += wv.z * xv.x; acc[2][1] += wv.z * xv.y; acc[2][2] += wv.z * xv.z; acc[2][3] += wv.z * xv.w;
      acc[3][0] += wv.w * xv.x; acc[3][1] += wv.w * xv.y; acc[3][2] += wv.w * xv.z; acc[3][3] += wv.w * xv.w;
    }
  }
  int p = p0 + tx * 4;
  float* yb = y + (size_t)b * O * HW + (size_t)(o0 + ty * 4) * HW;
#pragma unroll
  for (int j = 0; j < 4; j++) {
    float* yr = yb + (size_t)j * HW + p;
    if (p + 3 < HW) {
      *(float4*)yr = make_float4(acc[j][0], acc[j][1], acc[j][2], acc[j][3]);
    } else {
#pragma unroll
      for (int e = 0; e < 4; e++) if (p + e < HW) yr[e] = acc[j][e];
    }
  }
}

// ---------------------------------------------------------------------------
// MFMA windowed attention, head-pair blocks. 512 thr = 8 waves.
// ---------------------------------------------------------------------------
__global__ __launch_bounds__(512) void attn_mfma_kernel(
    const unsigned short* __restrict__ qn,   // (2,62,62,128) bf16, pre-scaled
    const unsigned short* __restrict__ kT,   // (2,248,248,128) bf16 NHWC
    const unsigned short* __restrict__ vp,   // (2,128,248,248) bf16 NCHW
    float* __restrict__ o) {
  int n = blockIdx.x, hp = blockIdx.y, b = blockIdx.z;
  int wi = n / 10, wj = n % 10;
  int wave = threadIdx.x >> 6;
  int hd = wave & 1, oct = wave >> 1;
  int h = hp * 2 + hd;
  int lane = threadIdx.x & 63;
  int quad = lane >> 4;
  int l15 = lane & 15;
  int y0 = 24 * wi, x0 = 24 * wj;

  __shared__ __align__(16) unsigned short lds[20480];  // 40,960 B
  unsigned short* Pw = lds + wave * 2560;              // [q][40keys] 5KB/wave

  bf16x8 QB[4];
#pragma unroll
  for (int nt = 0; nt < 4; nt++) {
    int qq = nt * 16 + l15;
    int qy = 6 * wi + (qq >> 3), qx = 6 * wj + (qq & 7);
    QB[nt] = __builtin_bit_cast(bf16x8,
        *(const uint4*)(qn + ((size_t)(b * HSW + qy * HS + qx)) * 128 + h * 32 + quad * 8));
  }

  f32x4 Oacc[2][4];
#pragma unroll
  for (int a = 0; a < 2; a++)
#pragma unroll
    for (int c = 0; c < 4; c++) Oacc[a][c] = f32x4{0.f, 0.f, 0.f, 0.f};
  float lsum[4] = {0.f, 0.f, 0.f, 0.f};

  const unsigned short* kb = kT + (size_t)b * HXW * 128 + h * 32;
  const unsigned short* vb = vp + ((size_t)(b * 128 + h * 32)) * HXW;
  const f32x4 zf = {0.f, 0.f, 0.f, 0.f};

#define LOADROW(r, K0, K1, V0, V1)                                              \
  {                                                                             \
    int y = y0 + (r);                                                           \
    const unsigned short* krow = kb + ((size_t)(y * HX + x0)) * 128;            \
    K0 = *(const uint4*)(krow + (size_t)l15 * 128 + quad * 8);                  \
    K1 = *(const uint4*)(krow + (size_t)(16 + l15) * 128 + quad * 8);           \
    const unsigned short* vrow = vb + (size_t)y * HX + x0 + quad * 8;           \
    V0 = *(const uint4*)(vrow + (size_t)l15 * HXW);                             \
    V1 = *(const uint4*)(vrow + (size_t)(16 + l15) * HXW);                      \
  }

  auto compute = [&](uint4 k0, uint4 k1, uint4 v0, uint4 v1) {
    bf16x8 KA0 = __builtin_bit_cast(bf16x8, k0);
    bf16x8 KA1 = __builtin_bit_cast(bf16x8, k1);
    bf16x8 VA0 = __builtin_bit_cast(bf16x8, v0);
    bf16x8 VA1 = __builtin_bit_cast(bf16x8, v1);
    f32x4 S[2][4];
#pragma unroll
    for (int nt = 0; nt < 4; nt++) {
      S[0][nt] = __builtin_amdgcn_mfma_f32_16x16x32_bf16(KA0, QB[nt], zf, 0, 0, 0);
      S[1][nt] = __builtin_amdgcn_mfma_f32_16x16x32_bf16(KA1, QB[nt], zf, 0, 0, 0);
    }
#pragma unroll
    for (int nt = 0; nt < 4; nt++) {
      float pv[2][4];
      float cs = 0.f;
#pragma unroll
      for (int mt = 0; mt < 2; mt++)
#pragma unroll
        for (int r = 0; r < 4; r++) {
          pv[mt][r] = __expf(S[mt][nt][r]);
          cs += pv[mt][r];
        }
      lsum[nt] += cs;
#pragma unroll
      for (int mt = 0; mt < 2; mt++) {
        uint2 d;
        d.x = (uint32_t)f2bf(pv[mt][0]) | ((uint32_t)f2bf(pv[mt][1]) << 16);
        d.y = (uint32_t)f2bf(pv[mt][2]) | ((uint32_t)f2bf(pv[mt][3]) << 16);
        *(uint2*)(Pw + (16 * nt + l15) * 40 + 16 * mt + quad * 4) = d;
      }
    }
#pragma unroll
    for (int nt = 0; nt < 4; nt++) {
      bf16x8 PB = __builtin_bit_cast(bf16x8, *(const uint4*)(Pw + (16 * nt + l15) * 40 + quad * 8));
      Oacc[0][nt] = __builtin_amdgcn_mfma_f32_16x16x32_bf16(VA0, PB, Oacc[0][nt], 0, 0, 0);
      Oacc[1][nt] = __builtin_amdgcn_mfma_f32_16x16x32_bf16(VA1, PB, Oacc[1][nt], 0, 0, 0);
    }
  };

  int rbase = oct * 8;
  uint4 kA0, kA1, vA0, vA1, kB0, kB1, vB0, vB1;
  LOADROW(rbase + 0, kA0, kA1, vA0, vA1);
  LOADROW(rbase + 1, kB0, kB1, vB0, vB1);
#pragma unroll 1
  for (int r = 0; r < 8; r += 2) {
    if (r + 2 < 8) {
      compute(kA0, kA1, vA0, vA1);
      LOADROW(rbase + r + 2, kA0, kA1, vA0, vA1);
      compute(kB0, kB1, vB0, vB1);
      LOADROW(rbase + r + 3, kB0, kB1, vB0, vB1);
    } else {
      compute(kA0, kA1, vA0, vA1);
      compute(kB0, kB1, vB0, vB1);
    }
  }
#undef LOADROW

#pragma unroll
  for (int nt = 0; nt < 4; nt++) {
    lsum[nt] += __shfl_xor(lsum[nt], 16, 64);
    lsum[nt] += __shfl_xor(lsum[nt], 32, 64);
  }

  float* mO = (float*)lds;                 // [oct][32ch][64q]  32 KB
  float* mL = (float*)(lds + 16384);       // [oct][64q]
#pragma unroll 1
  for (int p = 0; p < 2; p++) {
    __syncthreads();
    if (hd == p) {
#pragma unroll
      for (int mt = 0; mt < 2; mt++)
#pragma unroll
        for (int nt = 0; nt < 4; nt++)
#pragma unroll
          for (int r = 0; r < 4; r++)
            mO[oct * 2048 + (16 * mt + quad * 4 + r) * 64 + 16 * nt + l15] = Oacc[mt][nt][r];
      if (quad == 0) {
#pragma unroll
        for (int nt = 0; nt < 4; nt++) mL[oct * 64 + nt * 16 + l15] = lsum[nt];
      }
    }
    __syncthreads();
    {
      int q = threadIdx.x & 63;
      int cg = threadIdx.x >> 6;  // 0..7 -> 4 ch each
      float inv = 1.0f / (mL[q] + mL[64 + q] + mL[128 + q] + mL[192 + q]);
      float* ob = o + (((size_t)(b * 100 + n)) * 128 + (hp * 2 + p) * 32 + cg * 4) * 64 + q;
#pragma unroll
      for (int e = 0; e < 4; e++) {
        int ch = cg * 4 + e;
        float s = mO[ch * 64 + q] + mO[2048 + ch * 64 + q] +
                  mO[4096 + ch * 64 + q] + mO[6144 + ch * 64 + q];
        ob[(size_t)e * 64] = s * inv;
      }
    }
  }
}

// ---------------------------------------------------------------------------
// Reverse: scatter-average overlapping 8x8 windows (step 6) into (2,128,62,62)
// ---------------------------------------------------------------------------
__global__ void reverse_kernel(const float* __restrict__ win, float* __restrict__ out) {
  int i = blockIdx.x * 256 + threadIdx.x;
  const int total = 2 * 128 * HSW;
  if (i >= total) return;
  int x = i % HS;
  int t = i / HS;
  int y = t % HS;
  t /= HS;
  int c = t % 128;
  int b = t / 128;
  int wi0 = (y >= 7) ? (y - 2) / 6 : 0;
  int wi1 = min(9, y / 6);
  int wj0 = (x >= 7) ? (x - 2) / 6 : 0;
  int wj1 = min(9, x / 6);
  float s = 0.0f;
  for (int wi = wi0; wi <= wi1; wi++)
    for (int wj = wj0; wj <= wj1; wj++) {
      int di = y - 6 * wi, dj = x - 6 * wj;
      s += win[(((size_t)(b * 100 + wi * 10 + wj)) * 128 + c) * 64 + di * 8 + dj];
    }
  float cnt = (float)((wi1 - wi0 + 1) * (wj1 - wj0 + 1));
  out[i] = s / cnt;
}

// ---------------------------------------------------------------------------
extern "C" void kernel_launch(void* const* d_in, const int* in_sizes, int n_in,
                              void* d_out, int out_size, void* d_ws, size_t ws_size,
                              hipStream_t stream) {
  const float* x      = (const float*)d_in[0];
  const float* sp     = (const float*)d_in[1];
  const float* w_pos  = (const float*)d_in[2];
  const float* b_pos  = (const float*)d_in[3];
  const float* w_q    = (const float*)d_in[4];
  const float* w_qdw  = (const float*)d_in[5];
  const float* w_kv   = (const float*)d_in[6];
  const float* w_kvdw = (const float*)d_in[7];
  const float* w_out  = (const float*)d_in[8];
  float* out = (float*)d_out;

  const size_t N_x   = (size_t)2 * 128 * HXW;  // 15,745,024
  const size_t N_t   = (size_t)2 * 256 * HXW;
  const size_t N_s   = (size_t)2 * 128 * HSW;
  const size_t N_att = (size_t)2 * 100 * 128 * 64;

  float* ws = (float*)d_ws;
  unsigned short* xpb = (unsigned short*)ws;
  unsigned short* kT  = (unsigned short*)ws;
  unsigned short* vv  = kT + N_x;
  unsigned short* tkv = (unsigned short*)(ws + N_x);
  float* att = ws + N_x;
  float* rev = att + N_att;
  float* spp = ws + N_x + N_t / 2;
  float* tq  = spp + N_s;
  unsigned short* qn  = (unsigned short*)(tq + N_s);
  unsigned short* wkb = qn + N_s;              // 32768 ushorts
  (void)ws_size; (void)in_sizes; (void)n_in; (void)out_size;

  // 0. wkb = bf16(w_kv)
  cvt_bf16_kernel<<<128, 256, 0, stream>>>(w_kv, wkb, 256 * 128);
  // 1. xpb = bf16(x + dwconv3(x, w_pos, b_pos))   (bf16 NCHW)
  {
    int total4 = (int)(N_x / 4);
    dwconv4_bf16_kernel<<<(total4 + 255) / 256, 256, 0, stream>>>(x, w_pos, b_pos, xpb, total4);
  }
  // 2. spp = sp + dwconv3(sp, w_pos, b_pos)
  {
    int total = (int)N_s;
    dwconv3_kernel<<<(total + 255) / 256, 256, 0, stream>>>(sp, w_pos, b_pos, spp, 128, HS, HS, total, 1);
  }
  // 3. tq = conv1(spp, w_q)
  {
    int HW = HSW;
    dim3 grid((HW + 63) / 64, 2, 2);
    conv1_kernel<128><<<grid, 256, 0, stream>>>(spp, w_q, tq, HW);
  }
  // 4. qn = bf16_nhwc(dwconv3(tq, w_qdw)) * 32^-0.5
  {
    int total = (int)N_s;
    dwconv_q_kernel<<<(total + 255) / 256, 256, 0, stream>>>(tq, w_qdw, qn, total);
  }
  // 5. tkv = bf16_nhwc(mfma_conv1(xpb, wkb))   (xpb dead after)
  {
    dim3 grid(HXW / 64, 2);
    conv1_kv_mfma_kernel<<<grid, 256, 0, stream>>>(xpb, wkb, tkv);
  }
  // 6. kT (NHWC) + vv (NCHW) = bf16(dwconv3(tkv, w_kvdw))   (overwrites xpb)
  {
    dim3 grid(8, 124, 2);
    dwconv_kv_kernel<<<grid, 256, 0, stream>>>(tkv, w_kvdw, kT, vv);
  }
  // 7. attention -> att (2,100,128,64)
  {
    dim3 grid(100, 2, 2);
    attn_mfma_kernel<<<grid, 512, 0, stream>>>(qn, kT, vv, att);
  }
  // 8. rev = reverse(att)
  {
    int total = (int)N_s;
    reverse_kernel<<<(total + 255) / 256, 256, 0, stream>>>(att, rev);
  }
  // 9. out = conv1(rev, w_out)
  {
    int HW = HSW;
    dim3 grid((HW + 63) / 64, 2, 2);
    conv1_kernel<128><<<grid, 256, 0, stream>>>(rev, w_out, out, HW);
  }
}